// Round 9
// baseline (1950.086 us; speedup 1.0000x reference)
//
#include <hip/hip_runtime.h>
#include <math.h>

#define L_ 8
#define D_ 1024
#define H_ 16
#define HK_ 4
#define DH_ 64
#define F_ 2816
#define V_ 32000
#define T_ 1024
#define B_ 2
#define M_ (B_*T_)          // 2048 tokens
#define SCALE_ 0.125f       // DH^-0.5

typedef unsigned short u16;
typedef unsigned int   u32;
typedef __attribute__((ext_vector_type(4))) float  f32x4;
typedef __attribute__((ext_vector_type(8))) short  bf16x8;   // 8 bf16 = 4 VGPRs (MFMA A/B frag)
typedef __attribute__((ext_vector_type(4))) unsigned short u16x4;
typedef __attribute__((ext_vector_type(4))) unsigned int   u32x4;

__device__ __forceinline__ float bf2f(u16 h) {
    union { u32 u; float f; } v; v.u = ((u32)h) << 16; return v.f;
}
__device__ __forceinline__ u16 f2bf(float f) {   // round-to-nearest-even
    union { float f; u32 u; } v; v.f = f;
    u32 r = v.u + 0x7fffu + ((v.u >> 16) & 1u);
    return (u16)(r >> 16);
}

__device__ __forceinline__ void gl_lds16(const void* g, void* l) {
    __builtin_amdgcn_global_load_lds(
        (const __attribute__((address_space(1))) unsigned int*)g,
        (__attribute__((address_space(3))) unsigned int*)l,
        16, 0, 0);
}

__device__ __forceinline__ void bar8() {      // raw barrier + compiler fences
    asm volatile("" ::: "memory");
    __builtin_amdgcn_s_barrier();
    asm volatile("" ::: "memory");
}

// ---------------------------------------------------------------------------
// gemm8: 256x256 / BK=64 8-phase-class GEMM (m198/m201 structure, plain HIP).
// 8 waves (2M x 4N), per-wave C = 128x64 (8x4 frags). 2 LDS buffers
// (A,B: 2 x 32 KB each = 128 KB). Per K-tile: 4 phases x {ds_read subtile,
// stage 1 half-tile, barrier, lgkmcnt(0), setprio(1), 16 MFMA, setprio(0),
// barrier}. Counted vmcnt(4) once per tile (never 0 mid-loop). Both-sides
// XOR slot swizzle (attn2-proven): phys 16B slot = logical ^ (row&7).
// EPI: 1 = f32 store; 3 = fused SiLU (w1/w3 interleaved even/odd cols).
// ---------------------------------------------------------------------------
template<int EPI>
__global__ __launch_bounds__(512)
void gemm8_k(const u16* __restrict__ A, int K,
             const u16* __restrict__ W, int N,
             float* __restrict__ Of, u16* __restrict__ Ob)
{
    constexpr int TS = 256 * 64;            // u16 per tile buffer (32 KB)
    __shared__ u16 sA[2 * TS];              // 64 KB
    __shared__ u16 sB[2 * TS];              // 64 KB

    const int tid = threadIdx.x;
    const int lane = tid & 63, wv = tid >> 6;        // 8 waves
    const int wm = wv >> 2, wn = wv & 3;             // 2 x 4
    const int l15 = lane & 15, lhi = lane >> 4;

    // bijective XCD swizzle (grid % 8 == 0)
    const int nwg = gridDim.x;
    const int q8 = nwg >> 3;
    const int xcd = blockIdx.x & 7, off8 = blockIdx.x >> 3;
    const int wgid = xcd * q8 + off8;
    const int tM = wgid & 7, tN = wgid >> 3;         // M_/256 == 8

    const u16* Abase = A + (size_t)(tM * 256) * K;
    const u16* Wbase = W + (size_t)(tN * 256) * K;

    // staging lane geometry: chunk = 8 rows x 64 cols = 1 KB per wave-instr
    const int srow8 = lane >> 3;            // row within chunk (= row & 7)
    const int sp    = lane & 7;             // physical 16B slot
    const int scol  = (sp ^ srow8) * 8;     // pre-swizzled global col (elems)

    // stage half h (128 rows) of tile t2 into dst (A or B)
    auto stage = [&](const u16* gbase, int t2, int h, u16* dst) {
        const u16* g = gbase + (size_t)(h * 128) * K + (t2 << 6);
        u16* d = dst + h * 8192;
#pragma unroll
        for (int i = 0; i < 2; ++i) {
            int c = wv * 2 + i;                      // 0..15
            int row = c * 8 + srow8;                 // 0..127
            gl_lds16(g + (size_t)row * K + scol, d + c * 512);
        }
    };

    f32x4 acc[8][4];
#pragma unroll
    for (int i = 0; i < 8; ++i)
#pragma unroll
        for (int j = 0; j < 4; ++j) acc[i][j] = f32x4{0.f, 0.f, 0.f, 0.f};

    const int nt = K >> 6;                  // K-tiles of 64
    // prologue: A0(0) A1(0) B0(0) B1(0) [B0(1) B1(1)]
    stage(Abase, 0, 0, sA); stage(Abase, 0, 1, sA);
    stage(Wbase, 0, 0, sB); stage(Wbase, 0, 1, sB);
    if (nt > 1) {
        stage(Wbase, 1, 0, sB + TS); stage(Wbase, 1, 1, sB + TS);
        asm volatile("s_waitcnt vmcnt(4)" ::: "memory");
    } else {
        asm volatile("s_waitcnt vmcnt(0)" ::: "memory");
    }
    bar8();

    for (int t = 0; t < nt; ++t) {
        const int cur = t & 1;
        const u16* sa = sA + cur * TS;
        const u16* sb = sB + cur * TS;
        u16* saN = sA + (cur ^ 1) * TS;     // A(t+1)
        u16* sbN = sB + cur * TS;           // B(t+2): same parity as t

        bf16x8 breg[4][2];

#pragma unroll
        for (int p = 0; p < 4; ++p) {
            // ---- ds_read subtile (tile t) ----
            if (p == 0) {
#pragma unroll
                for (int j = 0; j < 4; ++j)
#pragma unroll
                    for (int kk = 0; kk < 2; ++kk) {
                        int br = wn * 64 + j * 16 + l15;
                        int ls = kk * 4 + lhi;
                        breg[j][kk] = *(const bf16x8*)
                            &sb[br * 64 + ((ls ^ (br & 7)) * 8)];
                    }
            }
            bf16x8 areg[2][2];
#pragma unroll
            for (int mi = 0; mi < 2; ++mi)
#pragma unroll
                for (int kk = 0; kk < 2; ++kk) {
                    int ar = wm * 128 + (p * 2 + mi) * 16 + l15;
                    int ls = kk * 4 + lhi;
                    areg[mi][kk] = *(const bf16x8*)
                        &sa[ar * 64 + ((ls ^ (ar & 7)) * 8)];
                }

            // ---- stage one half-tile ----
            if (p == 0 && t + 1 < nt) stage(Abase, t + 1, 0, saN);
            if (p == 1 && t + 1 < nt) stage(Abase, t + 1, 1, saN);
            if (p == 2 && t + 2 < nt) stage(Wbase, t + 2, 0, sbN);
            if (p == 3 && t + 2 < nt) stage(Wbase, t + 2, 1, sbN);

            // ---- counted gate, once per tile (guards tile t+1's reads) ----
            if (p == 3 && t + 1 < nt) {
                if (t + 2 < nt) asm volatile("s_waitcnt vmcnt(4)" ::: "memory");
                else            asm volatile("s_waitcnt vmcnt(0)" ::: "memory");
            }

            bar8();
            asm volatile("s_waitcnt lgkmcnt(0)" ::: "memory");
            __builtin_amdgcn_s_setprio(1);
#pragma unroll
            for (int mi = 0; mi < 2; ++mi)
#pragma unroll
                for (int j = 0; j < 4; ++j)
#pragma unroll
                    for (int kk = 0; kk < 2; ++kk)
                        acc[p * 2 + mi][j] = __builtin_amdgcn_mfma_f32_16x16x32_bf16(
                            areg[mi][kk], breg[j][kk], acc[p * 2 + mi][j], 0, 0, 0);
            __builtin_amdgcn_s_setprio(0);
            bar8();
        }
    }

    // epilogue: D col = lane&15, row = (lane>>4)*4 + reg
#pragma unroll
    for (int i = 0; i < 8; ++i)
#pragma unroll
        for (int j = 0; j < 4; ++j) {
            size_t gm = (size_t)tM * 256 + wm * 128 + i * 16 + lhi * 4;
            size_t gn = (size_t)tN * 256 + wn * 64 + j * 16 + l15;
#pragma unroll
            for (int r = 0; r < 4; ++r) {
                float v = acc[i][j][r];
                if (EPI == 1) {
                    Of[(gm + r) * (size_t)N + gn] = v;
                } else {   // EPI == 3: even col = h1, odd = h3
                    float b = __shfl_xor(v, 1);
                    if ((lane & 1) == 0) {
                        float s = v / (1.0f + expf(-v));
                        Ob[(gm + r) * (size_t)F_ + (gn >> 1)] = f2bf(s * b);
                    }
                }
            }
        }
}

// ---------------------------------------------------------------------------
// 2-phase double-buffered GEMM (proven): C[M,N]=A[M,K] x W[N,K]^T, bf16.
// EPI: 0 = bf16 store, 1 = f32 store, 2 = f32 +=,
//      3 = fused SiLU, 4 = fused RoPE + V-transpose
// ---------------------------------------------------------------------------
template<int BM, int BN, int EPI>
__global__ __launch_bounds__(256)
void gemm2_k(const u16* __restrict__ A, int K,
             const u16* __restrict__ W, int N,
             float* __restrict__ Of, u16* __restrict__ Ob,
             const float* __restrict__ tc, const float* __restrict__ ts)
{
    constexpr int FM = BM / 32;
    constexpr int FN = BN / 32;
    constexpr int GM = M_ / BM;
    constexpr int IPA = BM / 64;
    constexpr int IPB = BN / 64;
    __shared__ u16 sA[2 * BM * 32];
    __shared__ u16 sB[2 * BN * 32];

    const int tid  = threadIdx.x;
    const int lane = tid & 63, wv = tid >> 6;
    const int wm = wv >> 1, wn = wv & 1;
    const int l15 = lane & 15, lhi = lane >> 4;
    const int m0 = wm * (BM / 2), n0 = wn * (BN / 2);

    const int nwg = gridDim.x;
    const int q8 = nwg >> 3, r8 = nwg & 7;
    const int xcd = blockIdx.x & 7, off8 = blockIdx.x >> 3;
    const int wgid = (xcd < r8 ? xcd * (q8 + 1) : r8 * (q8 + 1) + (xcd - r8) * q8) + off8;
    const int tM = wgid % GM, tN = wgid / GM;

    const int srow = lane >> 2;
    const int scol = (lane & 3) * 8;

    const u16* Abase = A + (size_t)(tM * BM) * K;
    const u16* Wbase = W + (size_t)(tN * BN) * K;

    f32x4 acc[FM][FN];
#pragma unroll
    for (int i = 0; i < FM; ++i)
#pragma unroll
        for (int j = 0; j < FN; ++j) acc[i][j] = f32x4{0.f, 0.f, 0.f, 0.f};

    auto stage = [&](int kt, int buf) {
        u16* sa = sA + buf * (BM * 32);
        u16* sb = sB + buf * (BN * 32);
#pragma unroll
        for (int i = 0; i < IPA; ++i) {
            int c = wv * IPA + i;
            gl_lds16(Abase + (size_t)(c * 16 + srow) * K + kt + scol, sa + c * 512);
        }
#pragma unroll
        for (int i = 0; i < IPB; ++i) {
            int c = wv * IPB + i;
            gl_lds16(Wbase + (size_t)(c * 16 + srow) * K + kt + scol, sb + c * 512);
        }
    };

    const int nt = K >> 5;
    stage(0, 0);
    asm volatile("s_waitcnt vmcnt(0)" ::: "memory");
    __syncthreads();

    int cur = 0;
    for (int t = 0; t < nt; ++t) {
        if (t + 1 < nt) stage((t + 1) << 5, cur ^ 1);

        const u16* sa = sA + cur * (BM * 32);
        const u16* sb = sB + cur * (BN * 32);
        bf16x8 av[FM], bv[FN];
#pragma unroll
        for (int i = 0; i < FM; ++i)
            av[i] = *(const bf16x8*)&sa[(m0 + i * 16 + l15) * 32 + lhi * 8];
#pragma unroll
        for (int j = 0; j < FN; ++j)
            bv[j] = *(const bf16x8*)&sb[(n0 + j * 16 + l15) * 32 + lhi * 8];
#pragma unroll
        for (int i = 0; i < FM; ++i)
#pragma unroll
            for (int j = 0; j < FN; ++j)
                acc[i][j] = __builtin_amdgcn_mfma_f32_16x16x32_bf16(
                    av[i], bv[j], acc[i][j], 0, 0, 0);

        if (t + 1 < nt) {
            asm volatile("s_waitcnt vmcnt(0)" ::: "memory");
            __syncthreads();
            cur ^= 1;
        }
    }

#pragma unroll
    for (int i = 0; i < FM; ++i)
#pragma unroll
        for (int j = 0; j < FN; ++j) {
            size_t gm = (size_t)tM * BM + m0 + i * 16 + lhi * 4;
            size_t gn = (size_t)tN * BN + n0 + j * 16 + l15;
#pragma unroll
            for (int r = 0; r < 4; ++r) {
                float v = acc[i][j][r];
                size_t idx = (gm + r) * (size_t)N + gn;
                if (EPI == 0) {
                    Ob[idx] = f2bf(v);
                } else if (EPI == 1) {
                    Of[idx] = v;
                } else if (EPI == 2) {
                    Of[idx] += v;
                } else if (EPI == 3) {
                    float b = __shfl_xor(v, 1);
                    if ((lane & 1) == 0) {
                        float s = v / (1.0f + expf(-v));
                        Ob[(gm + r) * (size_t)F_ + (gn >> 1)] = f2bf(s * b);
                    }
                } else {   // EPI == 4: RoPE q/k; v cols -> transposed vt
                    float b = __shfl_xor(v, 1);
                    int gni = (int)gn;
                    int gmr = (int)(gm + r);
                    if (gni < 1280) {
                        int dd = gni & 63;
                        int jj = dd >> 1;
                        int tt = gmr & (T_ - 1);
                        float c = tc[tt * 32 + jj], s = ts[tt * 32 + jj];
                        float ro = ((dd & 1) == 0) ? (v * c - b * s) : (b * s + v * c);
                        Ob[idx] = f2bf(ro);
                    } else {
                        int vc = gni - 1280;              // 0..255
                        int hk = vc >> 6, dd = vc & 63;
                        int bb = gmr >> 10, tt = gmr & (T_ - 1);
                        ((u16*)Of)[((size_t)((bb * HK_ + hk) * DH_ + dd)) * T_ + tt] = f2bf(v);
                    }
                }
            }
        }
}

// f32 -> bf16 layer-strided conversion
__global__ __launch_bounds__(256)
void cvt_k(const float* __restrict__ src, u16* __restrict__ dst,
           unsigned long long sStride, unsigned long long dStride)
{
    int l = blockIdx.y;
    size_t i = ((size_t)blockIdx.x * 256 + threadIdx.x) * 4;
    f32x4 v = *(const f32x4*)(src + l * sStride + i);
    u16x4 o;
    o.x = f2bf(v.x); o.y = f2bf(v.y); o.z = f2bf(v.z); o.w = f2bf(v.w);
    *(u16x4*)(dst + l * dStride + i) = o;
}

// f32 -> bf16 with row interleave: src row f -> dst row 2f+off (rows of D_)
__global__ __launch_bounds__(256)
void cvt_il_k(const float* __restrict__ src, u16* __restrict__ dst,
              unsigned long long sStride, unsigned long long dStride, int off)
{
    int f = blockIdx.x, l = blockIdx.y;
    int i = threadIdx.x * 4;
    f32x4 v = *(const f32x4*)(src + l * sStride + (size_t)f * D_ + i);
    u16x4 o;
    o.x = f2bf(v.x); o.y = f2bf(v.y); o.z = f2bf(v.z); o.w = f2bf(v.w);
    *(u16x4*)(dst + l * dStride + (size_t)(2 * f + off) * D_ + i) = o;
}

// ---------------------------------------------------------------------------
// FALLBACK GEMM (round-1, proven): cast-in-staging, multi-W split.
// ---------------------------------------------------------------------------
template<int BM, int BN, int EPI, int NW>
__global__ __launch_bounds__(256)
void gemm_k(const u16* __restrict__ A, int K,
            const float* __restrict__ W0, const float* __restrict__ W1p,
            const float* __restrict__ W2p, int N0, int N1, int N,
            float* __restrict__ Of, u16* __restrict__ Ob)
{
    constexpr int FM = BM / 32;
    constexpr int FN = BN / 32;
    constexpr int LS = 40;
    __shared__ u16 sA[BM * LS];
    __shared__ u16 sB[BN * LS];

    const int tid  = threadIdx.x;
    const int lane = tid & 63, wv = tid >> 6;
    const int wm = wv >> 1, wn = wv & 1;
    const int l15 = lane & 15, lhi = lane >> 4;
    const int m0 = wm * (BM / 2), n0 = wn * (BN / 2);
    const int tM = blockIdx.y, tN = blockIdx.x;

    f32x4 acc[FM][FN];
#pragma unroll
    for (int i = 0; i < FM; ++i)
#pragma unroll
        for (int j = 0; j < FN; ++j) acc[i][j] = f32x4{0.f, 0.f, 0.f, 0.f};

    for (int kt = 0; kt < K; kt += 32) {
#pragma unroll
        for (int i = 0; i < BM / 64; ++i) {
            int cid = tid + i * 256;
            int row = cid >> 2, kc = cid & 3;
            const u16* src = A + (size_t)(tM * BM + row) * K + kt + kc * 8;
            *(u32x4*)&sA[row * LS + kc * 8] = *(const u32x4*)src;
        }
#pragma unroll
        for (int i = 0; i < BN / 32; ++i) {
            int cid = tid + i * 256;
            int row = cid >> 3, kc = cid & 7;
            int n = tN * BN + row;
            const float* wr;
            if (NW == 1)      wr = W0 + (size_t)n * K;
            else if (NW == 2) wr = (n < N0) ? (W0 + (size_t)n * K)
                                            : (W1p + (size_t)(n - N0) * K);
            else              wr = (n < N0) ? (W0 + (size_t)n * K)
                               : (n < N0 + N1) ? (W1p + (size_t)(n - N0) * K)
                                               : (W2p + (size_t)(n - N0 - N1) * K);
            f32x4 v = *(const f32x4*)(wr + kt + kc * 4);
            u16x4 o;
            o.x = f2bf(v.x); o.y = f2bf(v.y); o.z = f2bf(v.z); o.w = f2bf(v.w);
            *(u16x4*)&sB[row * LS + kc * 4] = o;
        }
        __syncthreads();

        bf16x8 av[FM], bv[FN];
#pragma unroll
        for (int i = 0; i < FM; ++i)
            av[i] = *(const bf16x8*)&sA[(m0 + i * 16 + l15) * LS + lhi * 8];
#pragma unroll
        for (int j = 0; j < FN; ++j)
            bv[j] = *(const bf16x8*)&sB[(n0 + j * 16 + l15) * LS + lhi * 8];
#pragma unroll
        for (int i = 0; i < FM; ++i)
#pragma unroll
            for (int j = 0; j < FN; ++j)
                acc[i][j] = __builtin_amdgcn_mfma_f32_16x16x32_bf16(
                    av[i], bv[j], acc[i][j], 0, 0, 0);
        __syncthreads();
    }

#pragma unroll
    for (int i = 0; i < FM; ++i)
#pragma unroll
        for (int j = 0; j < FN; ++j) {
            size_t gm = (size_t)tM * BM + m0 + i * 16 + lhi * 4;
            size_t gn = (size_t)tN * BN + n0 + j * 16 + l15;
#pragma unroll
            for (int r = 0; r < 4; ++r) {
                float v = acc[i][j][r];
                size_t idx = (gm + r) * (size_t)N + gn;
                if (EPI == 0)      Ob[idx] = f2bf(v);
                else if (EPI == 1) Of[idx] = v;
                else               Of[idx] += v;
            }
        }
}

// ---------------------------------------------------------------------------
// Flash attention v3: GQA-shared K/V staging (proven round 8).
// ---------------------------------------------------------------------------
__global__ __launch_bounds__(512)
void attn3_k(const u16* __restrict__ qkv, const u16* __restrict__ vt,
             u16* __restrict__ attn)
{
    const int qt = 31 - blockIdx.x;
    const int hk = blockIdx.y, b = blockIdx.z;
    const int tid = threadIdx.x;
    const int lane = tid & 63, w = tid >> 6;
    const int l15 = lane & 15, lhi = lane >> 4;
    const int h = hk * 4 + (w & 3);
    const int rg = w >> 2;

    __shared__ u16 sK[128 * 64];
    __shared__ u16 sVT[64 * 128];
    __shared__ u16 sP[8][16 * 136];

    const int q0 = qt * 32;
    const int qr0 = q0 + rg * 16;
    const u16* qptr = qkv + (size_t)(b * T_ + qr0 + l15) * 1536 + h * 64 + lhi * 8;
    bf16x8 aq0 = *(const bf16x8*)qptr;
    bf16x8 aq1 = *(const bf16x8*)(qptr + 32);

    f32x4 accO[4];
#pragma unroll
    for (int d = 0; d < 4; ++d) accO[d] = f32x4{0.f, 0.f, 0.f, 0.f};
    float m_r[4] = {-1e30f, -1e30f, -1e30f, -1e30f};
    float l_r[4] = {0.f, 0.f, 0.f, 0.f};
    const int myq = qr0 + lhi * 4;
    const int qmaxw = qr0 + 15;
    u16* sPw = sP[w];

    const int ntiles = (qt >> 2) + 1;
    const u16* vtb = vt + (size_t)((b * HK_ + hk) * DH_) * T_;
    const int L = lane;

    for (int kt = 0; kt < ntiles; ++kt) {
        const int t0 = kt * 128;
#pragma unroll
        for (int i = 0; i < 2; ++i) {
            int c = w * 2 + i;
            int row = c * 8 + (L >> 3);
            int p = L & 7;
            const u16* src = qkv + (size_t)(b * T_ + t0 + row) * 1536 + 1024 + hk * 64
                             + ((p ^ (row & 7)) * 8);
            gl_lds16(src, sK + c * 512);
        }
#pragma unroll
        for (int i = 0; i < 2; ++i) {
            int c = w * 2 + i;
            int row = c * 4 + (L >> 4);
            int p = L & 15;
            const u16* src = vtb + (size_t)row * T_ + t0 + ((p ^ (row & 15)) * 8);
            gl_lds16(src, sVT + c * 512);
        }
        asm volatile("s_waitcnt vmcnt(0)" ::: "memory");
        __syncthreads();

        const bool lastt = (kt == ntiles - 1);

        f32x4 accS[8];
#pragma unroll
        for (int nf = 0; nf < 8; ++nf)
            accS[nf] = f32x4{-1e30f, -1e30f, -1e30f, -1e30f};
#pragma unroll
        for (int pk = 0; pk < 4; ++pk) {
            if (t0 + pk * 32 > qmaxw) continue;
            f32x4 s0 = f32x4{0.f, 0.f, 0.f, 0.f};
            f32x4 s1 = f32x4{0.f, 0.f, 0.f, 0.f};
#pragma unroll
            for (int kk = 0; kk < 2; ++kk) {
                bf16x8 aqs = kk ? aq1 : aq0;
                int r0 = (pk * 2) * 16 + l15;
                int r1 = (pk * 2 + 1) * 16 + l15;
                int ls = kk * 4 + lhi;
                bf16x8 b0 = *(const bf16x8*)&sK[r0 * 64 + ((ls ^ (r0 & 7)) * 8)];
                bf16x8 b1 = *(const bf16x8*)&sK[r1 * 64 + ((ls ^ (r1 & 7)) * 8)];
                s0 = __builtin_amdgcn_mfma_f32_16x16x32_bf16(aqs, b0, s0, 0, 0, 0);
                s1 = __builtin_amdgcn_mfma_f32_16x16x32_bf16(aqs, b1, s1, 0, 0, 0);
            }
#pragma unroll
            for (int r = 0; r < 4; ++r) {
                float v0 = s0[r] * SCALE_;
                float v1 = s1[r] * SCALE_;
                if (lastt) {
                    int kp0 = t0 + (pk * 2) * 16 + l15;
                    int kp1 = kp0 + 16;
                    if (kp0 > myq + r) v0 = -1e30f;
                    if (kp1 > myq + r) v1 = -1e30f;
                }
                accS[pk * 2][r] = v0;
                accS[pk * 2 + 1][r] = v1;
            }
        }

        float sc[4];
#pragma unroll
        for (int r = 0; r < 4; ++r) {
            float mx = accS[0][r];
#pragma unroll
            for (int nf = 1; nf < 8; ++nf) mx = fmaxf(mx, accS[nf][r]);
#pragma unroll
            for (int off = 1; off < 16; off <<= 1) mx = fmaxf(mx, __shfl_xor(mx, off));
            float mn = fmaxf(m_r[r], mx);
            sc[r] = expf(m_r[r] - mn);
            m_r[r] = mn;
        }
        float rs[4] = {0.f, 0.f, 0.f, 0.f};
#pragma unroll
        for (int pk = 0; pk < 4; ++pk) {
            if (t0 + pk * 32 > qmaxw) continue;
#pragma unroll
            for (int g = 0; g < 2; ++g) {
                int nf = pk * 2 + g;
#pragma unroll
                for (int r = 0; r < 4; ++r) {
                    float p = expf(accS[nf][r] - m_r[r]);
                    accS[nf][r] = p;
                    rs[r] += p;
                }
            }
        }
#pragma unroll
        for (int r = 0; r < 4; ++r) {
#pragma unroll
            for (int off = 1; off < 16; off <<= 1) rs[r] += __shfl_xor(rs[r], off);
            l_r[r] = l_r[r] * sc[r] + rs[r];
        }
#pragma unroll
        for (int d = 0; d < 4; ++d)
#pragma unroll
            for (int r = 0; r < 4; ++r) accO[d][r] *= sc[r];

#pragma unroll
        for (int pk = 0; pk < 4; ++pk) {
            if (t0 + pk * 32 > qmaxw) continue;
#pragma unroll
            for (int g = 0; g < 2; ++g) {
                int nf = pk * 2 + g;
#pragma unroll
                for (int r = 0; r < 4; ++r)
                    sPw[(lhi * 4 + r) * 136 + nf * 16 + l15] = f2bf(accS[nf][r]);
            }
        }

#pragma unroll
        for (int kk = 0; kk < 4; ++kk) {
            if (t0 + kk * 32 > qmaxw) continue;
            bf16x8 pas = *(const bf16x8*)&sPw[l15 * 136 + kk * 32 + lhi * 8];
#pragma unroll
            for (int nf = 0; nf < 4; ++nf) {
                int row = nf * 16 + l15;
                int ls = kk * 4 + lhi;
                bf16x8 bvv = *(const bf16x8*)&sVT[row * 128 + ((ls ^ (row & 15)) * 8)];
                accO[nf] = __builtin_amdgcn_mfma_f32_16x16x32_bf16(pas, bvv, accO[nf], 0, 0, 0);
            }
        }
        __syncthreads();
    }

#pragma unroll
    for (int d = 0; d < 4; ++d)
#pragma unroll
        for (int r = 0; r < 4; ++r) {
            int row = qr0 + lhi * 4 + r;
            float o = accO[d][r] / l_r[r];
            attn[(size_t)(b * T_ + row) * 1024 + h * 64 + d * 16 + l15] = f2bf(o);
        }
}

// ---------------------------------------------------------------------------
// FALLBACK attention (round-1 proven)
// ---------------------------------------------------------------------------
__global__ __launch_bounds__(256)
void attn_k(const u16* __restrict__ qkv, u16* __restrict__ attn)
{
    const int qt = blockIdx.x, h = blockIdx.y, b = blockIdx.z;
    const int hk = h >> 2;
    const int tid = threadIdx.x;
    const int lane = tid & 63, w = tid >> 6;
    const int l15 = lane & 15, lhi = lane >> 4;
    __shared__ u16 sK[64 * 72];
    __shared__ u16 sVT[64 * 74];
    __shared__ u16 sP[4 * 16 * 72];

    const int q0 = qt * 64;
    const u16* qptr = qkv + (size_t)(b * T_ + q0 + w * 16 + l15) * 1536 + h * 64 + lhi * 8;
    bf16x8 aq0 = *(const bf16x8*)qptr;
    bf16x8 aq1 = *(const bf16x8*)(qptr + 32);

    f32x4 accO[4];
#pragma unroll
    for (int d = 0; d < 4; ++d) accO[d] = f32x4{0.f, 0.f, 0.f, 0.f};
    float m_r[4] = {-1e30f, -1e30f, -1e30f, -1e30f};
    float l_r[4] = {0.f, 0.f, 0.f, 0.f};
    const int myq = q0 + w * 16 + lhi * 4;
    u16* sPw = sP + w * 16 * 72;

    for (int kt = 0; kt <= qt; ++kt) {
#pragma unroll
        for (int i = 0; i < 2; ++i) {
            int cid = tid + i * 256;
            int r = cid >> 3, kc = cid & 7;
            const u16* src = qkv + (size_t)(b * T_ + kt * 64 + r) * 1536 + 1024 + hk * 64 + kc * 8;
            *(u32x4*)&sK[r * 72 + kc * 8] = *(const u32x4*)src;
        }
#pragma unroll
        for (int i = 0; i < 2; ++i) {
            int cid = tid + i * 256;
            int tt = cid >> 3, dc = cid & 7;
            const u16* src = qkv + (size_t)(b * T_ + kt * 64 + tt) * 1536 + 1280 + hk * 64 + dc * 8;
            bf16x8 vv = *(const bf16x8*)src;
#pragma unroll
            for (int j = 0; j < 8; ++j) sVT[(dc * 8 + j) * 74 + tt] = (u16)vv[j];
        }
        __syncthreads();

        f32x4 accS[4];
#pragma unroll
        for (int nf = 0; nf < 4; ++nf) accS[nf] = f32x4{0.f, 0.f, 0.f, 0.f};
#pragma unroll
        for (int s = 0; s < 2; ++s) {
            bf16x8 aqs = s ? aq1 : aq0;
#pragma unroll
            for (int nf = 0; nf < 4; ++nf) {
                bf16x8 bk = *(const bf16x8*)&sK[(nf * 16 + l15) * 72 + s * 32 + lhi * 8];
                accS[nf] = __builtin_amdgcn_mfma_f32_16x16x32_bf16(aqs, bk, accS[nf], 0, 0, 0);
            }
        }
#pragma unroll
        for (int nf = 0; nf < 4; ++nf)
#pragma unroll
            for (int r = 0; r < 4; ++r) {
                float v = accS[nf][r] * SCALE_;
                if (kt == qt) {
                    int kp = kt * 64 + nf * 16 + l15;
                    if (kp > myq + r) v = -1e30f;
                }
                accS[nf][r] = v;
            }
        float sc[4];
#pragma unroll
        for (int r = 0; r < 4; ++r) {
            float mx = fmaxf(fmaxf(accS[0][r], accS[1][r]), fmaxf(accS[2][r], accS[3][r]));
#pragma unroll
            for (int off = 1; off < 16; off <<= 1) mx = fmaxf(mx, __shfl_xor(mx, off));
            float mn = fmaxf(m_r[r], mx);
            sc[r] = expf(m_r[r] - mn);
            m_r[r] = mn;
        }
        float rs[4] = {0.f, 0.f, 0.f, 0.f};
#pragma unroll
        for (int nf = 0; nf < 4; ++nf)
#pragma unroll
            for (int r = 0; r < 4; ++r) {
                float p = expf(accS[nf][r] - m_r[r]);
                accS[nf][r] = p;
                rs[r] += p;
            }
#pragma unroll
        for (int r = 0; r < 4; ++r) {
#pragma unroll
            for (int off = 1; off < 16; off <<= 1) rs[r] += __shfl_xor(rs[r], off);
            l_r[r] = l_r[r] * sc[r] + rs[r];
        }
#pragma unroll
        for (int d = 0; d < 4; ++d)
#pragma unroll
            for (int r = 0; r < 4; ++r) accO[d][r] *= sc[r];

#pragma unroll
        for (int nf = 0; nf < 4; ++nf)
#pragma unroll
            for (int r = 0; r < 4; ++r)
                sPw[(lhi * 4 + r) * 72 + nf * 16 + l15] = f2bf(accS[nf][r]);
        bf16x8 pa0 = *(const bf16x8*)&sPw[l15 * 72 + lhi * 8];
        bf16x8 pa1 = *(const bf16x8*)&sPw[l15 * 72 + 32 + lhi * 8];
#pragma unroll
        for (int s = 0; s < 2; ++s) {
            bf16x8 pas = s ? pa1 : pa0;
#pragma unroll
            for (int d = 0; d < 4; ++d) {
                bf16x8 bvv = *(const bf16x8*)&sVT[(d * 16 + l15) * 74 + s * 32 + lhi * 8];
                accO[d] = __builtin_amdgcn_mfma_f32_16x16x32_bf16(pas, bvv, accO[d], 0, 0, 0);
            }
        }
        __syncthreads();
    }

#pragma unroll
    for (int d = 0; d < 4; ++d)
#pragma unroll
        for (int r = 0; r < 4; ++r) {
            int row = q0 + w * 16 + lhi * 4 + r;
            float o = accO[d][r] / l_r[r];
            attn[(size_t)(b * T_ + row) * 1024 + h * 64 + d * 16 + l15] = f2bf(o);
        }
}

// ---------------------------------------------------------------------------
// Small elementwise kernels
// ---------------------------------------------------------------------------
__global__ __launch_bounds__(256)
void gather_k(const int* __restrict__ ids, const float* __restrict__ emb,
              float* __restrict__ x)
{
    int m = blockIdx.x, tid = threadIdx.x;
    int id = ids[m];
    *(f32x4*)(x + (size_t)m * D_ + tid * 4) =
        *(const f32x4*)(emb + (size_t)id * D_ + tid * 4);
}

__global__ __launch_bounds__(256)
void rmsnorm_k(const float* __restrict__ x, const float* __restrict__ g,
               u16* __restrict__ out)
{
    const int row = blockIdx.x, tid = threadIdx.x;
    const float* xr = x + (size_t)row * D_;
    f32x4 v = *(const f32x4*)(xr + tid * 4);
    float ss = v.x * v.x + v.y * v.y + v.z * v.z + v.w * v.w;
#pragma unroll
    for (int off = 32; off >= 1; off >>= 1) ss += __shfl_xor(ss, off);
    __shared__ float red[4];
    if ((tid & 63) == 0) red[tid >> 6] = ss;
    __syncthreads();
    float tot = red[0] + red[1] + red[2] + red[3];
    float rr = rsqrtf(tot * (1.0f / D_) + 1e-6f);
    f32x4 wv = *(const f32x4*)(g + tid * 4);
    u16x4 o;
    o.x = f2bf(v.x * rr * wv.x); o.y = f2bf(v.y * rr * wv.y);
    o.z = f2bf(v.z * rr * wv.z); o.w = f2bf(v.w * rr * wv.w);
    *(u16x4*)(out + (size_t)row * D_ + tid * 4) = o;
}

// cos/sin tables: tab[t*32 + j] = cos/sin(t * theta^(-j/32))
__global__ __launch_bounds__(256)
void rope_tab_k(float* __restrict__ tc, float* __restrict__ ts)
{
    int idx = blockIdx.x * 256 + threadIdx.x;
    int t = idx >> 5, j = idx & 31;
    float inv = powf(10000.0f, -(float)j * (1.0f / 32.0f));
    float ang = (float)t * inv;
    tc[idx] = cosf(ang);
    ts[idx] = sinf(ang);
}

// f32-silu (fallback path)
__global__ __launch_bounds__(256)
void silu_f32_k(const float* __restrict__ h13, u16* __restrict__ hh)
{
    int m = blockIdx.y;
    int f = blockIdx.x * 256 + threadIdx.x;
    float a = h13[(size_t)m * (2 * F_) + f];
    float c = h13[(size_t)m * (2 * F_) + F_ + f];
    float s = a / (1.0f + expf(-a));
    hh[(size_t)m * F_ + f] = f2bf(s * c);
}

__global__ __launch_bounds__(640)
void rope_slow_k(u16* __restrict__ qkv)
{
    int m = blockIdx.x;
    int c2 = threadIdx.x;
    int col = (c2 < 512) ? (c2 * 2) : (1024 + (c2 - 512) * 2);
    int d = col & 63;
    int t = m & (T_ - 1);
    float ang = (float)t * powf(10000.0f, -(float)d / 64.0f);
    float cs = cosf(ang), sn = sinf(ang);
    u16* p = qkv + (size_t)m * 1536 + col;
    float x0 = bf2f(p[0]), x1 = bf2f(p[1]);
    p[0] = f2bf(x0 * cs - x1 * sn);
    p[1] = f2bf(x0 * sn + x1 * cs);
}

// ---------------------------------------------------------------------------
extern "C" void kernel_launch(void* const* d_in, const int* in_sizes, int n_in,
                              void* d_out, int out_size, void* d_ws, size_t ws_size,
                              hipStream_t stream)
{
    const int*   ids = (const int*)d_in[0];
    const float* emb = (const float*)d_in[1];
    const float* qw  = (const float*)d_in[2];
    const float* kw  = (const float*)d_in[3];
    const float* vw  = (const float*)d_in[4];
    const float* ow  = (const float*)d_in[5];
    const float* w1  = (const float*)d_in[6];
    const float* w2  = (const float*)d_in[7];
    const float* w3  = (const float*)d_in[8];
    const float* n1  = (const float*)d_in[9];
    const float* n2  = (const float*)d_in[10];
    const float* nfw = (const float*)d_in[11];
    float* out = (float*)d_out;
    char*  ws  = (char*)d_ws;

    // ---- workspace layout ----
    float* x    = (float*)(ws);                    //  8 MB residual f32
    u16*   xn   = (u16*)(ws + 8388608ULL);         //  4 MB normed acts
    u16*   qkvb = (u16*)(ws + 12582912ULL);        //  6 MB fused qkv
    u16*   attnb= (u16*)(ws + 18874368ULL);        //  4 MB attn out
    u16*   hh   = (u16*)(ws + 46137344ULL);        // 11 MB silu(h1)*h3
    float* ropec= (float*)(ws + 57671680ULL);      // 128 KB
    float* ropes= (float*)(ws + 57802752ULL);      // 128 KB
    u16*   embb = (u16*)(ws + 57933824ULL);        // 62.5 MB
    u16*   wqkv = (u16*)(ws + 123469824ULL);       // 24 MB
    u16*   wob  = (u16*)(ws + 148635648ULL);       // 16 MB
    u16*   w13b = (u16*)(ws + 165412864ULL);       // 88 MB (w1/w3 row-interleaved)
    u16*   w2b  = (u16*)(ws + 257687552ULL);       // 44 MB
    u16*   vtb  = (u16*)(ws + 303824896ULL);       //  1 MB V^T
    const unsigned long long NEED = 304873472ULL;

    if (ws_size >= NEED) {
        cvt_k<<<dim3(32000, 1), 256, 0, stream>>>(emb, embb, 0, 0);
        cvt_k<<<dim3(1024, L_), 256, 0, stream>>>(qw, wqkv,            1048576ULL, 1572864ULL);
        cvt_k<<<dim3(256,  L_), 256, 0, stream>>>(kw, wqkv + 1048576,  262144ULL,  1572864ULL);
        cvt_k<<<dim3(256,  L_), 256, 0, stream>>>(vw, wqkv + 1310720,  262144ULL,  1572864ULL);
        cvt_k<<<dim3(1024, L_), 256, 0, stream>>>(ow, wob,             1048576ULL, 1048576ULL);
        cvt_il_k<<<dim3(2816, L_), 256, 0, stream>>>(w1, w13b, 2883584ULL, 5767168ULL, 0);
        cvt_il_k<<<dim3(2816, L_), 256, 0, stream>>>(w3, w13b, 2883584ULL, 5767168ULL, 1);
        cvt_k<<<dim3(2816, L_), 256, 0, stream>>>(w2, w2b,             2883584ULL, 2883584ULL);
        rope_tab_k<<<T_ * 32 / 256, 256, 0, stream>>>(ropec, ropes);

        gather_k<<<M_, 256, 0, stream>>>(ids, emb, x);

        for (int l = 0; l < L_; ++l) {
            rmsnorm_k<<<M_, 256, 0, stream>>>(x, n1 + l * D_, xn);
            // fused QKV + RoPE + V-transpose (v cols -> vtb, not qkvb)
            gemm2_k<64, 64, 4><<<32 * 24, 256, 0, stream>>>(
                xn, D_, wqkv + (size_t)l * 1572864, 1536, (float*)vtb, qkvb, ropec, ropes);
            attn3_k<<<dim3(32, HK_, B_), 512, 0, stream>>>(qkvb, vtb, attnb);
            gemm2_k<64, 64, 2><<<32 * 16, 256, 0, stream>>>(
                attnb, D_, wob + (size_t)l * 1048576, 1024, x, nullptr, nullptr, nullptr);
            rmsnorm_k<<<M_, 256, 0, stream>>>(x, n2 + l * D_, xn);
            // fused W1||W3 (interleaved) + SiLU -> hh  (8-phase 256^2)
            gemm8_k<3><<<8 * 22, 512, 0, stream>>>(
                xn, D_, w13b + (size_t)l * 5767168, 5632, nullptr, hh);
            gemm2_k<64, 64, 2><<<32 * 16, 256, 0, stream>>>(
                hh, F_, w2b + (size_t)l * 2883584, 1024, x, nullptr, nullptr, nullptr);
        }

        rmsnorm_k<<<M_, 256, 0, stream>>>(x, nfw, xn);
        // logits (8-phase 256^2)
        gemm8_k<1><<<8 * 125, 512, 0, stream>>>(
            xn, D_, embb, V_, out, nullptr);
        return;
    }

    // ---------------- fallback: round-1 proven path ----------------
    float* h13f = (float*)(ws + 23068672ULL);
    u16*   hhf  = (u16*)(ws + 69206016ULL);
    gather_k<<<M_, 256, 0, stream>>>(ids, emb, x);

    for (int l = 0; l < L_; ++l) {
        rmsnorm_k<<<M_, 256, 0, stream>>>(x, n1 + l * D_, xn);
        gemm_k<128, 64, 0, 3><<<dim3(24, 16), 256, 0, stream>>>(
            xn, D_,
            qw + (size_t)l * H_ * DH_ * D_,
            kw + (size_t)l * HK_ * DH_ * D_,
            vw + (size_t)l * HK_ * DH_ * D_,
            1024, 256, 1536, nullptr, qkvb);
        rope_slow_k<<<M_, 640, 0, stream>>>(qkvb);
        attn_k<<<dim3(T_ / 64, H_, B_), 256, 0, stream>>>(qkvb, attnb);
        gemm_k<128, 64, 2, 1><<<dim3(16, 16), 256, 0, stream>>>(
            attnb, D_, ow + (size_t)l * D_ * D_, nullptr, nullptr,
            0, 0, D_, x, nullptr);
        rmsnorm_k<<<M_, 256, 0, stream>>>(x, n2 + l * D_, xn);
        gemm_k<128, 128, 1, 2><<<dim3(44, 16), 256, 0, stream>>>(
            xn, D_, w1 + (size_t)l * F_ * D_, w3 + (size_t)l * F_ * D_, nullptr,
            F_, 0, 2 * F_, h13f, nullptr);
        silu_f32_k<<<dim3(11, M_), 256, 0, stream>>>(h13f, hhf);
        gemm_k<128, 64, 2, 1><<<dim3(16, 16), 256, 0, stream>>>(
            hhf, F_, w2 + (size_t)l * D_ * F_, nullptr, nullptr,
            0, 0, D_, x, nullptr);
    }

    rmsnorm_k<<<M_, 256, 0, stream>>>(x, nfw, xn);
    gemm_k<128, 128, 1, 1><<<dim3(250, 16), 256, 0, stream>>>(
        xn, D_, emb, nullptr, nullptr, 0, 0, V_, out, nullptr);
}

// Round 10
// 1806.580 us; speedup vs baseline: 1.0794x; 1.0794x over previous
//
#include <hip/hip_runtime.h>
#include <math.h>

#define L_ 8
#define D_ 1024
#define H_ 16
#define HK_ 4
#define DH_ 64
#define F_ 2816
#define V_ 32000
#define T_ 1024
#define B_ 2
#define M_ (B_*T_)          // 2048 tokens
#define SCALE_ 0.125f       // DH^-0.5

typedef unsigned short u16;
typedef unsigned int   u32;
typedef __attribute__((ext_vector_type(4))) float  f32x4;
typedef __attribute__((ext_vector_type(8))) short  bf16x8;   // 8 bf16 = 4 VGPRs (MFMA A/B frag)
typedef __attribute__((ext_vector_type(4))) unsigned short u16x4;
typedef __attribute__((ext_vector_type(4))) unsigned int   u32x4;

__device__ __forceinline__ float bf2f(u16 h) {
    union { u32 u; float f; } v; v.u = ((u32)h) << 16; return v.f;
}
__device__ __forceinline__ u16 f2bf(float f) {   // round-to-nearest-even
    union { float f; u32 u; } v; v.f = f;
    u32 r = v.u + 0x7fffu + ((v.u >> 16) & 1u);
    return (u16)(r >> 16);
}

__device__ __forceinline__ void gl_lds16(const void* g, void* l) {
    __builtin_amdgcn_global_load_lds(
        (const __attribute__((address_space(1))) unsigned int*)g,
        (__attribute__((address_space(3))) unsigned int*)l,
        16, 0, 0);
}

__device__ __forceinline__ void bar8() {      // raw barrier + compiler fences
    asm volatile("" ::: "memory");
    __builtin_amdgcn_s_barrier();
    asm volatile("" ::: "memory");
}

// ---------------------------------------------------------------------------
// gemm8: 256x256 / BK=64 8-phase-class GEMM (bank-conflict-free, proven r9).
// Used for LOGITS only (grid 1000). New: coalesced f32x4 epilogue via LDS
// transpose (per-wave region in dead sA): 16 lanes -> 256B contiguous/row.
// ---------------------------------------------------------------------------
template<int EPI>
__global__ __launch_bounds__(512)
void gemm8_k(const u16* __restrict__ A, int K,
             const u16* __restrict__ W, int N,
             float* __restrict__ Of, u16* __restrict__ Ob)
{
    constexpr int TS = 256 * 64;            // u16 per tile buffer (32 KB)
    __shared__ u16 sA[2 * TS];              // 64 KB
    __shared__ u16 sB[2 * TS];              // 64 KB

    const int tid = threadIdx.x;
    const int lane = tid & 63, wv = tid >> 6;        // 8 waves
    const int wm = wv >> 2, wn = wv & 3;             // 2 x 4
    const int l15 = lane & 15, lhi = lane >> 4;

    // bijective XCD swizzle (grid % 8 == 0)
    const int nwg = gridDim.x;
    const int q8 = nwg >> 3;
    const int xcd = blockIdx.x & 7, off8 = blockIdx.x >> 3;
    const int wgid = xcd * q8 + off8;
    const int tM = wgid & 7, tN = wgid >> 3;         // M_/256 == 8

    const u16* Abase = A + (size_t)(tM * 256) * K;
    const u16* Wbase = W + (size_t)(tN * 256) * K;

    // staging lane geometry: chunk = 8 rows x 64 cols = 1 KB per wave-instr
    const int srow8 = lane >> 3;            // row within chunk (= row & 7)
    const int sp    = lane & 7;             // physical 16B slot
    const int scol  = (sp ^ srow8) * 8;     // pre-swizzled global col (elems)

    auto stage = [&](const u16* gbase, int t2, int h, u16* dst) {
        const u16* g = gbase + (size_t)(h * 128) * K + (t2 << 6);
        u16* d = dst + h * 8192;
#pragma unroll
        for (int i = 0; i < 2; ++i) {
            int c = wv * 2 + i;                      // 0..15
            int row = c * 8 + srow8;                 // 0..127
            gl_lds16(g + (size_t)row * K + scol, d + c * 512);
        }
    };

    f32x4 acc[8][4];
#pragma unroll
    for (int i = 0; i < 8; ++i)
#pragma unroll
        for (int j = 0; j < 4; ++j) acc[i][j] = f32x4{0.f, 0.f, 0.f, 0.f};

    const int nt = K >> 6;                  // K-tiles of 64
    stage(Abase, 0, 0, sA); stage(Abase, 0, 1, sA);
    stage(Wbase, 0, 0, sB); stage(Wbase, 0, 1, sB);
    if (nt > 1) {
        stage(Wbase, 1, 0, sB + TS); stage(Wbase, 1, 1, sB + TS);
        asm volatile("s_waitcnt vmcnt(4)" ::: "memory");
    } else {
        asm volatile("s_waitcnt vmcnt(0)" ::: "memory");
    }
    bar8();

    for (int t = 0; t < nt; ++t) {
        const int cur = t & 1;
        const u16* sa = sA + cur * TS;
        const u16* sb = sB + cur * TS;
        u16* saN = sA + (cur ^ 1) * TS;     // A(t+1)
        u16* sbN = sB + cur * TS;           // B(t+2): same parity as t

        bf16x8 breg[4][2];

#pragma unroll
        for (int p = 0; p < 4; ++p) {
            if (p == 0) {
#pragma unroll
                for (int j = 0; j < 4; ++j)
#pragma unroll
                    for (int kk = 0; kk < 2; ++kk) {
                        int br = wn * 64 + j * 16 + l15;
                        int ls = kk * 4 + lhi;
                        breg[j][kk] = *(const bf16x8*)
                            &sb[br * 64 + ((ls ^ (br & 7)) * 8)];
                    }
            }
            bf16x8 areg[2][2];
#pragma unroll
            for (int mi = 0; mi < 2; ++mi)
#pragma unroll
                for (int kk = 0; kk < 2; ++kk) {
                    int ar = wm * 128 + (p * 2 + mi) * 16 + l15;
                    int ls = kk * 4 + lhi;
                    areg[mi][kk] = *(const bf16x8*)
                        &sa[ar * 64 + ((ls ^ (ar & 7)) * 8)];
                }

            if (p == 0 && t + 1 < nt) stage(Abase, t + 1, 0, saN);
            if (p == 1 && t + 1 < nt) stage(Abase, t + 1, 1, saN);
            if (p == 2 && t + 2 < nt) stage(Wbase, t + 2, 0, sbN);
            if (p == 3 && t + 2 < nt) stage(Wbase, t + 2, 1, sbN);

            if (p == 3 && t + 1 < nt) {
                if (t + 2 < nt) asm volatile("s_waitcnt vmcnt(4)" ::: "memory");
                else            asm volatile("s_waitcnt vmcnt(0)" ::: "memory");
            }

            bar8();
            asm volatile("s_waitcnt lgkmcnt(0)" ::: "memory");
            __builtin_amdgcn_s_setprio(1);
#pragma unroll
            for (int mi = 0; mi < 2; ++mi)
#pragma unroll
                for (int j = 0; j < 4; ++j)
#pragma unroll
                    for (int kk = 0; kk < 2; ++kk)
                        acc[p * 2 + mi][j] = __builtin_amdgcn_mfma_f32_16x16x32_bf16(
                            areg[mi][kk], breg[j][kk], acc[p * 2 + mi][j], 0, 0, 0);
            __builtin_amdgcn_s_setprio(0);
            bar8();
        }
    }

    if (EPI == 1) {
        // coalesced epilogue: per-wave LDS transpose (sA dead; pad-68 rows)
        float* sw = (float*)sA + wv * (16 * 68);     // 4.25 KB/wave, 34 KB total
        const int cc = l15;                          // col-chunk (f32x4)
#pragma unroll
        for (int i = 0; i < 8; ++i) {
#pragma unroll
            for (int j = 0; j < 4; ++j)
#pragma unroll
                for (int r = 0; r < 4; ++r)
                    sw[(lhi * 4 + r) * 68 + j * 16 + l15] = acc[i][j][r];
            // same-wave LDS write->read ordering handled by lgkmcnt deps
#pragma unroll
            for (int g = 0; g < 4; ++g) {
                int row = g * 4 + lhi;
                f32x4 v = *(const f32x4*)&sw[row * 68 + cc * 4];
                size_t gm = (size_t)tM * 256 + wm * 128 + i * 16 + row;
                size_t gn = (size_t)tN * 256 + wn * 64 + cc * 4;
                *(f32x4*)&Of[gm * (size_t)N + gn] = v;
            }
        }
    } else {   // EPI == 3 (unused this round, kept valid)
#pragma unroll
        for (int i = 0; i < 8; ++i)
#pragma unroll
            for (int j = 0; j < 4; ++j) {
                size_t gm = (size_t)tM * 256 + wm * 128 + i * 16 + lhi * 4;
                size_t gn = (size_t)tN * 256 + wn * 64 + j * 16 + l15;
#pragma unroll
                for (int r = 0; r < 4; ++r) {
                    float v = acc[i][j][r];
                    float b = __shfl_xor(v, 1);
                    if ((lane & 1) == 0) {
                        float s = v / (1.0f + expf(-v));
                        Ob[(gm + r) * (size_t)F_ + (gn >> 1)] = f2bf(s * b);
                    }
                }
            }
    }
}

// ---------------------------------------------------------------------------
// 2-phase double-buffered GEMM (proven): C[M,N]=A[M,K] x W[N,K]^T, bf16.
// EPI: 0 = bf16 store, 1 = f32 store, 2 = f32 +=,
//      3 = fused SiLU, 4 = fused RoPE + V-transpose
// ---------------------------------------------------------------------------
template<int BM, int BN, int EPI>
__global__ __launch_bounds__(256)
void gemm2_k(const u16* __restrict__ A, int K,
             const u16* __restrict__ W, int N,
             float* __restrict__ Of, u16* __restrict__ Ob,
             const float* __restrict__ tc, const float* __restrict__ ts)
{
    constexpr int FM = BM / 32;
    constexpr int FN = BN / 32;
    constexpr int GM = M_ / BM;
    constexpr int IPA = BM / 64;
    constexpr int IPB = BN / 64;
    __shared__ u16 sA[2 * BM * 32];
    __shared__ u16 sB[2 * BN * 32];

    const int tid  = threadIdx.x;
    const int lane = tid & 63, wv = tid >> 6;
    const int wm = wv >> 1, wn = wv & 1;
    const int l15 = lane & 15, lhi = lane >> 4;
    const int m0 = wm * (BM / 2), n0 = wn * (BN / 2);

    const int nwg = gridDim.x;
    const int q8 = nwg >> 3, r8 = nwg & 7;
    const int xcd = blockIdx.x & 7, off8 = blockIdx.x >> 3;
    const int wgid = (xcd < r8 ? xcd * (q8 + 1) : r8 * (q8 + 1) + (xcd - r8) * q8) + off8;
    const int tM = wgid % GM, tN = wgid / GM;

    const int srow = lane >> 2;
    const int scol = (lane & 3) * 8;

    const u16* Abase = A + (size_t)(tM * BM) * K;
    const u16* Wbase = W + (size_t)(tN * BN) * K;

    f32x4 acc[FM][FN];
#pragma unroll
    for (int i = 0; i < FM; ++i)
#pragma unroll
        for (int j = 0; j < FN; ++j) acc[i][j] = f32x4{0.f, 0.f, 0.f, 0.f};

    auto stage = [&](int kt, int buf) {
        u16* sa = sA + buf * (BM * 32);
        u16* sb = sB + buf * (BN * 32);
#pragma unroll
        for (int i = 0; i < IPA; ++i) {
            int c = wv * IPA + i;
            gl_lds16(Abase + (size_t)(c * 16 + srow) * K + kt + scol, sa + c * 512);
        }
#pragma unroll
        for (int i = 0; i < IPB; ++i) {
            int c = wv * IPB + i;
            gl_lds16(Wbase + (size_t)(c * 16 + srow) * K + kt + scol, sb + c * 512);
        }
    };

    const int nt = K >> 5;
    stage(0, 0);
    asm volatile("s_waitcnt vmcnt(0)" ::: "memory");
    __syncthreads();

    int cur = 0;
    for (int t = 0; t < nt; ++t) {
        if (t + 1 < nt) stage((t + 1) << 5, cur ^ 1);

        const u16* sa = sA + cur * (BM * 32);
        const u16* sb = sB + cur * (BN * 32);
        bf16x8 av[FM], bv[FN];
#pragma unroll
        for (int i = 0; i < FM; ++i)
            av[i] = *(const bf16x8*)&sa[(m0 + i * 16 + l15) * 32 + lhi * 8];
#pragma unroll
        for (int j = 0; j < FN; ++j)
            bv[j] = *(const bf16x8*)&sb[(n0 + j * 16 + l15) * 32 + lhi * 8];
#pragma unroll
        for (int i = 0; i < FM; ++i)
#pragma unroll
            for (int j = 0; j < FN; ++j)
                acc[i][j] = __builtin_amdgcn_mfma_f32_16x16x32_bf16(
                    av[i], bv[j], acc[i][j], 0, 0, 0);

        if (t + 1 < nt) {
            asm volatile("s_waitcnt vmcnt(0)" ::: "memory");
            __syncthreads();
            cur ^= 1;
        }
    }

#pragma unroll
    for (int i = 0; i < FM; ++i)
#pragma unroll
        for (int j = 0; j < FN; ++j) {
            size_t gm = (size_t)tM * BM + m0 + i * 16 + lhi * 4;
            size_t gn = (size_t)tN * BN + n0 + j * 16 + l15;
#pragma unroll
            for (int r = 0; r < 4; ++r) {
                float v = acc[i][j][r];
                size_t idx = (gm + r) * (size_t)N + gn;
                if (EPI == 0) {
                    Ob[idx] = f2bf(v);
                } else if (EPI == 1) {
                    Of[idx] = v;
                } else if (EPI == 2) {
                    Of[idx] += v;
                } else if (EPI == 3) {
                    float b = __shfl_xor(v, 1);
                    if ((lane & 1) == 0) {
                        float s = v / (1.0f + expf(-v));
                        Ob[(gm + r) * (size_t)F_ + (gn >> 1)] = f2bf(s * b);
                    }
                } else {   // EPI == 4: RoPE q/k; v cols -> transposed vt
                    float b = __shfl_xor(v, 1);
                    int gni = (int)gn;
                    int gmr = (int)(gm + r);
                    if (gni < 1280) {
                        int dd = gni & 63;
                        int jj = dd >> 1;
                        int tt = gmr & (T_ - 1);
                        float c = tc[tt * 32 + jj], s = ts[tt * 32 + jj];
                        float ro = ((dd & 1) == 0) ? (v * c - b * s) : (b * s + v * c);
                        Ob[idx] = f2bf(ro);
                    } else {
                        int vc = gni - 1280;              // 0..255
                        int hk = vc >> 6, dd = vc & 63;
                        int bb = gmr >> 10, tt = gmr & (T_ - 1);
                        ((u16*)Of)[((size_t)((bb * HK_ + hk) * DH_ + dd)) * T_ + tt] = f2bf(v);
                    }
                }
            }
        }
}

// f32 -> bf16 layer-strided conversion
__global__ __launch_bounds__(256)
void cvt_k(const float* __restrict__ src, u16* __restrict__ dst,
           unsigned long long sStride, unsigned long long dStride)
{
    int l = blockIdx.y;
    size_t i = ((size_t)blockIdx.x * 256 + threadIdx.x) * 4;
    f32x4 v = *(const f32x4*)(src + l * sStride + i);
    u16x4 o;
    o.x = f2bf(v.x); o.y = f2bf(v.y); o.z = f2bf(v.z); o.w = f2bf(v.w);
    *(u16x4*)(dst + l * dStride + i) = o;
}

// f32 -> bf16 with row interleave: src row f -> dst row 2f+off (rows of D_)
__global__ __launch_bounds__(256)
void cvt_il_k(const float* __restrict__ src, u16* __restrict__ dst,
              unsigned long long sStride, unsigned long long dStride, int off)
{
    int f = blockIdx.x, l = blockIdx.y;
    int i = threadIdx.x * 4;
    f32x4 v = *(const f32x4*)(src + l * sStride + (size_t)f * D_ + i);
    u16x4 o;
    o.x = f2bf(v.x); o.y = f2bf(v.y); o.z = f2bf(v.z); o.w = f2bf(v.w);
    *(u16x4*)(dst + l * dStride + (size_t)(2 * f + off) * D_ + i) = o;
}

// ---------------------------------------------------------------------------
// FALLBACK GEMM (round-1, proven): cast-in-staging, multi-W split.
// ---------------------------------------------------------------------------
template<int BM, int BN, int EPI, int NW>
__global__ __launch_bounds__(256)
void gemm_k(const u16* __restrict__ A, int K,
            const float* __restrict__ W0, const float* __restrict__ W1p,
            const float* __restrict__ W2p, int N0, int N1, int N,
            float* __restrict__ Of, u16* __restrict__ Ob)
{
    constexpr int FM = BM / 32;
    constexpr int FN = BN / 32;
    constexpr int LS = 40;
    __shared__ u16 sA[BM * LS];
    __shared__ u16 sB[BN * LS];

    const int tid  = threadIdx.x;
    const int lane = tid & 63, wv = tid >> 6;
    const int wm = wv >> 1, wn = wv & 1;
    const int l15 = lane & 15, lhi = lane >> 4;
    const int m0 = wm * (BM / 2), n0 = wn * (BN / 2);
    const int tM = blockIdx.y, tN = blockIdx.x;

    f32x4 acc[FM][FN];
#pragma unroll
    for (int i = 0; i < FM; ++i)
#pragma unroll
        for (int j = 0; j < FN; ++j) acc[i][j] = f32x4{0.f, 0.f, 0.f, 0.f};

    for (int kt = 0; kt < K; kt += 32) {
#pragma unroll
        for (int i = 0; i < BM / 64; ++i) {
            int cid = tid + i * 256;
            int row = cid >> 2, kc = cid & 3;
            const u16* src = A + (size_t)(tM * BM + row) * K + kt + kc * 8;
            *(u32x4*)&sA[row * LS + kc * 8] = *(const u32x4*)src;
        }
#pragma unroll
        for (int i = 0; i < BN / 32; ++i) {
            int cid = tid + i * 256;
            int row = cid >> 3, kc = cid & 7;
            int n = tN * BN + row;
            const float* wr;
            if (NW == 1)      wr = W0 + (size_t)n * K;
            else if (NW == 2) wr = (n < N0) ? (W0 + (size_t)n * K)
                                            : (W1p + (size_t)(n - N0) * K);
            else              wr = (n < N0) ? (W0 + (size_t)n * K)
                               : (n < N0 + N1) ? (W1p + (size_t)(n - N0) * K)
                                               : (W2p + (size_t)(n - N0 - N1) * K);
            f32x4 v = *(const f32x4*)(wr + kt + kc * 4);
            u16x4 o;
            o.x = f2bf(v.x); o.y = f2bf(v.y); o.z = f2bf(v.z); o.w = f2bf(v.w);
            *(u16x4*)&sB[row * LS + kc * 4] = o;
        }
        __syncthreads();

        bf16x8 av[FM], bv[FN];
#pragma unroll
        for (int i = 0; i < FM; ++i)
            av[i] = *(const bf16x8*)&sA[(m0 + i * 16 + l15) * LS + lhi * 8];
#pragma unroll
        for (int j = 0; j < FN; ++j)
            bv[j] = *(const bf16x8*)&sB[(n0 + j * 16 + l15) * LS + lhi * 8];
#pragma unroll
        for (int i = 0; i < FM; ++i)
#pragma unroll
            for (int j = 0; j < FN; ++j)
                acc[i][j] = __builtin_amdgcn_mfma_f32_16x16x32_bf16(
                    av[i], bv[j], acc[i][j], 0, 0, 0);
        __syncthreads();
    }

#pragma unroll
    for (int i = 0; i < FM; ++i)
#pragma unroll
        for (int j = 0; j < FN; ++j) {
            size_t gm = (size_t)tM * BM + m0 + i * 16 + lhi * 4;
            size_t gn = (size_t)tN * BN + n0 + j * 16 + l15;
#pragma unroll
            for (int r = 0; r < 4; ++r) {
                float v = acc[i][j][r];
                size_t idx = (gm + r) * (size_t)N + gn;
                if (EPI == 0)      Ob[idx] = f2bf(v);
                else if (EPI == 1) Of[idx] = v;
                else               Of[idx] += v;
            }
        }
}

// ---------------------------------------------------------------------------
// Flash attention v3: GQA-shared K/V staging (proven round 8).
// ---------------------------------------------------------------------------
__global__ __launch_bounds__(512)
void attn3_k(const u16* __restrict__ qkv, const u16* __restrict__ vt,
             u16* __restrict__ attn)
{
    const int qt = 31 - blockIdx.x;
    const int hk = blockIdx.y, b = blockIdx.z;
    const int tid = threadIdx.x;
    const int lane = tid & 63, w = tid >> 6;
    const int l15 = lane & 15, lhi = lane >> 4;
    const int h = hk * 4 + (w & 3);
    const int rg = w >> 2;

    __shared__ u16 sK[128 * 64];
    __shared__ u16 sVT[64 * 128];
    __shared__ u16 sP[8][16 * 136];

    const int q0 = qt * 32;
    const int qr0 = q0 + rg * 16;
    const u16* qptr = qkv + (size_t)(b * T_ + qr0 + l15) * 1536 + h * 64 + lhi * 8;
    bf16x8 aq0 = *(const bf16x8*)qptr;
    bf16x8 aq1 = *(const bf16x8*)(qptr + 32);

    f32x4 accO[4];
#pragma unroll
    for (int d = 0; d < 4; ++d) accO[d] = f32x4{0.f, 0.f, 0.f, 0.f};
    float m_r[4] = {-1e30f, -1e30f, -1e30f, -1e30f};
    float l_r[4] = {0.f, 0.f, 0.f, 0.f};
    const int myq = qr0 + lhi * 4;
    const int qmaxw = qr0 + 15;
    u16* sPw = sP[w];

    const int ntiles = (qt >> 2) + 1;
    const u16* vtb = vt + (size_t)((b * HK_ + hk) * DH_) * T_;
    const int L = lane;

    for (int kt = 0; kt < ntiles; ++kt) {
        const int t0 = kt * 128;
#pragma unroll
        for (int i = 0; i < 2; ++i) {
            int c = w * 2 + i;
            int row = c * 8 + (L >> 3);
            int p = L & 7;
            const u16* src = qkv + (size_t)(b * T_ + t0 + row) * 1536 + 1024 + hk * 64
                             + ((p ^ (row & 7)) * 8);
            gl_lds16(src, sK + c * 512);
        }
#pragma unroll
        for (int i = 0; i < 2; ++i) {
            int c = w * 2 + i;
            int row = c * 4 + (L >> 4);
            int p = L & 15;
            const u16* src = vtb + (size_t)row * T_ + t0 + ((p ^ (row & 15)) * 8);
            gl_lds16(src, sVT + c * 512);
        }
        asm volatile("s_waitcnt vmcnt(0)" ::: "memory");
        __syncthreads();

        const bool lastt = (kt == ntiles - 1);

        f32x4 accS[8];
#pragma unroll
        for (int nf = 0; nf < 8; ++nf)
            accS[nf] = f32x4{-1e30f, -1e30f, -1e30f, -1e30f};
#pragma unroll
        for (int pk = 0; pk < 4; ++pk) {
            if (t0 + pk * 32 > qmaxw) continue;
            f32x4 s0 = f32x4{0.f, 0.f, 0.f, 0.f};
            f32x4 s1 = f32x4{0.f, 0.f, 0.f, 0.f};
#pragma unroll
            for (int kk = 0; kk < 2; ++kk) {
                bf16x8 aqs = kk ? aq1 : aq0;
                int r0 = (pk * 2) * 16 + l15;
                int r1 = (pk * 2 + 1) * 16 + l15;
                int ls = kk * 4 + lhi;
                bf16x8 b0 = *(const bf16x8*)&sK[r0 * 64 + ((ls ^ (r0 & 7)) * 8)];
                bf16x8 b1 = *(const bf16x8*)&sK[r1 * 64 + ((ls ^ (r1 & 7)) * 8)];
                s0 = __builtin_amdgcn_mfma_f32_16x16x32_bf16(aqs, b0, s0, 0, 0, 0);
                s1 = __builtin_amdgcn_mfma_f32_16x16x32_bf16(aqs, b1, s1, 0, 0, 0);
            }
#pragma unroll
            for (int r = 0; r < 4; ++r) {
                float v0 = s0[r] * SCALE_;
                float v1 = s1[r] * SCALE_;
                if (lastt) {
                    int kp0 = t0 + (pk * 2) * 16 + l15;
                    int kp1 = kp0 + 16;
                    if (kp0 > myq + r) v0 = -1e30f;
                    if (kp1 > myq + r) v1 = -1e30f;
                }
                accS[pk * 2][r] = v0;
                accS[pk * 2 + 1][r] = v1;
            }
        }

        float sc[4];
#pragma unroll
        for (int r = 0; r < 4; ++r) {
            float mx = accS[0][r];
#pragma unroll
            for (int nf = 1; nf < 8; ++nf) mx = fmaxf(mx, accS[nf][r]);
#pragma unroll
            for (int off = 1; off < 16; off <<= 1) mx = fmaxf(mx, __shfl_xor(mx, off));
            float mn = fmaxf(m_r[r], mx);
            sc[r] = expf(m_r[r] - mn);
            m_r[r] = mn;
        }
        float rs[4] = {0.f, 0.f, 0.f, 0.f};
#pragma unroll
        for (int pk = 0; pk < 4; ++pk) {
            if (t0 + pk * 32 > qmaxw) continue;
#pragma unroll
            for (int g = 0; g < 2; ++g) {
                int nf = pk * 2 + g;
#pragma unroll
                for (int r = 0; r < 4; ++r) {
                    float p = expf(accS[nf][r] - m_r[r]);
                    accS[nf][r] = p;
                    rs[r] += p;
                }
            }
        }
#pragma unroll
        for (int r = 0; r < 4; ++r) {
#pragma unroll
            for (int off = 1; off < 16; off <<= 1) rs[r] += __shfl_xor(rs[r], off);
            l_r[r] = l_r[r] * sc[r] + rs[r];
        }
#pragma unroll
        for (int d = 0; d < 4; ++d)
#pragma unroll
            for (int r = 0; r < 4; ++r) accO[d][r] *= sc[r];

#pragma unroll
        for (int pk = 0; pk < 4; ++pk) {
            if (t0 + pk * 32 > qmaxw) continue;
#pragma unroll
            for (int g = 0; g < 2; ++g) {
                int nf = pk * 2 + g;
#pragma unroll
                for (int r = 0; r < 4; ++r)
                    sPw[(lhi * 4 + r) * 136 + nf * 16 + l15] = f2bf(accS[nf][r]);
            }
        }

#pragma unroll
        for (int kk = 0; kk < 4; ++kk) {
            if (t0 + kk * 32 > qmaxw) continue;
            bf16x8 pas = *(const bf16x8*)&sPw[l15 * 136 + kk * 32 + lhi * 8];
#pragma unroll
            for (int nf = 0; nf < 4; ++nf) {
                int row = nf * 16 + l15;
                int ls = kk * 4 + lhi;
                bf16x8 bvv = *(const bf16x8*)&sVT[row * 128 + ((ls ^ (row & 15)) * 8)];
                accO[nf] = __builtin_amdgcn_mfma_f32_16x16x32_bf16(pas, bvv, accO[nf], 0, 0, 0);
            }
        }
        __syncthreads();
    }

#pragma unroll
    for (int d = 0; d < 4; ++d)
#pragma unroll
        for (int r = 0; r < 4; ++r) {
            int row = qr0 + lhi * 4 + r;
            float o = accO[d][r] / l_r[r];
            attn[(size_t)(b * T_ + row) * 1024 + h * 64 + d * 16 + l15] = f2bf(o);
        }
}

// ---------------------------------------------------------------------------
// FALLBACK attention (round-1 proven)
// ---------------------------------------------------------------------------
__global__ __launch_bounds__(256)
void attn_k(const u16* __restrict__ qkv, u16* __restrict__ attn)
{
    const int qt = blockIdx.x, h = blockIdx.y, b = blockIdx.z;
    const int hk = h >> 2;
    const int tid = threadIdx.x;
    const int lane = tid & 63, w = tid >> 6;
    const int l15 = lane & 15, lhi = lane >> 4;
    __shared__ u16 sK[64 * 72];
    __shared__ u16 sVT[64 * 74];
    __shared__ u16 sP[4 * 16 * 72];

    const int q0 = qt * 64;
    const u16* qptr = qkv + (size_t)(b * T_ + q0 + w * 16 + l15) * 1536 + h * 64 + lhi * 8;
    bf16x8 aq0 = *(const bf16x8*)qptr;
    bf16x8 aq1 = *(const bf16x8*)(qptr + 32);

    f32x4 accO[4];
#pragma unroll
    for (int d = 0; d < 4; ++d) accO[d] = f32x4{0.f, 0.f, 0.f, 0.f};
    float m_r[4] = {-1e30f, -1e30f, -1e30f, -1e30f};
    float l_r[4] = {0.f, 0.f, 0.f, 0.f};
    const int myq = q0 + w * 16 + lhi * 4;
    u16* sPw = sP + w * 16 * 72;

    for (int kt = 0; kt <= qt; ++kt) {
#pragma unroll
        for (int i = 0; i < 2; ++i) {
            int cid = tid + i * 256;
            int r = cid >> 3, kc = cid & 7;
            const u16* src = qkv + (size_t)(b * T_ + kt * 64 + r) * 1536 + 1024 + hk * 64 + kc * 8;
            *(u32x4*)&sK[r * 72 + kc * 8] = *(const u32x4*)src;
        }
#pragma unroll
        for (int i = 0; i < 2; ++i) {
            int cid = tid + i * 256;
            int tt = cid >> 3, dc = cid & 7;
            const u16* src = qkv + (size_t)(b * T_ + kt * 64 + tt) * 1536 + 1280 + hk * 64 + dc * 8;
            bf16x8 vv = *(const bf16x8*)src;
#pragma unroll
            for (int j = 0; j < 8; ++j) sVT[(dc * 8 + j) * 74 + tt] = (u16)vv[j];
        }
        __syncthreads();

        f32x4 accS[4];
#pragma unroll
        for (int nf = 0; nf < 4; ++nf) accS[nf] = f32x4{0.f, 0.f, 0.f, 0.f};
#pragma unroll
        for (int s = 0; s < 2; ++s) {
            bf16x8 aqs = s ? aq1 : aq0;
#pragma unroll
            for (int nf = 0; nf < 4; ++nf) {
                bf16x8 bk = *(const bf16x8*)&sK[(nf * 16 + l15) * 72 + s * 32 + lhi * 8];
                accS[nf] = __builtin_amdgcn_mfma_f32_16x16x32_bf16(aqs, bk, accS[nf], 0, 0, 0);
            }
        }
#pragma unroll
        for (int nf = 0; nf < 4; ++nf)
#pragma unroll
            for (int r = 0; r < 4; ++r) {
                float v = accS[nf][r] * SCALE_;
                if (kt == qt) {
                    int kp = kt * 64 + nf * 16 + l15;
                    if (kp > myq + r) v = -1e30f;
                }
                accS[nf][r] = v;
            }
        float sc[4];
#pragma unroll
        for (int r = 0; r < 4; ++r) {
            float mx = fmaxf(fmaxf(accS[0][r], accS[1][r]), fmaxf(accS[2][r], accS[3][r]));
#pragma unroll
            for (int off = 1; off < 16; off <<= 1) mx = fmaxf(mx, __shfl_xor(mx, off));
            float mn = fmaxf(m_r[r], mx);
            sc[r] = expf(m_r[r] - mn);
            m_r[r] = mn;
        }
        float rs[4] = {0.f, 0.f, 0.f, 0.f};
#pragma unroll
        for (int nf = 0; nf < 4; ++nf)
#pragma unroll
            for (int r = 0; r < 4; ++r) {
                float p = expf(accS[nf][r] - m_r[r]);
                accS[nf][r] = p;
                rs[r] += p;
            }
#pragma unroll
        for (int r = 0; r < 4; ++r) {
#pragma unroll
            for (int off = 1; off < 16; off <<= 1) rs[r] += __shfl_xor(rs[r], off);
            l_r[r] = l_r[r] * sc[r] + rs[r];
        }
#pragma unroll
        for (int d = 0; d < 4; ++d)
#pragma unroll
            for (int r = 0; r < 4; ++r) accO[d][r] *= sc[r];

#pragma unroll
        for (int nf = 0; nf < 4; ++nf)
#pragma unroll
            for (int r = 0; r < 4; ++r)
                sPw[(lhi * 4 + r) * 72 + nf * 16 + l15] = f2bf(accS[nf][r]);
        bf16x8 pa0 = *(const bf16x8*)&sPw[l15 * 72 + lhi * 8];
        bf16x8 pa1 = *(const bf16x8*)&sPw[l15 * 72 + 32 + lhi * 8];
#pragma unroll
        for (int s = 0; s < 2; ++s) {
            bf16x8 pas = s ? pa1 : pa0;
#pragma unroll
            for (int d = 0; d < 4; ++d) {
                bf16x8 bvv = *(const bf16x8*)&sVT[(d * 16 + l15) * 74 + s * 32 + lhi * 8];
                accO[d] = __builtin_amdgcn_mfma_f32_16x16x32_bf16(pas, bvv, accO[d], 0, 0, 0);
            }
        }
        __syncthreads();
    }

#pragma unroll
    for (int d = 0; d < 4; ++d)
#pragma unroll
        for (int r = 0; r < 4; ++r) {
            int row = q0 + w * 16 + lhi * 4 + r;
            float o = accO[d][r] / l_r[r];
            attn[(size_t)(b * T_ + row) * 1024 + h * 64 + d * 16 + l15] = f2bf(o);
        }
}

// ---------------------------------------------------------------------------
// Small elementwise kernels
// ---------------------------------------------------------------------------
__global__ __launch_bounds__(256)
void gather_k(const int* __restrict__ ids, const float* __restrict__ emb,
              float* __restrict__ x)
{
    int m = blockIdx.x, tid = threadIdx.x;
    int id = ids[m];
    *(f32x4*)(x + (size_t)m * D_ + tid * 4) =
        *(const f32x4*)(emb + (size_t)id * D_ + tid * 4);
}

__global__ __launch_bounds__(256)
void rmsnorm_k(const float* __restrict__ x, const float* __restrict__ g,
               u16* __restrict__ out)
{
    const int row = blockIdx.x, tid = threadIdx.x;
    const float* xr = x + (size_t)row * D_;
    f32x4 v = *(const f32x4*)(xr + tid * 4);
    float ss = v.x * v.x + v.y * v.y + v.z * v.z + v.w * v.w;
#pragma unroll
    for (int off = 32; off >= 1; off >>= 1) ss += __shfl_xor(ss, off);
    __shared__ float red[4];
    if ((tid & 63) == 0) red[tid >> 6] = ss;
    __syncthreads();
    float tot = red[0] + red[1] + red[2] + red[3];
    float rr = rsqrtf(tot * (1.0f / D_) + 1e-6f);
    f32x4 wv = *(const f32x4*)(g + tid * 4);
    u16x4 o;
    o.x = f2bf(v.x * rr * wv.x); o.y = f2bf(v.y * rr * wv.y);
    o.z = f2bf(v.z * rr * wv.z); o.w = f2bf(v.w * rr * wv.w);
    *(u16x4*)(out + (size_t)row * D_ + tid * 4) = o;
}

// cos/sin tables: tab[t*32 + j] = cos/sin(t * theta^(-j/32))
__global__ __launch_bounds__(256)
void rope_tab_k(float* __restrict__ tc, float* __restrict__ ts)
{
    int idx = blockIdx.x * 256 + threadIdx.x;
    int t = idx >> 5, j = idx & 31;
    float inv = powf(10000.0f, -(float)j * (1.0f / 32.0f));
    float ang = (float)t * inv;
    tc[idx] = cosf(ang);
    ts[idx] = sinf(ang);
}

// f32-silu (fallback path)
__global__ __launch_bounds__(256)
void silu_f32_k(const float* __restrict__ h13, u16* __restrict__ hh)
{
    int m = blockIdx.y;
    int f = blockIdx.x * 256 + threadIdx.x;
    float a = h13[(size_t)m * (2 * F_) + f];
    float c = h13[(size_t)m * (2 * F_) + F_ + f];
    float s = a / (1.0f + expf(-a));
    hh[(size_t)m * F_ + f] = f2bf(s * c);
}

__global__ __launch_bounds__(640)
void rope_slow_k(u16* __restrict__ qkv)
{
    int m = blockIdx.x;
    int c2 = threadIdx.x;
    int col = (c2 < 512) ? (c2 * 2) : (1024 + (c2 - 512) * 2);
    int d = col & 63;
    int t = m & (T_ - 1);
    float ang = (float)t * powf(10000.0f, -(float)d / 64.0f);
    float cs = cosf(ang), sn = sinf(ang);
    u16* p = qkv + (size_t)m * 1536 + col;
    float x0 = bf2f(p[0]), x1 = bf2f(p[1]);
    p[0] = f2bf(x0 * cs - x1 * sn);
    p[1] = f2bf(x0 * sn + x1 * cs);
}

// ---------------------------------------------------------------------------
extern "C" void kernel_launch(void* const* d_in, const int* in_sizes, int n_in,
                              void* d_out, int out_size, void* d_ws, size_t ws_size,
                              hipStream_t stream)
{
    const int*   ids = (const int*)d_in[0];
    const float* emb = (const float*)d_in[1];
    const float* qw  = (const float*)d_in[2];
    const float* kw  = (const float*)d_in[3];
    const float* vw  = (const float*)d_in[4];
    const float* ow  = (const float*)d_in[5];
    const float* w1  = (const float*)d_in[6];
    const float* w2  = (const float*)d_in[7];
    const float* w3  = (const float*)d_in[8];
    const float* n1  = (const float*)d_in[9];
    const float* n2  = (const float*)d_in[10];
    const float* nfw = (const float*)d_in[11];
    float* out = (float*)d_out;
    char*  ws  = (char*)d_ws;

    // ---- workspace layout ----
    float* x    = (float*)(ws);                    //  8 MB residual f32
    u16*   xn   = (u16*)(ws + 8388608ULL);         //  4 MB normed acts
    u16*   qkvb = (u16*)(ws + 12582912ULL);        //  6 MB fused qkv
    u16*   attnb= (u16*)(ws + 18874368ULL);        //  4 MB attn out
    u16*   hh   = (u16*)(ws + 46137344ULL);        // 11 MB silu(h1)*h3
    float* ropec= (float*)(ws + 57671680ULL);      // 128 KB
    float* ropes= (float*)(ws + 57802752ULL);      // 128 KB
    u16*   embb = (u16*)(ws + 57933824ULL);        // 62.5 MB
    u16*   wqkv = (u16*)(ws + 123469824ULL);       // 24 MB
    u16*   wob  = (u16*)(ws + 148635648ULL);       // 16 MB
    u16*   w13b = (u16*)(ws + 165412864ULL);       // 88 MB (w1/w3 row-interleaved)
    u16*   w2b  = (u16*)(ws + 257687552ULL);       // 44 MB
    u16*   vtb  = (u16*)(ws + 303824896ULL);       //  1 MB V^T
    const unsigned long long NEED = 304873472ULL;

    if (ws_size >= NEED) {
        cvt_k<<<dim3(32000, 1), 256, 0, stream>>>(emb, embb, 0, 0);
        cvt_k<<<dim3(1024, L_), 256, 0, stream>>>(qw, wqkv,            1048576ULL, 1572864ULL);
        cvt_k<<<dim3(256,  L_), 256, 0, stream>>>(kw, wqkv + 1048576,  262144ULL,  1572864ULL);
        cvt_k<<<dim3(256,  L_), 256, 0, stream>>>(vw, wqkv + 1310720,  262144ULL,  1572864ULL);
        cvt_k<<<dim3(1024, L_), 256, 0, stream>>>(ow, wob,             1048576ULL, 1048576ULL);
        cvt_il_k<<<dim3(2816, L_), 256, 0, stream>>>(w1, w13b, 2883584ULL, 5767168ULL, 0);
        cvt_il_k<<<dim3(2816, L_), 256, 0, stream>>>(w3, w13b, 2883584ULL, 5767168ULL, 1);
        cvt_k<<<dim3(2816, L_), 256, 0, stream>>>(w2, w2b,             2883584ULL, 2883584ULL);
        rope_tab_k<<<T_ * 32 / 256, 256, 0, stream>>>(ropec, ropes);

        gather_k<<<M_, 256, 0, stream>>>(ids, emb, x);

        for (int l = 0; l < L_; ++l) {
            rmsnorm_k<<<M_, 256, 0, stream>>>(x, n1 + l * D_, xn);
            // fused QKV + RoPE + V-transpose (v cols -> vtb, not qkvb)
            gemm2_k<64, 64, 4><<<32 * 24, 256, 0, stream>>>(
                xn, D_, wqkv + (size_t)l * 1572864, 1536, (float*)vtb, qkvb, ropec, ropes);
            attn3_k<<<dim3(32, HK_, B_), 512, 0, stream>>>(qkvb, vtb, attnb);
            gemm2_k<64, 64, 2><<<32 * 16, 256, 0, stream>>>(
                attnb, D_, wob + (size_t)l * 1048576, 1024, x, nullptr, nullptr, nullptr);
            rmsnorm_k<<<M_, 256, 0, stream>>>(x, n2 + l * D_, xn);
            // fused W1||W3 (interleaved) + SiLU -> hh  (proven 2-phase, grid 704)
            gemm2_k<128, 128, 3><<<16 * 44, 256, 0, stream>>>(
                xn, D_, w13b + (size_t)l * 5767168, 5632, nullptr, hh, nullptr, nullptr);
            gemm2_k<64, 64, 2><<<32 * 16, 256, 0, stream>>>(
                hh, F_, w2b + (size_t)l * 2883584, 1024, x, nullptr, nullptr, nullptr);
        }

        rmsnorm_k<<<M_, 256, 0, stream>>>(x, nfw, xn);
        // logits: 8-phase 256^2, coalesced f32x4 epilogue
        gemm8_k<1><<<8 * 125, 512, 0, stream>>>(
            xn, D_, embb, V_, out, nullptr);
        return;
    }

    // ---------------- fallback: round-1 proven path ----------------
    float* h13f = (float*)(ws + 23068672ULL);
    u16*   hhf  = (u16*)(ws + 69206016ULL);
    gather_k<<<M_, 256, 0, stream>>>(ids, emb, x);

    for (int l = 0; l < L_; ++l) {
        rmsnorm_k<<<M_, 256, 0, stream>>>(x, n1 + l * D_, xn);
        gemm_k<128, 64, 0, 3><<<dim3(24, 16), 256, 0, stream>>>(
            xn, D_,
            qw + (size_t)l * H_ * DH_ * D_,
            kw + (size_t)l * HK_ * DH_ * D_,
            vw + (size_t)l * HK_ * DH_ * D_,
            1024, 256, 1536, nullptr, qkvb);
        rope_slow_k<<<M_, 640, 0, stream>>>(qkvb);
        attn_k<<<dim3(T_ / 64, H_, B_), 256, 0, stream>>>(qkvb, attnb);
        gemm_k<128, 64, 2, 1><<<dim3(16, 16), 256, 0, stream>>>(
            attnb, D_, ow + (size_t)l * D_ * D_, nullptr, nullptr,
            0, 0, D_, x, nullptr);
        rmsnorm_k<<<M_, 256, 0, stream>>>(x, n2 + l * D_, xn);
        gemm_k<128, 128, 1, 2><<<dim3(44, 16), 256, 0, stream>>>(
            xn, D_, w1 + (size_t)l * F_ * D_, w3 + (size_t)l * F_ * D_, nullptr,
            F_, 0, 2 * F_, h13f, nullptr);
        silu_f32_k<<<dim3(11, M_), 256, 0, stream>>>(h13f, hhf);
        gemm_k<128, 64, 2, 1><<<dim3(16, 16), 256, 0, stream>>>(
            hhf, F_, w2 + (size_t)l * D_ * F_, nullptr, nullptr,
            0, 0, D_, x, nullptr);
    }

    rmsnorm_k<<<M_, 256, 0, stream>>>(x, nfw, xn);
    gemm_k<128, 128, 1, 1><<<dim3(250, 16), 256, 0, stream>>>(
        xn, D_, emb, nullptr, nullptr, 0, 0, V_, out, nullptr);
}

// Round 11
// 1719.316 us; speedup vs baseline: 1.1342x; 1.0508x over previous
//
#include <hip/hip_runtime.h>
#include <math.h>

#define L_ 8
#define D_ 1024
#define H_ 16
#define HK_ 4
#define DH_ 64
#define F_ 2816
#define V_ 32000
#define T_ 1024
#define B_ 2
#define M_ (B_*T_)          // 2048 tokens
#define SCALE_ 0.125f       // DH^-0.5

typedef unsigned short u16;
typedef unsigned int   u32;
typedef __attribute__((ext_vector_type(4))) float  f32x4;
typedef __attribute__((ext_vector_type(8))) short  bf16x8;   // 8 bf16 = 4 VGPRs (MFMA A/B frag)
typedef __attribute__((ext_vector_type(4))) unsigned short u16x4;
typedef __attribute__((ext_vector_type(4))) unsigned int   u32x4;

__device__ __forceinline__ float bf2f(u16 h) {
    union { u32 u; float f; } v; v.u = ((u32)h) << 16; return v.f;
}
__device__ __forceinline__ u16 f2bf(float f) {   // round-to-nearest-even
    union { float f; u32 u; } v; v.f = f;
    u32 r = v.u + 0x7fffu + ((v.u >> 16) & 1u);
    return (u16)(r >> 16);
}

__device__ __forceinline__ void gl_lds16(const void* g, void* l) {
    __builtin_amdgcn_global_load_lds(
        (const __attribute__((address_space(1))) unsigned int*)g,
        (__attribute__((address_space(3))) unsigned int*)l,
        16, 0, 0);
}

__device__ __forceinline__ void bar8() {      // raw barrier + compiler fences
    asm volatile("" ::: "memory");
    __builtin_amdgcn_s_barrier();
    asm volatile("" ::: "memory");
}

// ---------------------------------------------------------------------------
// gemm8: 256x256 / BK=64 8-phase GEMM (bank-conflict-free, proven r9/r10).
// LOGITS only (grid 1000). Coalesced f32x4 epilogue via per-wave LDS.
// ---------------------------------------------------------------------------
template<int EPI>
__global__ __launch_bounds__(512)
void gemm8_k(const u16* __restrict__ A, int K,
             const u16* __restrict__ W, int N,
             float* __restrict__ Of, u16* __restrict__ Ob)
{
    constexpr int TS = 256 * 64;            // u16 per tile buffer (32 KB)
    __shared__ u16 sA[2 * TS];              // 64 KB
    __shared__ u16 sB[2 * TS];              // 64 KB

    const int tid = threadIdx.x;
    const int lane = tid & 63, wv = tid >> 6;        // 8 waves
    const int wm = wv >> 2, wn = wv & 3;             // 2 x 4
    const int l15 = lane & 15, lhi = lane >> 4;

    const int nwg = gridDim.x;
    const int q8 = nwg >> 3;
    const int xcd = blockIdx.x & 7, off8 = blockIdx.x >> 3;
    const int wgid = xcd * q8 + off8;
    const int tM = wgid & 7, tN = wgid >> 3;         // M_/256 == 8

    const u16* Abase = A + (size_t)(tM * 256) * K;
    const u16* Wbase = W + (size_t)(tN * 256) * K;

    const int srow8 = lane >> 3;            // row within chunk
    const int sp    = lane & 7;             // physical 16B slot
    const int scol  = (sp ^ srow8) * 8;     // pre-swizzled global col (elems)

    auto stage = [&](const u16* gbase, int t2, int h, u16* dst) {
        const u16* g = gbase + (size_t)(h * 128) * K + (t2 << 6);
        u16* d = dst + h * 8192;
#pragma unroll
        for (int i = 0; i < 2; ++i) {
            int c = wv * 2 + i;                      // 0..15
            int row = c * 8 + srow8;                 // 0..127
            gl_lds16(g + (size_t)row * K + scol, d + c * 512);
        }
    };

    f32x4 acc[8][4];
#pragma unroll
    for (int i = 0; i < 8; ++i)
#pragma unroll
        for (int j = 0; j < 4; ++j) acc[i][j] = f32x4{0.f, 0.f, 0.f, 0.f};

    const int nt = K >> 6;
    stage(Abase, 0, 0, sA); stage(Abase, 0, 1, sA);
    stage(Wbase, 0, 0, sB); stage(Wbase, 0, 1, sB);
    if (nt > 1) {
        stage(Wbase, 1, 0, sB + TS); stage(Wbase, 1, 1, sB + TS);
        asm volatile("s_waitcnt vmcnt(4)" ::: "memory");
    } else {
        asm volatile("s_waitcnt vmcnt(0)" ::: "memory");
    }
    bar8();

    for (int t = 0; t < nt; ++t) {
        const int cur = t & 1;
        const u16* sa = sA + cur * TS;
        const u16* sb = sB + cur * TS;
        u16* saN = sA + (cur ^ 1) * TS;
        u16* sbN = sB + cur * TS;

        bf16x8 breg[4][2];

#pragma unroll
        for (int p = 0; p < 4; ++p) {
            if (p == 0) {
#pragma unroll
                for (int j = 0; j < 4; ++j)
#pragma unroll
                    for (int kk = 0; kk < 2; ++kk) {
                        int br = wn * 64 + j * 16 + l15;
                        int ls = kk * 4 + lhi;
                        breg[j][kk] = *(const bf16x8*)
                            &sb[br * 64 + ((ls ^ (br & 7)) * 8)];
                    }
            }
            bf16x8 areg[2][2];
#pragma unroll
            for (int mi = 0; mi < 2; ++mi)
#pragma unroll
                for (int kk = 0; kk < 2; ++kk) {
                    int ar = wm * 128 + (p * 2 + mi) * 16 + l15;
                    int ls = kk * 4 + lhi;
                    areg[mi][kk] = *(const bf16x8*)
                        &sa[ar * 64 + ((ls ^ (ar & 7)) * 8)];
                }

            if (p == 0 && t + 1 < nt) stage(Abase, t + 1, 0, saN);
            if (p == 1 && t + 1 < nt) stage(Abase, t + 1, 1, saN);
            if (p == 2 && t + 2 < nt) stage(Wbase, t + 2, 0, sbN);
            if (p == 3 && t + 2 < nt) stage(Wbase, t + 2, 1, sbN);

            if (p == 3 && t + 1 < nt) {
                if (t + 2 < nt) asm volatile("s_waitcnt vmcnt(4)" ::: "memory");
                else            asm volatile("s_waitcnt vmcnt(0)" ::: "memory");
            }

            bar8();
            asm volatile("s_waitcnt lgkmcnt(0)" ::: "memory");
            __builtin_amdgcn_s_setprio(1);
#pragma unroll
            for (int mi = 0; mi < 2; ++mi)
#pragma unroll
                for (int j = 0; j < 4; ++j)
#pragma unroll
                    for (int kk = 0; kk < 2; ++kk)
                        acc[p * 2 + mi][j] = __builtin_amdgcn_mfma_f32_16x16x32_bf16(
                            areg[mi][kk], breg[j][kk], acc[p * 2 + mi][j], 0, 0, 0);
            __builtin_amdgcn_s_setprio(0);
            bar8();
        }
    }

    if (EPI == 1) {
        float* sw = (float*)sA + wv * (16 * 68);
        const int cc = l15;
#pragma unroll
        for (int i = 0; i < 8; ++i) {
#pragma unroll
            for (int j = 0; j < 4; ++j)
#pragma unroll
                for (int r = 0; r < 4; ++r)
                    sw[(lhi * 4 + r) * 68 + j * 16 + l15] = acc[i][j][r];
#pragma unroll
            for (int g = 0; g < 4; ++g) {
                int row = g * 4 + lhi;
                f32x4 v = *(const f32x4*)&sw[row * 68 + cc * 4];
                size_t gm = (size_t)tM * 256 + wm * 128 + i * 16 + row;
                size_t gn = (size_t)tN * 256 + wn * 64 + cc * 4;
                *(f32x4*)&Of[gm * (size_t)N + gn] = v;
            }
        }
    } else {
#pragma unroll
        for (int i = 0; i < 8; ++i)
#pragma unroll
            for (int j = 0; j < 4; ++j) {
                size_t gm = (size_t)tM * 256 + wm * 128 + i * 16 + lhi * 4;
                size_t gn = (size_t)tN * 256 + wn * 64 + j * 16 + l15;
#pragma unroll
                for (int r = 0; r < 4; ++r) {
                    float v = acc[i][j][r];
                    float b = __shfl_xor(v, 1);
                    if ((lane & 1) == 0) {
                        float s = v / (1.0f + expf(-v));
                        Ob[(gm + r) * (size_t)F_ + (gn >> 1)] = f2bf(s * b);
                    }
                }
            }
    }
}

// ---------------------------------------------------------------------------
// 2-phase double-buffered GEMM (proven): C[M,N]=A[M,K] x W[N,K]^T, bf16.
// EPI: 0 = bf16 store, 1 = f32 store, 2 = f32 +=,
//      3 = fused SiLU, 4 = fused RoPE + V-transpose,
//      5 = split-K2 f32 partial store (Of[kh][M_][D_])
// ---------------------------------------------------------------------------
template<int BM, int BN, int EPI>
__global__ __launch_bounds__(256)
void gemm2_k(const u16* __restrict__ A, int K,
             const u16* __restrict__ W, int N,
             float* __restrict__ Of, u16* __restrict__ Ob,
             const float* __restrict__ tc, const float* __restrict__ ts)
{
    constexpr int FM = BM / 32;
    constexpr int FN = BN / 32;
    constexpr int GM = M_ / BM;
    constexpr int IPA = BM / 64;
    constexpr int IPB = BN / 64;
    __shared__ u16 sA[2 * BM * 32];
    __shared__ u16 sB[2 * BN * 32];

    const int tid  = threadIdx.x;
    const int lane = tid & 63, wv = tid >> 6;
    const int wm = wv >> 1, wn = wv & 1;
    const int l15 = lane & 15, lhi = lane >> 4;
    const int m0 = wm * (BM / 2), n0 = wn * (BN / 2);

    const int nwg = gridDim.x;
    const int q8 = nwg >> 3, r8 = nwg & 7;
    const int xcd = blockIdx.x & 7, off8 = blockIdx.x >> 3;
    const int wgid = (xcd < r8 ? xcd * (q8 + 1) : r8 * (q8 + 1) + (xcd - r8) * q8) + off8;

    int tM, tN, kh = 0, koff = 0, Klen = K;
    if (EPI == 5) {
        kh = wgid & 1;
        int wg2 = wgid >> 1;
        tM = wg2 % GM; tN = wg2 / GM;
        Klen = K >> 1; koff = kh * Klen;
    } else {
        tM = wgid % GM; tN = wgid / GM;
    }

    const int srow = lane >> 2;
    const int scol = (lane & 3) * 8;

    const u16* Abase = A + (size_t)(tM * BM) * K + koff;
    const u16* Wbase = W + (size_t)(tN * BN) * K + koff;

    f32x4 acc[FM][FN];
#pragma unroll
    for (int i = 0; i < FM; ++i)
#pragma unroll
        for (int j = 0; j < FN; ++j) acc[i][j] = f32x4{0.f, 0.f, 0.f, 0.f};

    auto stage = [&](int kt, int buf) {
        u16* sa = sA + buf * (BM * 32);
        u16* sb = sB + buf * (BN * 32);
#pragma unroll
        for (int i = 0; i < IPA; ++i) {
            int c = wv * IPA + i;
            gl_lds16(Abase + (size_t)(c * 16 + srow) * K + kt + scol, sa + c * 512);
        }
#pragma unroll
        for (int i = 0; i < IPB; ++i) {
            int c = wv * IPB + i;
            gl_lds16(Wbase + (size_t)(c * 16 + srow) * K + kt + scol, sb + c * 512);
        }
    };

    const int nt = Klen >> 5;
    stage(0, 0);
    asm volatile("s_waitcnt vmcnt(0)" ::: "memory");
    __syncthreads();

    int cur = 0;
    for (int t = 0; t < nt; ++t) {
        if (t + 1 < nt) stage((t + 1) << 5, cur ^ 1);

        const u16* sa = sA + cur * (BM * 32);
        const u16* sb = sB + cur * (BN * 32);
        bf16x8 av[FM], bv[FN];
#pragma unroll
        for (int i = 0; i < FM; ++i)
            av[i] = *(const bf16x8*)&sa[(m0 + i * 16 + l15) * 32 + lhi * 8];
#pragma unroll
        for (int j = 0; j < FN; ++j)
            bv[j] = *(const bf16x8*)&sb[(n0 + j * 16 + l15) * 32 + lhi * 8];
#pragma unroll
        for (int i = 0; i < FM; ++i)
#pragma unroll
            for (int j = 0; j < FN; ++j)
                acc[i][j] = __builtin_amdgcn_mfma_f32_16x16x32_bf16(
                    av[i], bv[j], acc[i][j], 0, 0, 0);

        if (t + 1 < nt) {
            asm volatile("s_waitcnt vmcnt(0)" ::: "memory");
            __syncthreads();
            cur ^= 1;
        }
    }

#pragma unroll
    for (int i = 0; i < FM; ++i)
#pragma unroll
        for (int j = 0; j < FN; ++j) {
            size_t gm = (size_t)tM * BM + m0 + i * 16 + lhi * 4;
            size_t gn = (size_t)tN * BN + n0 + j * 16 + l15;
#pragma unroll
            for (int r = 0; r < 4; ++r) {
                float v = acc[i][j][r];
                size_t idx = (gm + r) * (size_t)N + gn;
                if (EPI == 0) {
                    Ob[idx] = f2bf(v);
                } else if (EPI == 1) {
                    Of[idx] = v;
                } else if (EPI == 2) {
                    Of[idx] += v;
                } else if (EPI == 5) {
                    Of[(size_t)kh * (M_ * (size_t)D_) + idx] = v;
                } else if (EPI == 3) {
                    float b = __shfl_xor(v, 1);
                    if ((lane & 1) == 0) {
                        float s = v / (1.0f + expf(-v));
                        Ob[(gm + r) * (size_t)F_ + (gn >> 1)] = f2bf(s * b);
                    }
                } else {   // EPI == 4: RoPE q/k; v cols -> transposed vt
                    float b = __shfl_xor(v, 1);
                    int gni = (int)gn;
                    int gmr = (int)(gm + r);
                    if (gni < 1280) {
                        int dd = gni & 63;
                        int jj = dd >> 1;
                        int tt = gmr & (T_ - 1);
                        float c = tc[tt * 32 + jj], s = ts[tt * 32 + jj];
                        float ro = ((dd & 1) == 0) ? (v * c - b * s) : (b * s + v * c);
                        Ob[idx] = f2bf(ro);
                    } else {
                        int vc = gni - 1280;              // 0..255
                        int hk = vc >> 6, dd = vc & 63;
                        int bb = gmr >> 10, tt = gmr & (T_ - 1);
                        ((u16*)Of)[((size_t)((bb * HK_ + hk) * DH_ + dd)) * T_ + tt] = f2bf(v);
                    }
                }
            }
        }
}

// ---------------------------------------------------------------------------
// MEGA-PREP: all weight cvts + rope tables + gather in ONE dispatch.
// Segment bounds (blocks of 256 thr, 1024 elems each unless noted):
//  [0,32000) emb | [32000,40192) q | [40192,42240) k | [42240,44288) v
//  [44288,52480) ow | [52480,75008) w1-il | [75008,97536) w3-il
//  [97536,120064) w2 | [120064,122112) gather | [122112,122240) rope tab
// ---------------------------------------------------------------------------
__global__ __launch_bounds__(256)
void prep_k(const float* __restrict__ emb, const float* __restrict__ qw,
            const float* __restrict__ kw, const float* __restrict__ vw,
            const float* __restrict__ ow, const float* __restrict__ w1,
            const float* __restrict__ w2, const float* __restrict__ w3,
            const int* __restrict__ ids,
            u16* __restrict__ embb, u16* __restrict__ wqkv,
            u16* __restrict__ wob, u16* __restrict__ w13b,
            u16* __restrict__ w2b, float* __restrict__ x,
            float* __restrict__ tc, float* __restrict__ ts)
{
    const int bx = blockIdx.x, tid = threadIdx.x;
    const float* src = nullptr;
    u16* dst = nullptr;

    if (bx < 32000) {
        src = emb + (size_t)bx * 1024;           dst = embb + (size_t)bx * 1024;
    } else if (bx < 40192) {
        int lb = bx - 32000, l = lb >> 10, j = lb & 1023;
        src = qw + (size_t)l * 1048576 + j * 1024;
        dst = wqkv + (size_t)l * 1572864 + j * 1024;
    } else if (bx < 42240) {
        int lb = bx - 40192, l = lb >> 8, j = lb & 255;
        src = kw + (size_t)l * 262144 + j * 1024;
        dst = wqkv + (size_t)l * 1572864 + 1048576 + j * 1024;
    } else if (bx < 44288) {
        int lb = bx - 42240, l = lb >> 8, j = lb & 255;
        src = vw + (size_t)l * 262144 + j * 1024;
        dst = wqkv + (size_t)l * 1572864 + 1310720 + j * 1024;
    } else if (bx < 52480) {
        int lb = bx - 44288, l = lb >> 10, j = lb & 1023;
        src = ow + (size_t)l * 1048576 + j * 1024;
        dst = wob + (size_t)l * 1048576 + j * 1024;
    } else if (bx < 75008) {
        int lb = bx - 52480, l = lb / 2816, f = lb - l * 2816;
        src = w1 + (size_t)l * 2883584 + (size_t)f * 1024;
        dst = w13b + (size_t)l * 5767168 + (size_t)(2 * f) * 1024;
    } else if (bx < 97536) {
        int lb = bx - 75008, l = lb / 2816, f = lb - l * 2816;
        src = w3 + (size_t)l * 2883584 + (size_t)f * 1024;
        dst = w13b + (size_t)l * 5767168 + (size_t)(2 * f + 1) * 1024;
    } else if (bx < 120064) {
        int lb = bx - 97536, l = lb / 2816, f = lb - l * 2816;
        src = w2 + (size_t)l * 2883584 + (size_t)f * 1024;
        dst = w2b + (size_t)l * 2883584 + (size_t)f * 1024;
    } else if (bx < 122112) {
        int m = bx - 120064;
        int id = ids[m];
        *(f32x4*)(x + (size_t)m * D_ + tid * 4) =
            *(const f32x4*)(emb + (size_t)id * D_ + tid * 4);
        return;
    } else {
        int idx = (bx - 122112) * 256 + tid;     // T_*32 total
        int t = idx >> 5, j = idx & 31;
        float inv = powf(10000.0f, -(float)j * (1.0f / 32.0f));
        float ang = (float)t * inv;
        tc[idx] = cosf(ang);
        ts[idx] = sinf(ang);
        return;
    }
    f32x4 v = *(const f32x4*)(src + tid * 4);
    u16x4 o;
    o.x = f2bf(v.x); o.y = f2bf(v.y); o.z = f2bf(v.z); o.w = f2bf(v.w);
    *(u16x4*)(dst + tid * 4) = o;
}

// ---------------------------------------------------------------------------
// FALLBACK GEMM (round-1, proven): cast-in-staging, multi-W split.
// ---------------------------------------------------------------------------
template<int BM, int BN, int EPI, int NW>
__global__ __launch_bounds__(256)
void gemm_k(const u16* __restrict__ A, int K,
            const float* __restrict__ W0, const float* __restrict__ W1p,
            const float* __restrict__ W2p, int N0, int N1, int N,
            float* __restrict__ Of, u16* __restrict__ Ob)
{
    constexpr int FM = BM / 32;
    constexpr int FN = BN / 32;
    constexpr int LS = 40;
    __shared__ u16 sA[BM * LS];
    __shared__ u16 sB[BN * LS];

    const int tid  = threadIdx.x;
    const int lane = tid & 63, wv = tid >> 6;
    const int wm = wv >> 1, wn = wv & 1;
    const int l15 = lane & 15, lhi = lane >> 4;
    const int m0 = wm * (BM / 2), n0 = wn * (BN / 2);
    const int tM = blockIdx.y, tN = blockIdx.x;

    f32x4 acc[FM][FN];
#pragma unroll
    for (int i = 0; i < FM; ++i)
#pragma unroll
        for (int j = 0; j < FN; ++j) acc[i][j] = f32x4{0.f, 0.f, 0.f, 0.f};

    for (int kt = 0; kt < K; kt += 32) {
#pragma unroll
        for (int i = 0; i < BM / 64; ++i) {
            int cid = tid + i * 256;
            int row = cid >> 2, kc = cid & 3;
            const u16* src = A + (size_t)(tM * BM + row) * K + kt + kc * 8;
            *(u32x4*)&sA[row * LS + kc * 8] = *(const u32x4*)src;
        }
#pragma unroll
        for (int i = 0; i < BN / 32; ++i) {
            int cid = tid + i * 256;
            int row = cid >> 3, kc = cid & 7;
            int n = tN * BN + row;
            const float* wr;
            if (NW == 1)      wr = W0 + (size_t)n * K;
            else if (NW == 2) wr = (n < N0) ? (W0 + (size_t)n * K)
                                            : (W1p + (size_t)(n - N0) * K);
            else              wr = (n < N0) ? (W0 + (size_t)n * K)
                               : (n < N0 + N1) ? (W1p + (size_t)(n - N0) * K)
                                               : (W2p + (size_t)(n - N0 - N1) * K);
            f32x4 v = *(const f32x4*)(wr + kt + kc * 4);
            u16x4 o;
            o.x = f2bf(v.x); o.y = f2bf(v.y); o.z = f2bf(v.z); o.w = f2bf(v.w);
            *(u16x4*)&sB[row * LS + kc * 4] = o;
        }
        __syncthreads();

        bf16x8 av[FM], bv[FN];
#pragma unroll
        for (int i = 0; i < FM; ++i)
            av[i] = *(const bf16x8*)&sA[(m0 + i * 16 + l15) * LS + lhi * 8];
#pragma unroll
        for (int j = 0; j < FN; ++j)
            bv[j] = *(const bf16x8*)&sB[(n0 + j * 16 + l15) * LS + lhi * 8];
#pragma unroll
        for (int i = 0; i < FM; ++i)
#pragma unroll
            for (int j = 0; j < FN; ++j)
                acc[i][j] = __builtin_amdgcn_mfma_f32_16x16x32_bf16(
                    av[i], bv[j], acc[i][j], 0, 0, 0);
        __syncthreads();
    }

#pragma unroll
    for (int i = 0; i < FM; ++i)
#pragma unroll
        for (int j = 0; j < FN; ++j) {
            size_t gm = (size_t)tM * BM + m0 + i * 16 + lhi * 4;
            size_t gn = (size_t)tN * BN + n0 + j * 16 + l15;
#pragma unroll
            for (int r = 0; r < 4; ++r) {
                float v = acc[i][j][r];
                size_t idx = (gm + r) * (size_t)N + gn;
                if (EPI == 0)      Ob[idx] = f2bf(v);
                else if (EPI == 1) Of[idx] = v;
                else               Of[idx] += v;
            }
        }
}

// ---------------------------------------------------------------------------
// Flash attention v3: GQA-shared K/V staging (proven round 8).
// ---------------------------------------------------------------------------
__global__ __launch_bounds__(512)
void attn3_k(const u16* __restrict__ qkv, const u16* __restrict__ vt,
             u16* __restrict__ attn)
{
    const int qt = 31 - blockIdx.x;
    const int hk = blockIdx.y, b = blockIdx.z;
    const int tid = threadIdx.x;
    const int lane = tid & 63, w = tid >> 6;
    const int l15 = lane & 15, lhi = lane >> 4;
    const int h = hk * 4 + (w & 3);
    const int rg = w >> 2;

    __shared__ u16 sK[128 * 64];
    __shared__ u16 sVT[64 * 128];
    __shared__ u16 sP[8][16 * 136];

    const int q0 = qt * 32;
    const int qr0 = q0 + rg * 16;
    const u16* qptr = qkv + (size_t)(b * T_ + qr0 + l15) * 1536 + h * 64 + lhi * 8;
    bf16x8 aq0 = *(const bf16x8*)qptr;
    bf16x8 aq1 = *(const bf16x8*)(qptr + 32);

    f32x4 accO[4];
#pragma unroll
    for (int d = 0; d < 4; ++d) accO[d] = f32x4{0.f, 0.f, 0.f, 0.f};
    float m_r[4] = {-1e30f, -1e30f, -1e30f, -1e30f};
    float l_r[4] = {0.f, 0.f, 0.f, 0.f};
    const int myq = qr0 + lhi * 4;
    const int qmaxw = qr0 + 15;
    u16* sPw = sP[w];

    const int ntiles = (qt >> 2) + 1;
    const u16* vtb = vt + (size_t)((b * HK_ + hk) * DH_) * T_;
    const int L = lane;

    for (int kt = 0; kt < ntiles; ++kt) {
        const int t0 = kt * 128;
#pragma unroll
        for (int i = 0; i < 2; ++i) {
            int c = w * 2 + i;
            int row = c * 8 + (L >> 3);
            int p = L & 7;
            const u16* src = qkv + (size_t)(b * T_ + t0 + row) * 1536 + 1024 + hk * 64
                             + ((p ^ (row & 7)) * 8);
            gl_lds16(src, sK + c * 512);
        }
#pragma unroll
        for (int i = 0; i < 2; ++i) {
            int c = w * 2 + i;
            int row = c * 4 + (L >> 4);
            int p = L & 15;
            const u16* src = vtb + (size_t)row * T_ + t0 + ((p ^ (row & 15)) * 8);
            gl_lds16(src, sVT + c * 512);
        }
        asm volatile("s_waitcnt vmcnt(0)" ::: "memory");
        __syncthreads();

        const bool lastt = (kt == ntiles - 1);

        f32x4 accS[8];
#pragma unroll
        for (int nf = 0; nf < 8; ++nf)
            accS[nf] = f32x4{-1e30f, -1e30f, -1e30f, -1e30f};
#pragma unroll
        for (int pk = 0; pk < 4; ++pk) {
            if (t0 + pk * 32 > qmaxw) continue;
            f32x4 s0 = f32x4{0.f, 0.f, 0.f, 0.f};
            f32x4 s1 = f32x4{0.f, 0.f, 0.f, 0.f};
#pragma unroll
            for (int kk = 0; kk < 2; ++kk) {
                bf16x8 aqs = kk ? aq1 : aq0;
                int r0 = (pk * 2) * 16 + l15;
                int r1 = (pk * 2 + 1) * 16 + l15;
                int ls = kk * 4 + lhi;
                bf16x8 b0 = *(const bf16x8*)&sK[r0 * 64 + ((ls ^ (r0 & 7)) * 8)];
                bf16x8 b1 = *(const bf16x8*)&sK[r1 * 64 + ((ls ^ (r1 & 7)) * 8)];
                s0 = __builtin_amdgcn_mfma_f32_16x16x32_bf16(aqs, b0, s0, 0, 0, 0);
                s1 = __builtin_amdgcn_mfma_f32_16x16x32_bf16(aqs, b1, s1, 0, 0, 0);
            }
#pragma unroll
            for (int r = 0; r < 4; ++r) {
                float v0 = s0[r] * SCALE_;
                float v1 = s1[r] * SCALE_;
                if (lastt) {
                    int kp0 = t0 + (pk * 2) * 16 + l15;
                    int kp1 = kp0 + 16;
                    if (kp0 > myq + r) v0 = -1e30f;
                    if (kp1 > myq + r) v1 = -1e30f;
                }
                accS[pk * 2][r] = v0;
                accS[pk * 2 + 1][r] = v1;
            }
        }

        float sc[4];
#pragma unroll
        for (int r = 0; r < 4; ++r) {
            float mx = accS[0][r];
#pragma unroll
            for (int nf = 1; nf < 8; ++nf) mx = fmaxf(mx, accS[nf][r]);
#pragma unroll
            for (int off = 1; off < 16; off <<= 1) mx = fmaxf(mx, __shfl_xor(mx, off));
            float mn = fmaxf(m_r[r], mx);
            sc[r] = expf(m_r[r] - mn);
            m_r[r] = mn;
        }
        float rs[4] = {0.f, 0.f, 0.f, 0.f};
#pragma unroll
        for (int pk = 0; pk < 4; ++pk) {
            if (t0 + pk * 32 > qmaxw) continue;
#pragma unroll
            for (int g = 0; g < 2; ++g) {
                int nf = pk * 2 + g;
#pragma unroll
                for (int r = 0; r < 4; ++r) {
                    float p = expf(accS[nf][r] - m_r[r]);
                    accS[nf][r] = p;
                    rs[r] += p;
                }
            }
        }
#pragma unroll
        for (int r = 0; r < 4; ++r) {
#pragma unroll
            for (int off = 1; off < 16; off <<= 1) rs[r] += __shfl_xor(rs[r], off);
            l_r[r] = l_r[r] * sc[r] + rs[r];
        }
#pragma unroll
        for (int d = 0; d < 4; ++d)
#pragma unroll
            for (int r = 0; r < 4; ++r) accO[d][r] *= sc[r];

#pragma unroll
        for (int pk = 0; pk < 4; ++pk) {
            if (t0 + pk * 32 > qmaxw) continue;
#pragma unroll
            for (int g = 0; g < 2; ++g) {
                int nf = pk * 2 + g;
#pragma unroll
                for (int r = 0; r < 4; ++r)
                    sPw[(lhi * 4 + r) * 136 + nf * 16 + l15] = f2bf(accS[nf][r]);
            }
        }

#pragma unroll
        for (int kk = 0; kk < 4; ++kk) {
            if (t0 + kk * 32 > qmaxw) continue;
            bf16x8 pas = *(const bf16x8*)&sPw[l15 * 136 + kk * 32 + lhi * 8];
#pragma unroll
            for (int nf = 0; nf < 4; ++nf) {
                int row = nf * 16 + l15;
                int ls = kk * 4 + lhi;
                bf16x8 bvv = *(const bf16x8*)&sVT[row * 128 + ((ls ^ (row & 15)) * 8)];
                accO[nf] = __builtin_amdgcn_mfma_f32_16x16x32_bf16(pas, bvv, accO[nf], 0, 0, 0);
            }
        }
        __syncthreads();
    }

#pragma unroll
    for (int d = 0; d < 4; ++d)
#pragma unroll
        for (int r = 0; r < 4; ++r) {
            int row = qr0 + lhi * 4 + r;
            float o = accO[d][r] / l_r[r];
            attn[(size_t)(b * T_ + row) * 1024 + h * 64 + d * 16 + l15] = f2bf(o);
        }
}

// ---------------------------------------------------------------------------
// FALLBACK attention (round-1 proven)
// ---------------------------------------------------------------------------
__global__ __launch_bounds__(256)
void attn_k(const u16* __restrict__ qkv, u16* __restrict__ attn)
{
    const int qt = blockIdx.x, h = blockIdx.y, b = blockIdx.z;
    const int hk = h >> 2;
    const int tid = threadIdx.x;
    const int lane = tid & 63, w = tid >> 6;
    const int l15 = lane & 15, lhi = lane >> 4;
    __shared__ u16 sK[64 * 72];
    __shared__ u16 sVT[64 * 74];
    __shared__ u16 sP[4 * 16 * 72];

    const int q0 = qt * 64;
    const u16* qptr = qkv + (size_t)(b * T_ + q0 + w * 16 + l15) * 1536 + h * 64 + lhi * 8;
    bf16x8 aq0 = *(const bf16x8*)qptr;
    bf16x8 aq1 = *(const bf16x8*)(qptr + 32);

    f32x4 accO[4];
#pragma unroll
    for (int d = 0; d < 4; ++d) accO[d] = f32x4{0.f, 0.f, 0.f, 0.f};
    float m_r[4] = {-1e30f, -1e30f, -1e30f, -1e30f};
    float l_r[4] = {0.f, 0.f, 0.f, 0.f};
    const int myq = q0 + w * 16 + lhi * 4;
    u16* sPw = sP + w * 16 * 72;

    for (int kt = 0; kt <= qt; ++kt) {
#pragma unroll
        for (int i = 0; i < 2; ++i) {
            int cid = tid + i * 256;
            int r = cid >> 3, kc = cid & 7;
            const u16* src = qkv + (size_t)(b * T_ + kt * 64 + r) * 1536 + 1024 + hk * 64 + kc * 8;
            *(u32x4*)&sK[r * 72 + kc * 8] = *(const u32x4*)src;
        }
#pragma unroll
        for (int i = 0; i < 2; ++i) {
            int cid = tid + i * 256;
            int tt = cid >> 3, dc = cid & 7;
            const u16* src = qkv + (size_t)(b * T_ + kt * 64 + tt) * 1536 + 1280 + hk * 64 + dc * 8;
            bf16x8 vv = *(const bf16x8*)src;
#pragma unroll
            for (int j = 0; j < 8; ++j) sVT[(dc * 8 + j) * 74 + tt] = (u16)vv[j];
        }
        __syncthreads();

        f32x4 accS[4];
#pragma unroll
        for (int nf = 0; nf < 4; ++nf) accS[nf] = f32x4{0.f, 0.f, 0.f, 0.f};
#pragma unroll
        for (int s = 0; s < 2; ++s) {
            bf16x8 aqs = s ? aq1 : aq0;
#pragma unroll
            for (int nf = 0; nf < 4; ++nf) {
                bf16x8 bk = *(const bf16x8*)&sK[(nf * 16 + l15) * 72 + s * 32 + lhi * 8];
                accS[nf] = __builtin_amdgcn_mfma_f32_16x16x32_bf16(aqs, bk, accS[nf], 0, 0, 0);
            }
        }
#pragma unroll
        for (int nf = 0; nf < 4; ++nf)
#pragma unroll
            for (int r = 0; r < 4; ++r) {
                float v = accS[nf][r] * SCALE_;
                if (kt == qt) {
                    int kp = kt * 64 + nf * 16 + l15;
                    if (kp > myq + r) v = -1e30f;
                }
                accS[nf][r] = v;
            }
        float sc[4];
#pragma unroll
        for (int r = 0; r < 4; ++r) {
            float mx = fmaxf(fmaxf(accS[0][r], accS[1][r]), fmaxf(accS[2][r], accS[3][r]));
#pragma unroll
            for (int off = 1; off < 16; off <<= 1) mx = fmaxf(mx, __shfl_xor(mx, off));
            float mn = fmaxf(m_r[r], mx);
            sc[r] = expf(m_r[r] - mn);
            m_r[r] = mn;
        }
        float rs[4] = {0.f, 0.f, 0.f, 0.f};
#pragma unroll
        for (int nf = 0; nf < 4; ++nf)
#pragma unroll
            for (int r = 0; r < 4; ++r) {
                float p = expf(accS[nf][r] - m_r[r]);
                accS[nf][r] = p;
                rs[r] += p;
            }
#pragma unroll
        for (int r = 0; r < 4; ++r) {
#pragma unroll
            for (int off = 1; off < 16; off <<= 1) rs[r] += __shfl_xor(rs[r], off);
            l_r[r] = l_r[r] * sc[r] + rs[r];
        }
#pragma unroll
        for (int d = 0; d < 4; ++d)
#pragma unroll
            for (int r = 0; r < 4; ++r) accO[d][r] *= sc[r];

#pragma unroll
        for (int nf = 0; nf < 4; ++nf)
#pragma unroll
            for (int r = 0; r < 4; ++r)
                sPw[(lhi * 4 + r) * 72 + nf * 16 + l15] = f2bf(accS[nf][r]);
        bf16x8 pa0 = *(const bf16x8*)&sPw[l15 * 72 + lhi * 8];
        bf16x8 pa1 = *(const bf16x8*)&sPw[l15 * 72 + 32 + lhi * 8];
#pragma unroll
        for (int s = 0; s < 2; ++s) {
            bf16x8 pas = s ? pa1 : pa0;
#pragma unroll
            for (int d = 0; d < 4; ++d) {
                bf16x8 bvv = *(const bf16x8*)&sVT[(d * 16 + l15) * 74 + s * 32 + lhi * 8];
                accO[d] = __builtin_amdgcn_mfma_f32_16x16x32_bf16(pas, bvv, accO[d], 0, 0, 0);
            }
        }
        __syncthreads();
    }

#pragma unroll
    for (int d = 0; d < 4; ++d)
#pragma unroll
        for (int r = 0; r < 4; ++r) {
            int row = q0 + w * 16 + lhi * 4 + r;
            float o = accO[d][r] / l_r[r];
            attn[(size_t)(b * T_ + row) * 1024 + h * 64 + d * 16 + l15] = f2bf(o);
        }
}

// ---------------------------------------------------------------------------
// Small elementwise kernels
// ---------------------------------------------------------------------------
__global__ __launch_bounds__(256)
void gather_k(const int* __restrict__ ids, const float* __restrict__ emb,
              float* __restrict__ x)
{
    int m = blockIdx.x, tid = threadIdx.x;
    int id = ids[m];
    *(f32x4*)(x + (size_t)m * D_ + tid * 4) =
        *(const f32x4*)(emb + (size_t)id * D_ + tid * 4);
}

__global__ __launch_bounds__(256)
void rmsnorm_k(const float* __restrict__ x, const float* __restrict__ g,
               u16* __restrict__ out)
{
    const int row = blockIdx.x, tid = threadIdx.x;
    const float* xr = x + (size_t)row * D_;
    f32x4 v = *(const f32x4*)(xr + tid * 4);
    float ss = v.x * v.x + v.y * v.y + v.z * v.z + v.w * v.w;
#pragma unroll
    for (int off = 32; off >= 1; off >>= 1) ss += __shfl_xor(ss, off);
    __shared__ float red[4];
    if ((tid & 63) == 0) red[tid >> 6] = ss;
    __syncthreads();
    float tot = red[0] + red[1] + red[2] + red[3];
    float rr = rsqrtf(tot * (1.0f / D_) + 1e-6f);
    f32x4 wv = *(const f32x4*)(g + tid * 4);
    u16x4 o;
    o.x = f2bf(v.x * rr * wv.x); o.y = f2bf(v.y * rr * wv.y);
    o.z = f2bf(v.z * rr * wv.z); o.w = f2bf(v.w * rr * wv.w);
    *(u16x4*)(out + (size_t)row * D_ + tid * 4) = o;
}

// x += p0 + p1 (split-K partials), store x, then rmsnorm -> out (bf16)
__global__ __launch_bounds__(256)
void rmsnorm_add_k(float* __restrict__ x, const float* __restrict__ p,
                   const float* __restrict__ g, u16* __restrict__ out)
{
    const int row = blockIdx.x, tid = threadIdx.x;
    float* xr = x + (size_t)row * D_;
    const float* p0 = p + (size_t)row * D_;
    const float* p1 = p + (size_t)(M_ * (size_t)D_) + (size_t)row * D_;
    f32x4 a = *(const f32x4*)(xr + tid * 4);
    f32x4 b = *(const f32x4*)(p0 + tid * 4);
    f32x4 c = *(const f32x4*)(p1 + tid * 4);
    f32x4 v;
    v.x = a.x + b.x + c.x; v.y = a.y + b.y + c.y;
    v.z = a.z + b.z + c.z; v.w = a.w + b.w + c.w;
    *(f32x4*)(xr + tid * 4) = v;
    float ss = v.x * v.x + v.y * v.y + v.z * v.z + v.w * v.w;
#pragma unroll
    for (int off = 32; off >= 1; off >>= 1) ss += __shfl_xor(ss, off);
    __shared__ float red[4];
    if ((tid & 63) == 0) red[tid >> 6] = ss;
    __syncthreads();
    float tot = red[0] + red[1] + red[2] + red[3];
    float rr = rsqrtf(tot * (1.0f / D_) + 1e-6f);
    f32x4 wv = *(const f32x4*)(g + tid * 4);
    u16x4 o;
    o.x = f2bf(v.x * rr * wv.x); o.y = f2bf(v.y * rr * wv.y);
    o.z = f2bf(v.z * rr * wv.z); o.w = f2bf(v.w * rr * wv.w);
    *(u16x4*)(out + (size_t)row * D_ + tid * 4) = o;
}

// f32-silu (fallback path)
__global__ __launch_bounds__(256)
void silu_f32_k(const float* __restrict__ h13, u16* __restrict__ hh)
{
    int m = blockIdx.y;
    int f = blockIdx.x * 256 + threadIdx.x;
    float a = h13[(size_t)m * (2 * F_) + f];
    float c = h13[(size_t)m * (2 * F_) + F_ + f];
    float s = a / (1.0f + expf(-a));
    hh[(size_t)m * F_ + f] = f2bf(s * c);
}

__global__ __launch_bounds__(640)
void rope_slow_k(u16* __restrict__ qkv)
{
    int m = blockIdx.x;
    int c2 = threadIdx.x;
    int col = (c2 < 512) ? (c2 * 2) : (1024 + (c2 - 512) * 2);
    int d = col & 63;
    int t = m & (T_ - 1);
    float ang = (float)t * powf(10000.0f, -(float)d / 64.0f);
    float cs = cosf(ang), sn = sinf(ang);
    u16* p = qkv + (size_t)m * 1536 + col;
    float x0 = bf2f(p[0]), x1 = bf2f(p[1]);
    p[0] = f2bf(x0 * cs - x1 * sn);
    p[1] = f2bf(x0 * sn + x1 * cs);
}

// ---------------------------------------------------------------------------
extern "C" void kernel_launch(void* const* d_in, const int* in_sizes, int n_in,
                              void* d_out, int out_size, void* d_ws, size_t ws_size,
                              hipStream_t stream)
{
    const int*   ids = (const int*)d_in[0];
    const float* emb = (const float*)d_in[1];
    const float* qw  = (const float*)d_in[2];
    const float* kw  = (const float*)d_in[3];
    const float* vw  = (const float*)d_in[4];
    const float* ow  = (const float*)d_in[5];
    const float* w1  = (const float*)d_in[6];
    const float* w2  = (const float*)d_in[7];
    const float* w3  = (const float*)d_in[8];
    const float* n1  = (const float*)d_in[9];
    const float* n2  = (const float*)d_in[10];
    const float* nfw = (const float*)d_in[11];
    float* out = (float*)d_out;
    char*  ws  = (char*)d_ws;

    // ---- workspace layout ----
    float* x    = (float*)(ws);                    //  8 MB residual f32
    u16*   xn   = (u16*)(ws + 8388608ULL);         //  4 MB normed acts
    u16*   qkvb = (u16*)(ws + 12582912ULL);        //  6 MB fused qkv
    u16*   attnb= (u16*)(ws + 18874368ULL);        //  4 MB attn out
    float* pW   = (float*)(ws + 23068672ULL);      // 16 MB W2 split-K partials
    u16*   hh   = (u16*)(ws + 46137344ULL);        // 11 MB silu(h1)*h3
    float* ropec= (float*)(ws + 57671680ULL);      // 128 KB
    float* ropes= (float*)(ws + 57802752ULL);      // 128 KB
    u16*   embb = (u16*)(ws + 57933824ULL);        // 62.5 MB
    u16*   wqkv = (u16*)(ws + 123469824ULL);       // 24 MB
    u16*   wob  = (u16*)(ws + 148635648ULL);       // 16 MB
    u16*   w13b = (u16*)(ws + 165412864ULL);       // 88 MB (w1/w3 row-interleaved)
    u16*   w2b  = (u16*)(ws + 257687552ULL);       // 44 MB
    u16*   vtb  = (u16*)(ws + 303824896ULL);       //  1 MB V^T
    const unsigned long long NEED = 304873472ULL;

    if (ws_size >= NEED) {
        // ONE mega-prep dispatch: all cvts + rope tables + gather
        prep_k<<<122240, 256, 0, stream>>>(
            emb, qw, kw, vw, ow, w1, w2, w3, ids,
            embb, wqkv, wob, w13b, w2b, x, ropec, ropes);

        for (int l = 0; l < L_; ++l) {
            if (l == 0)
                rmsnorm_k<<<M_, 256, 0, stream>>>(x, n1, xn);
            else
                rmsnorm_add_k<<<M_, 256, 0, stream>>>(x, pW, n1 + l * D_, xn);
            // fused QKV + RoPE + V-transpose (v cols -> vtb, not qkvb)
            gemm2_k<64, 64, 4><<<32 * 24, 256, 0, stream>>>(
                xn, D_, wqkv + (size_t)l * 1572864, 1536, (float*)vtb, qkvb, ropec, ropes);
            attn3_k<<<dim3(32, HK_, B_), 512, 0, stream>>>(qkvb, vtb, attnb);
            gemm2_k<64, 64, 2><<<32 * 16, 256, 0, stream>>>(
                attnb, D_, wob + (size_t)l * 1048576, 1024, x, nullptr, nullptr, nullptr);
            rmsnorm_k<<<M_, 256, 0, stream>>>(x, n2 + l * D_, xn);
            // fused W1||W3 (interleaved) + SiLU -> hh
            gemm2_k<128, 128, 3><<<16 * 44, 256, 0, stream>>>(
                xn, D_, w13b + (size_t)l * 5767168, 5632, nullptr, hh, nullptr, nullptr);
            // W2 split-K2 -> f32 partials pW (absorbed by next rmsnorm_add)
            gemm2_k<64, 64, 5><<<2 * 32 * 16, 256, 0, stream>>>(
                hh, F_, w2b + (size_t)l * 2883584, 1024, pW, nullptr, nullptr, nullptr);
        }

        rmsnorm_add_k<<<M_, 256, 0, stream>>>(x, pW, nfw, xn);
        // logits: 8-phase 256^2, coalesced f32x4 epilogue
        gemm8_k<1><<<8 * 125, 512, 0, stream>>>(
            xn, D_, embb, V_, out, nullptr);
        return;
    }

    // ---------------- fallback: round-1 proven path ----------------
    float* h13f = (float*)(ws + 23068672ULL);
    u16*   hhf  = (u16*)(ws + 69206016ULL);
    gather_k<<<M_, 256, 0, stream>>>(ids, emb, x);

    for (int l = 0; l < L_; ++l) {
        rmsnorm_k<<<M_, 256, 0, stream>>>(x, n1 + l * D_, xn);
        gemm_k<128, 64, 0, 3><<<dim3(24, 16), 256, 0, stream>>>(
            xn, D_,
            qw + (size_t)l * H_ * DH_ * D_,
            kw + (size_t)l * HK_ * DH_ * D_,
            vw + (size_t)l * HK_ * DH_ * D_,
            1024, 256, 1536, nullptr, qkvb);
        rope_slow_k<<<M_, 640, 0, stream>>>(qkvb);
        attn_k<<<dim3(T_ / 64, H_, B_), 256, 0, stream>>>(qkvb, attnb);
        gemm_k<128, 64, 2, 1><<<dim3(16, 16), 256, 0, stream>>>(
            attnb, D_, ow + (size_t)l * D_ * D_, nullptr, nullptr,
            0, 0, D_, x, nullptr);
        rmsnorm_k<<<M_, 256, 0, stream>>>(x, n2 + l * D_, xn);
        gemm_k<128, 128, 1, 2><<<dim3(44, 16), 256, 0, stream>>>(
            xn, D_, w1 + (size_t)l * F_ * D_, w3 + (size_t)l * F_ * D_, nullptr,
            F_, 0, 2 * F_, h13f, nullptr);
        silu_f32_k<<<dim3(11, M_), 256, 0, stream>>>(h13f, hhf);
        gemm_k<128, 64, 2, 1><<<dim3(16, 16), 256, 0, stream>>>(
            hhf, F_, w2 + (size_t)l * D_ * F_, nullptr, nullptr,
            0, 0, D_, x, nullptr);
    }

    rmsnorm_k<<<M_, 256, 0, stream>>>(x, nfw, xn);
    gemm_k<128, 128, 1, 1><<<dim3(250, 16), 256, 0, stream>>>(
        xn, D_, emb, nullptr, nullptr, 0, 0, V_, out, nullptr);
}

// Round 12
// 1684.536 us; speedup vs baseline: 1.1576x; 1.0206x over previous
//
#include <hip/hip_runtime.h>
#include <math.h>

#define L_ 8
#define D_ 1024
#define H_ 16
#define HK_ 4
#define DH_ 64
#define F_ 2816
#define V_ 32000
#define T_ 1024
#define B_ 2
#define M_ (B_*T_)          // 2048 tokens
#define SCALE_ 0.125f       // DH^-0.5

typedef unsigned short u16;
typedef unsigned int   u32;
typedef __attribute__((ext_vector_type(4))) float  f32x4;
typedef __attribute__((ext_vector_type(8))) short  bf16x8;   // 8 bf16 = 4 VGPRs (MFMA A/B frag)
typedef __attribute__((ext_vector_type(4))) unsigned short u16x4;
typedef __attribute__((ext_vector_type(4))) unsigned int   u32x4;

__device__ __forceinline__ float bf2f(u16 h) {
    union { u32 u; float f; } v; v.u = ((u32)h) << 16; return v.f;
}
__device__ __forceinline__ u16 f2bf(float f) {   // round-to-nearest-even
    union { float f; u32 u; } v; v.f = f;
    u32 r = v.u + 0x7fffu + ((v.u >> 16) & 1u);
    return (u16)(r >> 16);
}

__device__ __forceinline__ void gl_lds16(const void* g, void* l) {
    __builtin_amdgcn_global_load_lds(
        (const __attribute__((address_space(1))) unsigned int*)g,
        (__attribute__((address_space(3))) unsigned int*)l,
        16, 0, 0);
}

// ---------------------------------------------------------------------------
// 2-phase double-buffered GEMM (proven): C[M,N]=A[M,K] x W[N,K]^T, bf16.
// BK=32, 4 waves 2x2, bijective XCD swizzle, global_load_lds staging.
// EPI: 0 = bf16 store, 1 = f32 store, 2 = f32 +=,
//      3 = fused SiLU (w1/w3 row-interleaved), 4 = fused RoPE + V-transpose,
//      5 = split-K2 f32 partial store (Of[kh][M_][D_])
// ---------------------------------------------------------------------------
template<int BM, int BN, int EPI>
__global__ __launch_bounds__(256)
void gemm2_k(const u16* __restrict__ A, int K,
             const u16* __restrict__ W, int N,
             float* __restrict__ Of, u16* __restrict__ Ob,
             const float* __restrict__ tc, const float* __restrict__ ts)
{
    constexpr int FM = BM / 32;
    constexpr int FN = BN / 32;
    constexpr int GM = M_ / BM;
    constexpr int IPA = BM / 64;
    constexpr int IPB = BN / 64;
    __shared__ u16 sA[2 * BM * 32];
    __shared__ u16 sB[2 * BN * 32];

    const int tid  = threadIdx.x;
    const int lane = tid & 63, wv = tid >> 6;
    const int wm = wv >> 1, wn = wv & 1;
    const int l15 = lane & 15, lhi = lane >> 4;
    const int m0 = wm * (BM / 2), n0 = wn * (BN / 2);

    const int nwg = gridDim.x;
    const int q8 = nwg >> 3, r8 = nwg & 7;
    const int xcd = blockIdx.x & 7, off8 = blockIdx.x >> 3;
    const int wgid = (xcd < r8 ? xcd * (q8 + 1) : r8 * (q8 + 1) + (xcd - r8) * q8) + off8;

    int tM, tN, kh = 0, koff = 0, Klen = K;
    if (EPI == 5) {
        kh = wgid & 1;
        int wg2 = wgid >> 1;
        tM = wg2 % GM; tN = wg2 / GM;
        Klen = K >> 1; koff = kh * Klen;
    } else {
        tM = wgid % GM; tN = wgid / GM;
    }

    const int srow = lane >> 2;
    const int scol = (lane & 3) * 8;

    const u16* Abase = A + (size_t)(tM * BM) * K + koff;
    const u16* Wbase = W + (size_t)(tN * BN) * K + koff;

    f32x4 acc[FM][FN];
#pragma unroll
    for (int i = 0; i < FM; ++i)
#pragma unroll
        for (int j = 0; j < FN; ++j) acc[i][j] = f32x4{0.f, 0.f, 0.f, 0.f};

    auto stage = [&](int kt, int buf) {
        u16* sa = sA + buf * (BM * 32);
        u16* sb = sB + buf * (BN * 32);
#pragma unroll
        for (int i = 0; i < IPA; ++i) {
            int c = wv * IPA + i;
            gl_lds16(Abase + (size_t)(c * 16 + srow) * K + kt + scol, sa + c * 512);
        }
#pragma unroll
        for (int i = 0; i < IPB; ++i) {
            int c = wv * IPB + i;
            gl_lds16(Wbase + (size_t)(c * 16 + srow) * K + kt + scol, sb + c * 512);
        }
    };

    const int nt = Klen >> 5;
    stage(0, 0);
    asm volatile("s_waitcnt vmcnt(0)" ::: "memory");
    __syncthreads();

    int cur = 0;
    for (int t = 0; t < nt; ++t) {
        if (t + 1 < nt) stage((t + 1) << 5, cur ^ 1);

        const u16* sa = sA + cur * (BM * 32);
        const u16* sb = sB + cur * (BN * 32);
        bf16x8 av[FM], bv[FN];
#pragma unroll
        for (int i = 0; i < FM; ++i)
            av[i] = *(const bf16x8*)&sa[(m0 + i * 16 + l15) * 32 + lhi * 8];
#pragma unroll
        for (int j = 0; j < FN; ++j)
            bv[j] = *(const bf16x8*)&sb[(n0 + j * 16 + l15) * 32 + lhi * 8];
#pragma unroll
        for (int i = 0; i < FM; ++i)
#pragma unroll
            for (int j = 0; j < FN; ++j)
                acc[i][j] = __builtin_amdgcn_mfma_f32_16x16x32_bf16(
                    av[i], bv[j], acc[i][j], 0, 0, 0);

        if (t + 1 < nt) {
            asm volatile("s_waitcnt vmcnt(0)" ::: "memory");
            __syncthreads();
            cur ^= 1;
        }
    }

#pragma unroll
    for (int i = 0; i < FM; ++i)
#pragma unroll
        for (int j = 0; j < FN; ++j) {
            size_t gm = (size_t)tM * BM + m0 + i * 16 + lhi * 4;
            size_t gn = (size_t)tN * BN + n0 + j * 16 + l15;
#pragma unroll
            for (int r = 0; r < 4; ++r) {
                float v = acc[i][j][r];
                size_t idx = (gm + r) * (size_t)N + gn;
                if (EPI == 0) {
                    Ob[idx] = f2bf(v);
                } else if (EPI == 1) {
                    Of[idx] = v;
                } else if (EPI == 2) {
                    Of[idx] += v;
                } else if (EPI == 5) {
                    Of[(size_t)kh * (M_ * (size_t)D_) + idx] = v;
                } else if (EPI == 3) {
                    float b = __shfl_xor(v, 1);
                    if ((lane & 1) == 0) {
                        float s = v / (1.0f + expf(-v));
                        Ob[(gm + r) * (size_t)F_ + (gn >> 1)] = f2bf(s * b);
                    }
                } else {   // EPI == 4: RoPE q/k; v cols -> transposed vt
                    float b = __shfl_xor(v, 1);
                    int gni = (int)gn;
                    int gmr = (int)(gm + r);
                    if (gni < 1280) {
                        int dd = gni & 63;
                        int jj = dd >> 1;
                        int tt = gmr & (T_ - 1);
                        float c = tc[tt * 32 + jj], s = ts[tt * 32 + jj];
                        float ro = ((dd & 1) == 0) ? (v * c - b * s) : (b * s + v * c);
                        Ob[idx] = f2bf(ro);
                    } else {
                        int vc = gni - 1280;              // 0..255
                        int hk = vc >> 6, dd = vc & 63;
                        int bb = gmr >> 10, tt = gmr & (T_ - 1);
                        ((u16*)Of)[((size_t)((bb * HK_ + hk) * DH_ + dd)) * T_ + tt] = f2bf(v);
                    }
                }
            }
        }
}

// ---------------------------------------------------------------------------
// MEGA-PREP: all weight cvts + rope tables + gather in ONE dispatch.
// ---------------------------------------------------------------------------
__global__ __launch_bounds__(256)
void prep_k(const float* __restrict__ emb, const float* __restrict__ qw,
            const float* __restrict__ kw, const float* __restrict__ vw,
            const float* __restrict__ ow, const float* __restrict__ w1,
            const float* __restrict__ w2, const float* __restrict__ w3,
            const int* __restrict__ ids,
            u16* __restrict__ embb, u16* __restrict__ wqkv,
            u16* __restrict__ wob, u16* __restrict__ w13b,
            u16* __restrict__ w2b, float* __restrict__ x,
            float* __restrict__ tc, float* __restrict__ ts)
{
    const int bx = blockIdx.x, tid = threadIdx.x;
    const float* src = nullptr;
    u16* dst = nullptr;

    if (bx < 32000) {
        src = emb + (size_t)bx * 1024;           dst = embb + (size_t)bx * 1024;
    } else if (bx < 40192) {
        int lb = bx - 32000, l = lb >> 10, j = lb & 1023;
        src = qw + (size_t)l * 1048576 + j * 1024;
        dst = wqkv + (size_t)l * 1572864 + j * 1024;
    } else if (bx < 42240) {
        int lb = bx - 40192, l = lb >> 8, j = lb & 255;
        src = kw + (size_t)l * 262144 + j * 1024;
        dst = wqkv + (size_t)l * 1572864 + 1048576 + j * 1024;
    } else if (bx < 44288) {
        int lb = bx - 42240, l = lb >> 8, j = lb & 255;
        src = vw + (size_t)l * 262144 + j * 1024;
        dst = wqkv + (size_t)l * 1572864 + 1310720 + j * 1024;
    } else if (bx < 52480) {
        int lb = bx - 44288, l = lb >> 10, j = lb & 1023;
        src = ow + (size_t)l * 1048576 + j * 1024;
        dst = wob + (size_t)l * 1048576 + j * 1024;
    } else if (bx < 75008) {
        int lb = bx - 52480, l = lb / 2816, f = lb - l * 2816;
        src = w1 + (size_t)l * 2883584 + (size_t)f * 1024;
        dst = w13b + (size_t)l * 5767168 + (size_t)(2 * f) * 1024;
    } else if (bx < 97536) {
        int lb = bx - 75008, l = lb / 2816, f = lb - l * 2816;
        src = w3 + (size_t)l * 2883584 + (size_t)f * 1024;
        dst = w13b + (size_t)l * 5767168 + (size_t)(2 * f + 1) * 1024;
    } else if (bx < 120064) {
        int lb = bx - 97536, l = lb / 2816, f = lb - l * 2816;
        src = w2 + (size_t)l * 2883584 + (size_t)f * 1024;
        dst = w2b + (size_t)l * 2883584 + (size_t)f * 1024;
    } else if (bx < 122112) {
        int m = bx - 120064;
        int id = ids[m];
        *(f32x4*)(x + (size_t)m * D_ + tid * 4) =
            *(const f32x4*)(emb + (size_t)id * D_ + tid * 4);
        return;
    } else {
        int idx = (bx - 122112) * 256 + tid;     // T_*32 total
        int t = idx >> 5, j = idx & 31;
        float inv = powf(10000.0f, -(float)j * (1.0f / 32.0f));
        float ang = (float)t * inv;
        tc[idx] = cosf(ang);
        ts[idx] = sinf(ang);
        return;
    }
    f32x4 v = *(const f32x4*)(src + tid * 4);
    u16x4 o;
    o.x = f2bf(v.x); o.y = f2bf(v.y); o.z = f2bf(v.z); o.w = f2bf(v.w);
    *(u16x4*)(dst + tid * 4) = o;
}

// ---------------------------------------------------------------------------
// FALLBACK GEMM (round-1, proven): cast-in-staging, multi-W split.
// ---------------------------------------------------------------------------
template<int BM, int BN, int EPI, int NW>
__global__ __launch_bounds__(256)
void gemm_k(const u16* __restrict__ A, int K,
            const float* __restrict__ W0, const float* __restrict__ W1p,
            const float* __restrict__ W2p, int N0, int N1, int N,
            float* __restrict__ Of, u16* __restrict__ Ob)
{
    constexpr int FM = BM / 32;
    constexpr int FN = BN / 32;
    constexpr int LS = 40;
    __shared__ u16 sA[BM * LS];
    __shared__ u16 sB[BN * LS];

    const int tid  = threadIdx.x;
    const int lane = tid & 63, wv = tid >> 6;
    const int wm = wv >> 1, wn = wv & 1;
    const int l15 = lane & 15, lhi = lane >> 4;
    const int m0 = wm * (BM / 2), n0 = wn * (BN / 2);
    const int tM = blockIdx.y, tN = blockIdx.x;

    f32x4 acc[FM][FN];
#pragma unroll
    for (int i = 0; i < FM; ++i)
#pragma unroll
        for (int j = 0; j < FN; ++j) acc[i][j] = f32x4{0.f, 0.f, 0.f, 0.f};

    for (int kt = 0; kt < K; kt += 32) {
#pragma unroll
        for (int i = 0; i < BM / 64; ++i) {
            int cid = tid + i * 256;
            int row = cid >> 2, kc = cid & 3;
            const u16* src = A + (size_t)(tM * BM + row) * K + kt + kc * 8;
            *(u32x4*)&sA[row * LS + kc * 8] = *(const u32x4*)src;
        }
#pragma unroll
        for (int i = 0; i < BN / 32; ++i) {
            int cid = tid + i * 256;
            int row = cid >> 3, kc = cid & 7;
            int n = tN * BN + row;
            const float* wr;
            if (NW == 1)      wr = W0 + (size_t)n * K;
            else if (NW == 2) wr = (n < N0) ? (W0 + (size_t)n * K)
                                            : (W1p + (size_t)(n - N0) * K);
            else              wr = (n < N0) ? (W0 + (size_t)n * K)
                               : (n < N0 + N1) ? (W1p + (size_t)(n - N0) * K)
                                               : (W2p + (size_t)(n - N0 - N1) * K);
            f32x4 v = *(const f32x4*)(wr + kt + kc * 4);
            u16x4 o;
            o.x = f2bf(v.x); o.y = f2bf(v.y); o.z = f2bf(v.z); o.w = f2bf(v.w);
            *(u16x4*)&sB[row * LS + kc * 4] = o;
        }
        __syncthreads();

        bf16x8 av[FM], bv[FN];
#pragma unroll
        for (int i = 0; i < FM; ++i)
            av[i] = *(const bf16x8*)&sA[(m0 + i * 16 + l15) * LS + lhi * 8];
#pragma unroll
        for (int j = 0; j < FN; ++j)
            bv[j] = *(const bf16x8*)&sB[(n0 + j * 16 + l15) * LS + lhi * 8];
#pragma unroll
        for (int i = 0; i < FM; ++i)
#pragma unroll
            for (int j = 0; j < FN; ++j)
                acc[i][j] = __builtin_amdgcn_mfma_f32_16x16x32_bf16(
                    av[i], bv[j], acc[i][j], 0, 0, 0);
        __syncthreads();
    }

#pragma unroll
    for (int i = 0; i < FM; ++i)
#pragma unroll
        for (int j = 0; j < FN; ++j) {
            size_t gm = (size_t)tM * BM + m0 + i * 16 + lhi * 4;
            size_t gn = (size_t)tN * BN + n0 + j * 16 + l15;
#pragma unroll
            for (int r = 0; r < 4; ++r) {
                float v = acc[i][j][r];
                size_t idx = (gm + r) * (size_t)N + gn;
                if (EPI == 0)      Ob[idx] = f2bf(v);
                else if (EPI == 1) Of[idx] = v;
                else               Of[idx] += v;
            }
        }
}

// ---------------------------------------------------------------------------
// Flash attention v3: GQA-shared K/V staging (proven round 8).
// ---------------------------------------------------------------------------
__global__ __launch_bounds__(512)
void attn3_k(const u16* __restrict__ qkv, const u16* __restrict__ vt,
             u16* __restrict__ attn)
{
    const int qt = 31 - blockIdx.x;
    const int hk = blockIdx.y, b = blockIdx.z;
    const int tid = threadIdx.x;
    const int lane = tid & 63, w = tid >> 6;
    const int l15 = lane & 15, lhi = lane >> 4;
    const int h = hk * 4 + (w & 3);
    const int rg = w >> 2;

    __shared__ u16 sK[128 * 64];
    __shared__ u16 sVT[64 * 128];
    __shared__ u16 sP[8][16 * 136];

    const int q0 = qt * 32;
    const int qr0 = q0 + rg * 16;
    const u16* qptr = qkv + (size_t)(b * T_ + qr0 + l15) * 1536 + h * 64 + lhi * 8;
    bf16x8 aq0 = *(const bf16x8*)qptr;
    bf16x8 aq1 = *(const bf16x8*)(qptr + 32);

    f32x4 accO[4];
#pragma unroll
    for (int d = 0; d < 4; ++d) accO[d] = f32x4{0.f, 0.f, 0.f, 0.f};
    float m_r[4] = {-1e30f, -1e30f, -1e30f, -1e30f};
    float l_r[4] = {0.f, 0.f, 0.f, 0.f};
    const int myq = qr0 + lhi * 4;
    const int qmaxw = qr0 + 15;
    u16* sPw = sP[w];

    const int ntiles = (qt >> 2) + 1;
    const u16* vtb = vt + (size_t)((b * HK_ + hk) * DH_) * T_;
    const int L = lane;

    for (int kt = 0; kt < ntiles; ++kt) {
        const int t0 = kt * 128;
#pragma unroll
        for (int i = 0; i < 2; ++i) {
            int c = w * 2 + i;
            int row = c * 8 + (L >> 3);
            int p = L & 7;
            const u16* src = qkv + (size_t)(b * T_ + t0 + row) * 1536 + 1024 + hk * 64
                             + ((p ^ (row & 7)) * 8);
            gl_lds16(src, sK + c * 512);
        }
#pragma unroll
        for (int i = 0; i < 2; ++i) {
            int c = w * 2 + i;
            int row = c * 4 + (L >> 4);
            int p = L & 15;
            const u16* src = vtb + (size_t)row * T_ + t0 + ((p ^ (row & 15)) * 8);
            gl_lds16(src, sVT + c * 512);
        }
        asm volatile("s_waitcnt vmcnt(0)" ::: "memory");
        __syncthreads();

        const bool lastt = (kt == ntiles - 1);

        f32x4 accS[8];
#pragma unroll
        for (int nf = 0; nf < 8; ++nf)
            accS[nf] = f32x4{-1e30f, -1e30f, -1e30f, -1e30f};
#pragma unroll
        for (int pk = 0; pk < 4; ++pk) {
            if (t0 + pk * 32 > qmaxw) continue;
            f32x4 s0 = f32x4{0.f, 0.f, 0.f, 0.f};
            f32x4 s1 = f32x4{0.f, 0.f, 0.f, 0.f};
#pragma unroll
            for (int kk = 0; kk < 2; ++kk) {
                bf16x8 aqs = kk ? aq1 : aq0;
                int r0 = (pk * 2) * 16 + l15;
                int r1 = (pk * 2 + 1) * 16 + l15;
                int ls = kk * 4 + lhi;
                bf16x8 b0 = *(const bf16x8*)&sK[r0 * 64 + ((ls ^ (r0 & 7)) * 8)];
                bf16x8 b1 = *(const bf16x8*)&sK[r1 * 64 + ((ls ^ (r1 & 7)) * 8)];
                s0 = __builtin_amdgcn_mfma_f32_16x16x32_bf16(aqs, b0, s0, 0, 0, 0);
                s1 = __builtin_amdgcn_mfma_f32_16x16x32_bf16(aqs, b1, s1, 0, 0, 0);
            }
#pragma unroll
            for (int r = 0; r < 4; ++r) {
                float v0 = s0[r] * SCALE_;
                float v1 = s1[r] * SCALE_;
                if (lastt) {
                    int kp0 = t0 + (pk * 2) * 16 + l15;
                    int kp1 = kp0 + 16;
                    if (kp0 > myq + r) v0 = -1e30f;
                    if (kp1 > myq + r) v1 = -1e30f;
                }
                accS[pk * 2][r] = v0;
                accS[pk * 2 + 1][r] = v1;
            }
        }

        float sc[4];
#pragma unroll
        for (int r = 0; r < 4; ++r) {
            float mx = accS[0][r];
#pragma unroll
            for (int nf = 1; nf < 8; ++nf) mx = fmaxf(mx, accS[nf][r]);
#pragma unroll
            for (int off = 1; off < 16; off <<= 1) mx = fmaxf(mx, __shfl_xor(mx, off));
            float mn = fmaxf(m_r[r], mx);
            sc[r] = expf(m_r[r] - mn);
            m_r[r] = mn;
        }
        float rs[4] = {0.f, 0.f, 0.f, 0.f};
#pragma unroll
        for (int pk = 0; pk < 4; ++pk) {
            if (t0 + pk * 32 > qmaxw) continue;
#pragma unroll
            for (int g = 0; g < 2; ++g) {
                int nf = pk * 2 + g;
#pragma unroll
                for (int r = 0; r < 4; ++r) {
                    float p = expf(accS[nf][r] - m_r[r]);
                    accS[nf][r] = p;
                    rs[r] += p;
                }
            }
        }
#pragma unroll
        for (int r = 0; r < 4; ++r) {
#pragma unroll
            for (int off = 1; off < 16; off <<= 1) rs[r] += __shfl_xor(rs[r], off);
            l_r[r] = l_r[r] * sc[r] + rs[r];
        }
#pragma unroll
        for (int d = 0; d < 4; ++d)
#pragma unroll
            for (int r = 0; r < 4; ++r) accO[d][r] *= sc[r];

#pragma unroll
        for (int pk = 0; pk < 4; ++pk) {
            if (t0 + pk * 32 > qmaxw) continue;
#pragma unroll
            for (int g = 0; g < 2; ++g) {
                int nf = pk * 2 + g;
#pragma unroll
                for (int r = 0; r < 4; ++r)
                    sPw[(lhi * 4 + r) * 136 + nf * 16 + l15] = f2bf(accS[nf][r]);
            }
        }

#pragma unroll
        for (int kk = 0; kk < 4; ++kk) {
            if (t0 + kk * 32 > qmaxw) continue;
            bf16x8 pas = *(const bf16x8*)&sPw[l15 * 136 + kk * 32 + lhi * 8];
#pragma unroll
            for (int nf = 0; nf < 4; ++nf) {
                int row = nf * 16 + l15;
                int ls = kk * 4 + lhi;
                bf16x8 bvv = *(const bf16x8*)&sVT[row * 128 + ((ls ^ (row & 15)) * 8)];
                accO[nf] = __builtin_amdgcn_mfma_f32_16x16x32_bf16(pas, bvv, accO[nf], 0, 0, 0);
            }
        }
        __syncthreads();
    }

#pragma unroll
    for (int d = 0; d < 4; ++d)
#pragma unroll
        for (int r = 0; r < 4; ++r) {
            int row = qr0 + lhi * 4 + r;
            float o = accO[d][r] / l_r[r];
            attn[(size_t)(b * T_ + row) * 1024 + h * 64 + d * 16 + l15] = f2bf(o);
        }
}

// ---------------------------------------------------------------------------
// FALLBACK attention (round-1 proven)
// ---------------------------------------------------------------------------
__global__ __launch_bounds__(256)
void attn_k(const u16* __restrict__ qkv, u16* __restrict__ attn)
{
    const int qt = blockIdx.x, h = blockIdx.y, b = blockIdx.z;
    const int hk = h >> 2;
    const int tid = threadIdx.x;
    const int lane = tid & 63, w = tid >> 6;
    const int l15 = lane & 15, lhi = lane >> 4;
    __shared__ u16 sK[64 * 72];
    __shared__ u16 sVT[64 * 74];
    __shared__ u16 sP[4 * 16 * 72];

    const int q0 = qt * 64;
    const u16* qptr = qkv + (size_t)(b * T_ + q0 + w * 16 + l15) * 1536 + h * 64 + lhi * 8;
    bf16x8 aq0 = *(const bf16x8*)qptr;
    bf16x8 aq1 = *(const bf16x8*)(qptr + 32);

    f32x4 accO[4];
#pragma unroll
    for (int d = 0; d < 4; ++d) accO[d] = f32x4{0.f, 0.f, 0.f, 0.f};
    float m_r[4] = {-1e30f, -1e30f, -1e30f, -1e30f};
    float l_r[4] = {0.f, 0.f, 0.f, 0.f};
    const int myq = q0 + w * 16 + lhi * 4;
    u16* sPw = sP + w * 16 * 72;

    for (int kt = 0; kt <= qt; ++kt) {
#pragma unroll
        for (int i = 0; i < 2; ++i) {
            int cid = tid + i * 256;
            int r = cid >> 3, kc = cid & 7;
            const u16* src = qkv + (size_t)(b * T_ + kt * 64 + r) * 1536 + 1024 + hk * 64 + kc * 8;
            *(u32x4*)&sK[r * 72 + kc * 8] = *(const u32x4*)src;
        }
#pragma unroll
        for (int i = 0; i < 2; ++i) {
            int cid = tid + i * 256;
            int tt = cid >> 3, dc = cid & 7;
            const u16* src = qkv + (size_t)(b * T_ + kt * 64 + tt) * 1536 + 1280 + hk * 64 + dc * 8;
            bf16x8 vv = *(const bf16x8*)src;
#pragma unroll
            for (int j = 0; j < 8; ++j) sVT[(dc * 8 + j) * 74 + tt] = (u16)vv[j];
        }
        __syncthreads();

        f32x4 accS[4];
#pragma unroll
        for (int nf = 0; nf < 4; ++nf) accS[nf] = f32x4{0.f, 0.f, 0.f, 0.f};
#pragma unroll
        for (int s = 0; s < 2; ++s) {
            bf16x8 aqs = s ? aq1 : aq0;
#pragma unroll
            for (int nf = 0; nf < 4; ++nf) {
                bf16x8 bk = *(const bf16x8*)&sK[(nf * 16 + l15) * 72 + s * 32 + lhi * 8];
                accS[nf] = __builtin_amdgcn_mfma_f32_16x16x32_bf16(aqs, bk, accS[nf], 0, 0, 0);
            }
        }
#pragma unroll
        for (int nf = 0; nf < 4; ++nf)
#pragma unroll
            for (int r = 0; r < 4; ++r) {
                float v = accS[nf][r] * SCALE_;
                if (kt == qt) {
                    int kp = kt * 64 + nf * 16 + l15;
                    if (kp > myq + r) v = -1e30f;
                }
                accS[nf][r] = v;
            }
        float sc[4];
#pragma unroll
        for (int r = 0; r < 4; ++r) {
            float mx = fmaxf(fmaxf(accS[0][r], accS[1][r]), fmaxf(accS[2][r], accS[3][r]));
#pragma unroll
            for (int off = 1; off < 16; off <<= 1) mx = fmaxf(mx, __shfl_xor(mx, off));
            float mn = fmaxf(m_r[r], mx);
            sc[r] = expf(m_r[r] - mn);
            m_r[r] = mn;
        }
        float rs[4] = {0.f, 0.f, 0.f, 0.f};
#pragma unroll
        for (int nf = 0; nf < 4; ++nf)
#pragma unroll
            for (int r = 0; r < 4; ++r) {
                float p = expf(accS[nf][r] - m_r[r]);
                accS[nf][r] = p;
                rs[r] += p;
            }
#pragma unroll
        for (int r = 0; r < 4; ++r) {
#pragma unroll
            for (int off = 1; off < 16; off <<= 1) rs[r] += __shfl_xor(rs[r], off);
            l_r[r] = l_r[r] * sc[r] + rs[r];
        }
#pragma unroll
        for (int d = 0; d < 4; ++d)
#pragma unroll
            for (int r = 0; r < 4; ++r) accO[d][r] *= sc[r];

#pragma unroll
        for (int nf = 0; nf < 4; ++nf)
#pragma unroll
            for (int r = 0; r < 4; ++r)
                sPw[(lhi * 4 + r) * 72 + nf * 16 + l15] = f2bf(accS[nf][r]);
        bf16x8 pa0 = *(const bf16x8*)&sPw[l15 * 72 + lhi * 8];
        bf16x8 pa1 = *(const bf16x8*)&sPw[l15 * 72 + 32 + lhi * 8];
#pragma unroll
        for (int s = 0; s < 2; ++s) {
            bf16x8 pas = s ? pa1 : pa0;
#pragma unroll
            for (int d = 0; d < 4; ++d) {
                bf16x8 bvv = *(const bf16x8*)&sVT[(d * 16 + l15) * 74 + s * 32 + lhi * 8];
                accO[d] = __builtin_amdgcn_mfma_f32_16x16x32_bf16(pas, bvv, accO[d], 0, 0, 0);
            }
        }
        __syncthreads();
    }

#pragma unroll
    for (int d = 0; d < 4; ++d)
#pragma unroll
        for (int r = 0; r < 4; ++r) {
            int row = q0 + w * 16 + lhi * 4 + r;
            float o = accO[d][r] / l_r[r];
            attn[(size_t)(b * T_ + row) * 1024 + h * 64 + d * 16 + l15] = f2bf(o);
        }
}

// ---------------------------------------------------------------------------
// Small elementwise kernels
// ---------------------------------------------------------------------------
__global__ __launch_bounds__(256)
void gather_k(const int* __restrict__ ids, const float* __restrict__ emb,
              float* __restrict__ x)
{
    int m = blockIdx.x, tid = threadIdx.x;
    int id = ids[m];
    *(f32x4*)(x + (size_t)m * D_ + tid * 4) =
        *(const f32x4*)(emb + (size_t)id * D_ + tid * 4);
}

__global__ __launch_bounds__(256)
void rmsnorm_k(const float* __restrict__ x, const float* __restrict__ g,
               u16* __restrict__ out)
{
    const int row = blockIdx.x, tid = threadIdx.x;
    const float* xr = x + (size_t)row * D_;
    f32x4 v = *(const f32x4*)(xr + tid * 4);
    float ss = v.x * v.x + v.y * v.y + v.z * v.z + v.w * v.w;
#pragma unroll
    for (int off = 32; off >= 1; off >>= 1) ss += __shfl_xor(ss, off);
    __shared__ float red[4];
    if ((tid & 63) == 0) red[tid >> 6] = ss;
    __syncthreads();
    float tot = red[0] + red[1] + red[2] + red[3];
    float rr = rsqrtf(tot * (1.0f / D_) + 1e-6f);
    f32x4 wv = *(const f32x4*)(g + tid * 4);
    u16x4 o;
    o.x = f2bf(v.x * rr * wv.x); o.y = f2bf(v.y * rr * wv.y);
    o.z = f2bf(v.z * rr * wv.z); o.w = f2bf(v.w * rr * wv.w);
    *(u16x4*)(out + (size_t)row * D_ + tid * 4) = o;
}

// x += p0 + p1 (split-K partials), store x, then rmsnorm -> out (bf16)
__global__ __launch_bounds__(256)
void rmsnorm_add_k(float* __restrict__ x, const float* __restrict__ p,
                   const float* __restrict__ g, u16* __restrict__ out)
{
    const int row = blockIdx.x, tid = threadIdx.x;
    float* xr = x + (size_t)row * D_;
    const float* p0 = p + (size_t)row * D_;
    const float* p1 = p + (size_t)(M_ * (size_t)D_) + (size_t)row * D_;
    f32x4 a = *(const f32x4*)(xr + tid * 4);
    f32x4 b = *(const f32x4*)(p0 + tid * 4);
    f32x4 c = *(const f32x4*)(p1 + tid * 4);
    f32x4 v;
    v.x = a.x + b.x + c.x; v.y = a.y + b.y + c.y;
    v.z = a.z + b.z + c.z; v.w = a.w + b.w + c.w;
    *(f32x4*)(xr + tid * 4) = v;
    float ss = v.x * v.x + v.y * v.y + v.z * v.z + v.w * v.w;
#pragma unroll
    for (int off = 32; off >= 1; off >>= 1) ss += __shfl_xor(ss, off);
    __shared__ float red[4];
    if ((tid & 63) == 0) red[tid >> 6] = ss;
    __syncthreads();
    float tot = red[0] + red[1] + red[2] + red[3];
    float rr = rsqrtf(tot * (1.0f / D_) + 1e-6f);
    f32x4 wv = *(const f32x4*)(g + tid * 4);
    u16x4 o;
    o.x = f2bf(v.x * rr * wv.x); o.y = f2bf(v.y * rr * wv.y);
    o.z = f2bf(v.z * rr * wv.z); o.w = f2bf(v.w * rr * wv.w);
    *(u16x4*)(out + (size_t)row * D_ + tid * 4) = o;
}

// f32-silu (fallback path)
__global__ __launch_bounds__(256)
void silu_f32_k(const float* __restrict__ h13, u16* __restrict__ hh)
{
    int m = blockIdx.y;
    int f = blockIdx.x * 256 + threadIdx.x;
    float a = h13[(size_t)m * (2 * F_) + f];
    float c = h13[(size_t)m * (2 * F_) + F_ + f];
    float s = a / (1.0f + expf(-a));
    hh[(size_t)m * F_ + f] = f2bf(s * c);
}

__global__ __launch_bounds__(640)
void rope_slow_k(u16* __restrict__ qkv)
{
    int m = blockIdx.x;
    int c2 = threadIdx.x;
    int col = (c2 < 512) ? (c2 * 2) : (1024 + (c2 - 512) * 2);
    int d = col & 63;
    int t = m & (T_ - 1);
    float ang = (float)t * powf(10000.0f, -(float)d / 64.0f);
    float cs = cosf(ang), sn = sinf(ang);
    u16* p = qkv + (size_t)m * 1536 + col;
    float x0 = bf2f(p[0]), x1 = bf2f(p[1]);
    p[0] = f2bf(x0 * cs - x1 * sn);
    p[1] = f2bf(x0 * sn + x1 * cs);
}

// ---------------------------------------------------------------------------
extern "C" void kernel_launch(void* const* d_in, const int* in_sizes, int n_in,
                              void* d_out, int out_size, void* d_ws, size_t ws_size,
                              hipStream_t stream)
{
    const int*   ids = (const int*)d_in[0];
    const float* emb = (const float*)d_in[1];
    const float* qw  = (const float*)d_in[2];
    const float* kw  = (const float*)d_in[3];
    const float* vw  = (const float*)d_in[4];
    const float* ow  = (const float*)d_in[5];
    const float* w1  = (const float*)d_in[6];
    const float* w2  = (const float*)d_in[7];
    const float* w3  = (const float*)d_in[8];
    const float* n1  = (const float*)d_in[9];
    const float* n2  = (const float*)d_in[10];
    const float* nfw = (const float*)d_in[11];
    float* out = (float*)d_out;
    char*  ws  = (char*)d_ws;

    // ---- workspace layout ----
    float* x    = (float*)(ws);                    //  8 MB residual f32
    u16*   xn   = (u16*)(ws + 8388608ULL);         //  4 MB normed acts
    u16*   qkvb = (u16*)(ws + 12582912ULL);        //  6 MB fused qkv
    u16*   attnb= (u16*)(ws + 18874368ULL);        //  4 MB attn out
    float* pW   = (float*)(ws + 23068672ULL);      // 16 MB split-K partials (O & W2 time-shared)
    u16*   hh   = (u16*)(ws + 46137344ULL);        // 11 MB silu(h1)*h3
    float* ropec= (float*)(ws + 57671680ULL);      // 128 KB
    float* ropes= (float*)(ws + 57802752ULL);      // 128 KB
    u16*   embb = (u16*)(ws + 57933824ULL);        // 62.5 MB
    u16*   wqkv = (u16*)(ws + 123469824ULL);       // 24 MB
    u16*   wob  = (u16*)(ws + 148635648ULL);       // 16 MB
    u16*   w13b = (u16*)(ws + 165412864ULL);       // 88 MB (w1/w3 row-interleaved)
    u16*   w2b  = (u16*)(ws + 257687552ULL);       // 44 MB
    u16*   vtb  = (u16*)(ws + 303824896ULL);       //  1 MB V^T
    const unsigned long long NEED = 304873472ULL;

    if (ws_size >= NEED) {
        // ONE mega-prep dispatch: all cvts + rope tables + gather
        prep_k<<<122240, 256, 0, stream>>>(
            emb, qw, kw, vw, ow, w1, w2, w3, ids,
            embb, wqkv, wob, w13b, w2b, x, ropec, ropes);

        for (int l = 0; l < L_; ++l) {
            if (l == 0)
                rmsnorm_k<<<M_, 256, 0, stream>>>(x, n1, xn);
            else
                rmsnorm_add_k<<<M_, 256, 0, stream>>>(x, pW, n1 + l * D_, xn);
            // fused QKV + RoPE + V-transpose (v cols -> vtb, not qkvb)
            gemm2_k<64, 64, 4><<<32 * 24, 256, 0, stream>>>(
                xn, D_, wqkv + (size_t)l * 1572864, 1536, (float*)vtb, qkvb, ropec, ropes);
            attn3_k<<<dim3(32, HK_, B_), 512, 0, stream>>>(qkvb, vtb, attnb);
            // O-proj split-K2 -> f32 partials pW (absorbed by n2 rmsnorm_add)
            gemm2_k<64, 64, 5><<<2 * 32 * 16, 256, 0, stream>>>(
                attnb, D_, wob + (size_t)l * 1048576, 1024, pW, nullptr, nullptr, nullptr);
            rmsnorm_add_k<<<M_, 256, 0, stream>>>(x, pW, n2 + l * D_, xn);
            // fused W1||W3 (interleaved) + SiLU -> hh
            gemm2_k<128, 128, 3><<<16 * 44, 256, 0, stream>>>(
                xn, D_, w13b + (size_t)l * 5767168, 5632, nullptr, hh, nullptr, nullptr);
            // W2 split-K2 -> f32 partials pW (absorbed by next rmsnorm_add)
            gemm2_k<64, 64, 5><<<2 * 32 * 16, 256, 0, stream>>>(
                hh, F_, w2b + (size_t)l * 2883584, 1024, pW, nullptr, nullptr, nullptr);
        }

        rmsnorm_add_k<<<M_, 256, 0, stream>>>(x, pW, nfw, xn);
        // logits: 2-phase 256x128 (multi-block occupancy + 2x B-reuse)
        gemm2_k<256, 128, 1><<<8 * 250, 256, 0, stream>>>(
            xn, D_, embb, V_, out, nullptr, nullptr, nullptr);
        return;
    }

    // ---------------- fallback: round-1 proven path ----------------
    float* h13f = (float*)(ws + 23068672ULL);
    u16*   hhf  = (u16*)(ws + 69206016ULL);
    gather_k<<<M_, 256, 0, stream>>>(ids, emb, x);

    for (int l = 0; l < L_; ++l) {
        rmsnorm_k<<<M_, 256, 0, stream>>>(x, n1 + l * D_, xn);
        gemm_k<128, 64, 0, 3><<<dim3(24, 16), 256, 0, stream>>>(
            xn, D_,
            qw + (size_t)l * H_ * DH_ * D_,
            kw + (size_t)l * HK_ * DH_ * D_,
            vw + (size_t)l * HK_ * DH_ * D_,
            1024, 256, 1536, nullptr, qkvb);
        rope_slow_k<<<M_, 640, 0, stream>>>(qkvb);
        attn_k<<<dim3(T_ / 64, H_, B_), 256, 0, stream>>>(qkvb, attnb);
        gemm_k<128, 64, 2, 1><<<dim3(16, 16), 256, 0, stream>>>(
            attnb, D_, ow + (size_t)l * D_ * D_, nullptr, nullptr,
            0, 0, D_, x, nullptr);
        rmsnorm_k<<<M_, 256, 0, stream>>>(x, n2 + l * D_, xn);
        gemm_k<128, 128, 1, 2><<<dim3(44, 16), 256, 0, stream>>>(
            xn, D_, w1 + (size_t)l * F_ * D_, w3 + (size_t)l * F_ * D_, nullptr,
            F_, 0, 2 * F_, h13f, nullptr);
        silu_f32_k<<<dim3(11, M_), 256, 0, stream>>>(h13f, hhf);
        gemm_k<128, 64, 2, 1><<<dim3(16, 16), 256, 0, stream>>>(
            hhf, F_, w2 + (size_t)l * D_ * F_, nullptr, nullptr,
            0, 0, D_, x, nullptr);
    }

    rmsnorm_k<<<M_, 256, 0, stream>>>(x, nfw, xn);
    gemm_k<128, 128, 1, 1><<<dim3(250, 16), 256, 0, stream>>>(
        xn, D_, emb, nullptr, nullptr, 0, 0, V_, out, nullptr);
}

// Round 13
// 1672.482 us; speedup vs baseline: 1.1660x; 1.0072x over previous
//
#include <hip/hip_runtime.h>
#include <math.h>

#define L_ 8
#define D_ 1024
#define H_ 16
#define HK_ 4
#define DH_ 64
#define F_ 2816
#define V_ 32000
#define T_ 1024
#define B_ 2
#define M_ (B_*T_)          // 2048 tokens
#define SCALE_ 0.125f       // DH^-0.5

typedef unsigned short u16;
typedef unsigned int   u32;
typedef __attribute__((ext_vector_type(4))) float  f32x4;
typedef __attribute__((ext_vector_type(8))) short  bf16x8;   // 8 bf16 = 4 VGPRs (MFMA A/B frag)
typedef __attribute__((ext_vector_type(4))) unsigned short u16x4;
typedef __attribute__((ext_vector_type(4))) unsigned int   u32x4;

__device__ __forceinline__ float bf2f(u16 h) {
    union { u32 u; float f; } v; v.u = ((u32)h) << 16; return v.f;
}
__device__ __forceinline__ u16 f2bf(float f) {   // round-to-nearest-even
    union { float f; u32 u; } v; v.f = f;
    u32 r = v.u + 0x7fffu + ((v.u >> 16) & 1u);
    return (u16)(r >> 16);
}

__device__ __forceinline__ void gl_lds16(const void* g, void* l) {
    __builtin_amdgcn_global_load_lds(
        (const __attribute__((address_space(1))) unsigned int*)g,
        (__attribute__((address_space(3))) unsigned int*)l,
        16, 0, 0);
}

__device__ __forceinline__ void bar8() {      // raw barrier + compiler fences
    asm volatile("" ::: "memory");
    __builtin_amdgcn_s_barrier();
    asm volatile("" ::: "memory");
}

// ---------------------------------------------------------------------------
// gemm8: 256x256 / BK=64 8-phase GEMM (bank-conflict-free, proven r9/r10).
// LOGITS only (grid 1000). Coalesced f32x4 epilogue via per-wave LDS.
// ---------------------------------------------------------------------------
template<int EPI>
__global__ __launch_bounds__(512)
void gemm8_k(const u16* __restrict__ A, int K,
             const u16* __restrict__ W, int N,
             float* __restrict__ Of, u16* __restrict__ Ob)
{
    constexpr int TS = 256 * 64;            // u16 per tile buffer (32 KB)
    __shared__ u16 sA[2 * TS];              // 64 KB
    __shared__ u16 sB[2 * TS];              // 64 KB

    const int tid = threadIdx.x;
    const int lane = tid & 63, wv = tid >> 6;        // 8 waves
    const int wm = wv >> 2, wn = wv & 3;             // 2 x 4
    const int l15 = lane & 15, lhi = lane >> 4;

    const int nwg = gridDim.x;
    const int q8 = nwg >> 3;
    const int xcd = blockIdx.x & 7, off8 = blockIdx.x >> 3;
    const int wgid = xcd * q8 + off8;
    const int tM = wgid & 7, tN = wgid >> 3;         // M_/256 == 8

    const u16* Abase = A + (size_t)(tM * 256) * K;
    const u16* Wbase = W + (size_t)(tN * 256) * K;

    const int srow8 = lane >> 3;            // row within chunk
    const int sp    = lane & 7;             // physical 16B slot
    const int scol  = (sp ^ srow8) * 8;     // pre-swizzled global col (elems)

    auto stage = [&](const u16* gbase, int t2, int h, u16* dst) {
        const u16* g = gbase + (size_t)(h * 128) * K + (t2 << 6);
        u16* d = dst + h * 8192;
#pragma unroll
        for (int i = 0; i < 2; ++i) {
            int c = wv * 2 + i;                      // 0..15
            int row = c * 8 + srow8;                 // 0..127
            gl_lds16(g + (size_t)row * K + scol, d + c * 512);
        }
    };

    f32x4 acc[8][4];
#pragma unroll
    for (int i = 0; i < 8; ++i)
#pragma unroll
        for (int j = 0; j < 4; ++j) acc[i][j] = f32x4{0.f, 0.f, 0.f, 0.f};

    const int nt = K >> 6;
    stage(Abase, 0, 0, sA); stage(Abase, 0, 1, sA);
    stage(Wbase, 0, 0, sB); stage(Wbase, 0, 1, sB);
    if (nt > 1) {
        stage(Wbase, 1, 0, sB + TS); stage(Wbase, 1, 1, sB + TS);
        asm volatile("s_waitcnt vmcnt(4)" ::: "memory");
    } else {
        asm volatile("s_waitcnt vmcnt(0)" ::: "memory");
    }
    bar8();

    for (int t = 0; t < nt; ++t) {
        const int cur = t & 1;
        const u16* sa = sA + cur * TS;
        const u16* sb = sB + cur * TS;
        u16* saN = sA + (cur ^ 1) * TS;
        u16* sbN = sB + cur * TS;

        bf16x8 breg[4][2];

#pragma unroll
        for (int p = 0; p < 4; ++p) {
            if (p == 0) {
#pragma unroll
                for (int j = 0; j < 4; ++j)
#pragma unroll
                    for (int kk = 0; kk < 2; ++kk) {
                        int br = wn * 64 + j * 16 + l15;
                        int ls = kk * 4 + lhi;
                        breg[j][kk] = *(const bf16x8*)
                            &sb[br * 64 + ((ls ^ (br & 7)) * 8)];
                    }
            }
            bf16x8 areg[2][2];
#pragma unroll
            for (int mi = 0; mi < 2; ++mi)
#pragma unroll
                for (int kk = 0; kk < 2; ++kk) {
                    int ar = wm * 128 + (p * 2 + mi) * 16 + l15;
                    int ls = kk * 4 + lhi;
                    areg[mi][kk] = *(const bf16x8*)
                        &sa[ar * 64 + ((ls ^ (ar & 7)) * 8)];
                }

            if (p == 0 && t + 1 < nt) stage(Abase, t + 1, 0, saN);
            if (p == 1 && t + 1 < nt) stage(Abase, t + 1, 1, saN);
            if (p == 2 && t + 2 < nt) stage(Wbase, t + 2, 0, sbN);
            if (p == 3 && t + 2 < nt) stage(Wbase, t + 2, 1, sbN);

            if (p == 3 && t + 1 < nt) {
                if (t + 2 < nt) asm volatile("s_waitcnt vmcnt(4)" ::: "memory");
                else            asm volatile("s_waitcnt vmcnt(0)" ::: "memory");
            }

            bar8();
            asm volatile("s_waitcnt lgkmcnt(0)" ::: "memory");
            __builtin_amdgcn_s_setprio(1);
#pragma unroll
            for (int mi = 0; mi < 2; ++mi)
#pragma unroll
                for (int j = 0; j < 4; ++j)
#pragma unroll
                    for (int kk = 0; kk < 2; ++kk)
                        acc[p * 2 + mi][j] = __builtin_amdgcn_mfma_f32_16x16x32_bf16(
                            areg[mi][kk], breg[j][kk], acc[p * 2 + mi][j], 0, 0, 0);
            __builtin_amdgcn_s_setprio(0);
            bar8();
        }
    }

    if (EPI == 1) {
        float* sw = (float*)sA + wv * (16 * 68);
        const int cc = l15;
#pragma unroll
        for (int i = 0; i < 8; ++i) {
#pragma unroll
            for (int j = 0; j < 4; ++j)
#pragma unroll
                for (int r = 0; r < 4; ++r)
                    sw[(lhi * 4 + r) * 68 + j * 16 + l15] = acc[i][j][r];
#pragma unroll
            for (int g = 0; g < 4; ++g) {
                int row = g * 4 + lhi;
                f32x4 v = *(const f32x4*)&sw[row * 68 + cc * 4];
                size_t gm = (size_t)tM * 256 + wm * 128 + i * 16 + row;
                size_t gn = (size_t)tN * 256 + wn * 64 + cc * 4;
                *(f32x4*)&Of[gm * (size_t)N + gn] = v;
            }
        }
    } else {
#pragma unroll
        for (int i = 0; i < 8; ++i)
#pragma unroll
            for (int j = 0; j < 4; ++j) {
                size_t gm = (size_t)tM * 256 + wm * 128 + i * 16 + lhi * 4;
                size_t gn = (size_t)tN * 256 + wn * 64 + j * 16 + l15;
#pragma unroll
                for (int r = 0; r < 4; ++r) {
                    float v = acc[i][j][r];
                    float b = __shfl_xor(v, 1);
                    if ((lane & 1) == 0) {
                        float s = v / (1.0f + expf(-v));
                        Ob[(gm + r) * (size_t)F_ + (gn >> 1)] = f2bf(s * b);
                    }
                }
            }
    }
}

// ---------------------------------------------------------------------------
// 2-phase double-buffered GEMM (proven): C[M,N]=A[M,K] x W[N,K]^T, bf16.
// EPI: 0 = bf16 store, 1 = f32 store, 2 = f32 +=,
//      3 = fused SiLU (w1/w3 row-interleaved), 4 = fused RoPE + V-transpose,
//      5 = split-K2 f32 partial store (Of[kh][M_][D_])
// ---------------------------------------------------------------------------
template<int BM, int BN, int EPI>
__global__ __launch_bounds__(256)
void gemm2_k(const u16* __restrict__ A, int K,
             const u16* __restrict__ W, int N,
             float* __restrict__ Of, u16* __restrict__ Ob,
             const float* __restrict__ tc, const float* __restrict__ ts)
{
    constexpr int FM = BM / 32;
    constexpr int FN = BN / 32;
    constexpr int GM = M_ / BM;
    constexpr int IPA = BM / 64;
    constexpr int IPB = BN / 64;
    __shared__ u16 sA[2 * BM * 32];
    __shared__ u16 sB[2 * BN * 32];

    const int tid  = threadIdx.x;
    const int lane = tid & 63, wv = tid >> 6;
    const int wm = wv >> 1, wn = wv & 1;
    const int l15 = lane & 15, lhi = lane >> 4;
    const int m0 = wm * (BM / 2), n0 = wn * (BN / 2);

    const int nwg = gridDim.x;
    const int q8 = nwg >> 3, r8 = nwg & 7;
    const int xcd = blockIdx.x & 7, off8 = blockIdx.x >> 3;
    const int wgid = (xcd < r8 ? xcd * (q8 + 1) : r8 * (q8 + 1) + (xcd - r8) * q8) + off8;

    int tM, tN, kh = 0, koff = 0, Klen = K;
    if (EPI == 5) {
        kh = wgid & 1;
        int wg2 = wgid >> 1;
        tM = wg2 % GM; tN = wg2 / GM;
        Klen = K >> 1; koff = kh * Klen;
    } else {
        tM = wgid % GM; tN = wgid / GM;
    }

    const int srow = lane >> 2;
    const int scol = (lane & 3) * 8;

    const u16* Abase = A + (size_t)(tM * BM) * K + koff;
    const u16* Wbase = W + (size_t)(tN * BN) * K + koff;

    f32x4 acc[FM][FN];
#pragma unroll
    for (int i = 0; i < FM; ++i)
#pragma unroll
        for (int j = 0; j < FN; ++j) acc[i][j] = f32x4{0.f, 0.f, 0.f, 0.f};

    auto stage = [&](int kt, int buf) {
        u16* sa = sA + buf * (BM * 32);
        u16* sb = sB + buf * (BN * 32);
#pragma unroll
        for (int i = 0; i < IPA; ++i) {
            int c = wv * IPA + i;
            gl_lds16(Abase + (size_t)(c * 16 + srow) * K + kt + scol, sa + c * 512);
        }
#pragma unroll
        for (int i = 0; i < IPB; ++i) {
            int c = wv * IPB + i;
            gl_lds16(Wbase + (size_t)(c * 16 + srow) * K + kt + scol, sb + c * 512);
        }
    };

    const int nt = Klen >> 5;
    stage(0, 0);
    asm volatile("s_waitcnt vmcnt(0)" ::: "memory");
    __syncthreads();

    int cur = 0;
    for (int t = 0; t < nt; ++t) {
        if (t + 1 < nt) stage((t + 1) << 5, cur ^ 1);

        const u16* sa = sA + cur * (BM * 32);
        const u16* sb = sB + cur * (BN * 32);
        bf16x8 av[FM], bv[FN];
#pragma unroll
        for (int i = 0; i < FM; ++i)
            av[i] = *(const bf16x8*)&sa[(m0 + i * 16 + l15) * 32 + lhi * 8];
#pragma unroll
        for (int j = 0; j < FN; ++j)
            bv[j] = *(const bf16x8*)&sb[(n0 + j * 16 + l15) * 32 + lhi * 8];
#pragma unroll
        for (int i = 0; i < FM; ++i)
#pragma unroll
            for (int j = 0; j < FN; ++j)
                acc[i][j] = __builtin_amdgcn_mfma_f32_16x16x32_bf16(
                    av[i], bv[j], acc[i][j], 0, 0, 0);

        if (t + 1 < nt) {
            asm volatile("s_waitcnt vmcnt(0)" ::: "memory");
            __syncthreads();
            cur ^= 1;
        }
    }

#pragma unroll
    for (int i = 0; i < FM; ++i)
#pragma unroll
        for (int j = 0; j < FN; ++j) {
            size_t gm = (size_t)tM * BM + m0 + i * 16 + lhi * 4;
            size_t gn = (size_t)tN * BN + n0 + j * 16 + l15;
#pragma unroll
            for (int r = 0; r < 4; ++r) {
                float v = acc[i][j][r];
                size_t idx = (gm + r) * (size_t)N + gn;
                if (EPI == 0) {
                    Ob[idx] = f2bf(v);
                } else if (EPI == 1) {
                    Of[idx] = v;
                } else if (EPI == 2) {
                    Of[idx] += v;
                } else if (EPI == 5) {
                    Of[(size_t)kh * (M_ * (size_t)D_) + idx] = v;
                } else if (EPI == 3) {
                    float b = __shfl_xor(v, 1);
                    if ((lane & 1) == 0) {
                        float s = v / (1.0f + expf(-v));
                        Ob[(gm + r) * (size_t)F_ + (gn >> 1)] = f2bf(s * b);
                    }
                } else {   // EPI == 4: RoPE q/k; v cols -> transposed vt
                    float b = __shfl_xor(v, 1);
                    int gni = (int)gn;
                    int gmr = (int)(gm + r);
                    if (gni < 1280) {
                        int dd = gni & 63;
                        int jj = dd >> 1;
                        int tt = gmr & (T_ - 1);
                        float c = tc[tt * 32 + jj], s = ts[tt * 32 + jj];
                        float ro = ((dd & 1) == 0) ? (v * c - b * s) : (b * s + v * c);
                        Ob[idx] = f2bf(ro);
                    } else {
                        int vc = gni - 1280;              // 0..255
                        int hk = vc >> 6, dd = vc & 63;
                        int bb = gmr >> 10, tt = gmr & (T_ - 1);
                        ((u16*)Of)[((size_t)((bb * HK_ + hk) * DH_ + dd)) * T_ + tt] = f2bf(v);
                    }
                }
            }
        }
}

// ---------------------------------------------------------------------------
// MEGA-PREP: all weight cvts + rope tables + gather in ONE dispatch.
// ---------------------------------------------------------------------------
__global__ __launch_bounds__(256)
void prep_k(const float* __restrict__ emb, const float* __restrict__ qw,
            const float* __restrict__ kw, const float* __restrict__ vw,
            const float* __restrict__ ow, const float* __restrict__ w1,
            const float* __restrict__ w2, const float* __restrict__ w3,
            const int* __restrict__ ids,
            u16* __restrict__ embb, u16* __restrict__ wqkv,
            u16* __restrict__ wob, u16* __restrict__ w13b,
            u16* __restrict__ w2b, float* __restrict__ x,
            float* __restrict__ tc, float* __restrict__ ts)
{
    const int bx = blockIdx.x, tid = threadIdx.x;
    const float* src = nullptr;
    u16* dst = nullptr;

    if (bx < 32000) {
        src = emb + (size_t)bx * 1024;           dst = embb + (size_t)bx * 1024;
    } else if (bx < 40192) {
        int lb = bx - 32000, l = lb >> 10, j = lb & 1023;
        src = qw + (size_t)l * 1048576 + j * 1024;
        dst = wqkv + (size_t)l * 1572864 + j * 1024;
    } else if (bx < 42240) {
        int lb = bx - 40192, l = lb >> 8, j = lb & 255;
        src = kw + (size_t)l * 262144 + j * 1024;
        dst = wqkv + (size_t)l * 1572864 + 1048576 + j * 1024;
    } else if (bx < 44288) {
        int lb = bx - 42240, l = lb >> 8, j = lb & 255;
        src = vw + (size_t)l * 262144 + j * 1024;
        dst = wqkv + (size_t)l * 1572864 + 1310720 + j * 1024;
    } else if (bx < 52480) {
        int lb = bx - 44288, l = lb >> 10, j = lb & 1023;
        src = ow + (size_t)l * 1048576 + j * 1024;
        dst = wob + (size_t)l * 1048576 + j * 1024;
    } else if (bx < 75008) {
        int lb = bx - 52480, l = lb / 2816, f = lb - l * 2816;
        src = w1 + (size_t)l * 2883584 + (size_t)f * 1024;
        dst = w13b + (size_t)l * 5767168 + (size_t)(2 * f) * 1024;
    } else if (bx < 97536) {
        int lb = bx - 75008, l = lb / 2816, f = lb - l * 2816;
        src = w3 + (size_t)l * 2883584 + (size_t)f * 1024;
        dst = w13b + (size_t)l * 5767168 + (size_t)(2 * f + 1) * 1024;
    } else if (bx < 120064) {
        int lb = bx - 97536, l = lb / 2816, f = lb - l * 2816;
        src = w2 + (size_t)l * 2883584 + (size_t)f * 1024;
        dst = w2b + (size_t)l * 2883584 + (size_t)f * 1024;
    } else if (bx < 122112) {
        int m = bx - 120064;
        int id = ids[m];
        *(f32x4*)(x + (size_t)m * D_ + tid * 4) =
            *(const f32x4*)(emb + (size_t)id * D_ + tid * 4);
        return;
    } else {
        int idx = (bx - 122112) * 256 + tid;     // T_*32 total
        int t = idx >> 5, j = idx & 31;
        float inv = powf(10000.0f, -(float)j * (1.0f / 32.0f));
        float ang = (float)t * inv;
        tc[idx] = cosf(ang);
        ts[idx] = sinf(ang);
        return;
    }
    f32x4 v = *(const f32x4*)(src + tid * 4);
    u16x4 o;
    o.x = f2bf(v.x); o.y = f2bf(v.y); o.z = f2bf(v.z); o.w = f2bf(v.w);
    *(u16x4*)(dst + tid * 4) = o;
}

// ---------------------------------------------------------------------------
// FALLBACK GEMM (round-1, proven): cast-in-staging, multi-W split.
// ---------------------------------------------------------------------------
template<int BM, int BN, int EPI, int NW>
__global__ __launch_bounds__(256)
void gemm_k(const u16* __restrict__ A, int K,
            const float* __restrict__ W0, const float* __restrict__ W1p,
            const float* __restrict__ W2p, int N0, int N1, int N,
            float* __restrict__ Of, u16* __restrict__ Ob)
{
    constexpr int FM = BM / 32;
    constexpr int FN = BN / 32;
    constexpr int LS = 40;
    __shared__ u16 sA[BM * LS];
    __shared__ u16 sB[BN * LS];

    const int tid  = threadIdx.x;
    const int lane = tid & 63, wv = tid >> 6;
    const int wm = wv >> 1, wn = wv & 1;
    const int l15 = lane & 15, lhi = lane >> 4;
    const int m0 = wm * (BM / 2), n0 = wn * (BN / 2);
    const int tM = blockIdx.y, tN = blockIdx.x;

    f32x4 acc[FM][FN];
#pragma unroll
    for (int i = 0; i < FM; ++i)
#pragma unroll
        for (int j = 0; j < FN; ++j) acc[i][j] = f32x4{0.f, 0.f, 0.f, 0.f};

    for (int kt = 0; kt < K; kt += 32) {
#pragma unroll
        for (int i = 0; i < BM / 64; ++i) {
            int cid = tid + i * 256;
            int row = cid >> 2, kc = cid & 3;
            const u16* src = A + (size_t)(tM * BM + row) * K + kt + kc * 8;
            *(u32x4*)&sA[row * LS + kc * 8] = *(const u32x4*)src;
        }
#pragma unroll
        for (int i = 0; i < BN / 32; ++i) {
            int cid = tid + i * 256;
            int row = cid >> 3, kc = cid & 7;
            int n = tN * BN + row;
            const float* wr;
            if (NW == 1)      wr = W0 + (size_t)n * K;
            else if (NW == 2) wr = (n < N0) ? (W0 + (size_t)n * K)
                                            : (W1p + (size_t)(n - N0) * K);
            else              wr = (n < N0) ? (W0 + (size_t)n * K)
                               : (n < N0 + N1) ? (W1p + (size_t)(n - N0) * K)
                                               : (W2p + (size_t)(n - N0 - N1) * K);
            f32x4 v = *(const f32x4*)(wr + kt + kc * 4);
            u16x4 o;
            o.x = f2bf(v.x); o.y = f2bf(v.y); o.z = f2bf(v.z); o.w = f2bf(v.w);
            *(u16x4*)&sB[row * LS + kc * 4] = o;
        }
        __syncthreads();

        bf16x8 av[FM], bv[FN];
#pragma unroll
        for (int i = 0; i < FM; ++i)
            av[i] = *(const bf16x8*)&sA[(m0 + i * 16 + l15) * LS + lhi * 8];
#pragma unroll
        for (int j = 0; j < FN; ++j)
            bv[j] = *(const bf16x8*)&sB[(n0 + j * 16 + l15) * LS + lhi * 8];
#pragma unroll
        for (int i = 0; i < FM; ++i)
#pragma unroll
            for (int j = 0; j < FN; ++j)
                acc[i][j] = __builtin_amdgcn_mfma_f32_16x16x32_bf16(
                    av[i], bv[j], acc[i][j], 0, 0, 0);
        __syncthreads();
    }

#pragma unroll
    for (int i = 0; i < FM; ++i)
#pragma unroll
        for (int j = 0; j < FN; ++j) {
            size_t gm = (size_t)tM * BM + m0 + i * 16 + lhi * 4;
            size_t gn = (size_t)tN * BN + n0 + j * 16 + l15;
#pragma unroll
            for (int r = 0; r < 4; ++r) {
                float v = acc[i][j][r];
                size_t idx = (gm + r) * (size_t)N + gn;
                if (EPI == 0)      Ob[idx] = f2bf(v);
                else if (EPI == 1) Of[idx] = v;
                else               Of[idx] += v;
            }
        }
}

// ---------------------------------------------------------------------------
// Flash attention v3: GQA-shared K/V staging (proven round 8).
// ---------------------------------------------------------------------------
__global__ __launch_bounds__(512)
void attn3_k(const u16* __restrict__ qkv, const u16* __restrict__ vt,
             u16* __restrict__ attn)
{
    const int qt = 31 - blockIdx.x;
    const int hk = blockIdx.y, b = blockIdx.z;
    const int tid = threadIdx.x;
    const int lane = tid & 63, w = tid >> 6;
    const int l15 = lane & 15, lhi = lane >> 4;
    const int h = hk * 4 + (w & 3);
    const int rg = w >> 2;

    __shared__ u16 sK[128 * 64];
    __shared__ u16 sVT[64 * 128];
    __shared__ u16 sP[8][16 * 136];

    const int q0 = qt * 32;
    const int qr0 = q0 + rg * 16;
    const u16* qptr = qkv + (size_t)(b * T_ + qr0 + l15) * 1536 + h * 64 + lhi * 8;
    bf16x8 aq0 = *(const bf16x8*)qptr;
    bf16x8 aq1 = *(const bf16x8*)(qptr + 32);

    f32x4 accO[4];
#pragma unroll
    for (int d = 0; d < 4; ++d) accO[d] = f32x4{0.f, 0.f, 0.f, 0.f};
    float m_r[4] = {-1e30f, -1e30f, -1e30f, -1e30f};
    float l_r[4] = {0.f, 0.f, 0.f, 0.f};
    const int myq = qr0 + lhi * 4;
    const int qmaxw = qr0 + 15;
    u16* sPw = sP[w];

    const int ntiles = (qt >> 2) + 1;
    const u16* vtb = vt + (size_t)((b * HK_ + hk) * DH_) * T_;
    const int L = lane;

    for (int kt = 0; kt < ntiles; ++kt) {
        const int t0 = kt * 128;
#pragma unroll
        for (int i = 0; i < 2; ++i) {
            int c = w * 2 + i;
            int row = c * 8 + (L >> 3);
            int p = L & 7;
            const u16* src = qkv + (size_t)(b * T_ + t0 + row) * 1536 + 1024 + hk * 64
                             + ((p ^ (row & 7)) * 8);
            gl_lds16(src, sK + c * 512);
        }
#pragma unroll
        for (int i = 0; i < 2; ++i) {
            int c = w * 2 + i;
            int row = c * 4 + (L >> 4);
            int p = L & 15;
            const u16* src = vtb + (size_t)row * T_ + t0 + ((p ^ (row & 15)) * 8);
            gl_lds16(src, sVT + c * 512);
        }
        asm volatile("s_waitcnt vmcnt(0)" ::: "memory");
        __syncthreads();

        const bool lastt = (kt == ntiles - 1);

        f32x4 accS[8];
#pragma unroll
        for (int nf = 0; nf < 8; ++nf)
            accS[nf] = f32x4{-1e30f, -1e30f, -1e30f, -1e30f};
#pragma unroll
        for (int pk = 0; pk < 4; ++pk) {
            if (t0 + pk * 32 > qmaxw) continue;
            f32x4 s0 = f32x4{0.f, 0.f, 0.f, 0.f};
            f32x4 s1 = f32x4{0.f, 0.f, 0.f, 0.f};
#pragma unroll
            for (int kk = 0; kk < 2; ++kk) {
                bf16x8 aqs = kk ? aq1 : aq0;
                int r0 = (pk * 2) * 16 + l15;
                int r1 = (pk * 2 + 1) * 16 + l15;
                int ls = kk * 4 + lhi;
                bf16x8 b0 = *(const bf16x8*)&sK[r0 * 64 + ((ls ^ (r0 & 7)) * 8)];
                bf16x8 b1 = *(const bf16x8*)&sK[r1 * 64 + ((ls ^ (r1 & 7)) * 8)];
                s0 = __builtin_amdgcn_mfma_f32_16x16x32_bf16(aqs, b0, s0, 0, 0, 0);
                s1 = __builtin_amdgcn_mfma_f32_16x16x32_bf16(aqs, b1, s1, 0, 0, 0);
            }
#pragma unroll
            for (int r = 0; r < 4; ++r) {
                float v0 = s0[r] * SCALE_;
                float v1 = s1[r] * SCALE_;
                if (lastt) {
                    int kp0 = t0 + (pk * 2) * 16 + l15;
                    int kp1 = kp0 + 16;
                    if (kp0 > myq + r) v0 = -1e30f;
                    if (kp1 > myq + r) v1 = -1e30f;
                }
                accS[pk * 2][r] = v0;
                accS[pk * 2 + 1][r] = v1;
            }
        }

        float sc[4];
#pragma unroll
        for (int r = 0; r < 4; ++r) {
            float mx = accS[0][r];
#pragma unroll
            for (int nf = 1; nf < 8; ++nf) mx = fmaxf(mx, accS[nf][r]);
#pragma unroll
            for (int off = 1; off < 16; off <<= 1) mx = fmaxf(mx, __shfl_xor(mx, off));
            float mn = fmaxf(m_r[r], mx);
            sc[r] = expf(m_r[r] - mn);
            m_r[r] = mn;
        }
        float rs[4] = {0.f, 0.f, 0.f, 0.f};
#pragma unroll
        for (int pk = 0; pk < 4; ++pk) {
            if (t0 + pk * 32 > qmaxw) continue;
#pragma unroll
            for (int g = 0; g < 2; ++g) {
                int nf = pk * 2 + g;
#pragma unroll
                for (int r = 0; r < 4; ++r) {
                    float p = expf(accS[nf][r] - m_r[r]);
                    accS[nf][r] = p;
                    rs[r] += p;
                }
            }
        }
#pragma unroll
        for (int r = 0; r < 4; ++r) {
#pragma unroll
            for (int off = 1; off < 16; off <<= 1) rs[r] += __shfl_xor(rs[r], off);
            l_r[r] = l_r[r] * sc[r] + rs[r];
        }
#pragma unroll
        for (int d = 0; d < 4; ++d)
#pragma unroll
            for (int r = 0; r < 4; ++r) accO[d][r] *= sc[r];

#pragma unroll
        for (int pk = 0; pk < 4; ++pk) {
            if (t0 + pk * 32 > qmaxw) continue;
#pragma unroll
            for (int g = 0; g < 2; ++g) {
                int nf = pk * 2 + g;
#pragma unroll
                for (int r = 0; r < 4; ++r)
                    sPw[(lhi * 4 + r) * 136 + nf * 16 + l15] = f2bf(accS[nf][r]);
            }
        }

#pragma unroll
        for (int kk = 0; kk < 4; ++kk) {
            if (t0 + kk * 32 > qmaxw) continue;
            bf16x8 pas = *(const bf16x8*)&sPw[l15 * 136 + kk * 32 + lhi * 8];
#pragma unroll
            for (int nf = 0; nf < 4; ++nf) {
                int row = nf * 16 + l15;
                int ls = kk * 4 + lhi;
                bf16x8 bvv = *(const bf16x8*)&sVT[row * 128 + ((ls ^ (row & 15)) * 8)];
                accO[nf] = __builtin_amdgcn_mfma_f32_16x16x32_bf16(pas, bvv, accO[nf], 0, 0, 0);
            }
        }
        __syncthreads();
    }

#pragma unroll
    for (int d = 0; d < 4; ++d)
#pragma unroll
        for (int r = 0; r < 4; ++r) {
            int row = qr0 + lhi * 4 + r;
            float o = accO[d][r] / l_r[r];
            attn[(size_t)(b * T_ + row) * 1024 + h * 64 + d * 16 + l15] = f2bf(o);
        }
}

// ---------------------------------------------------------------------------
// FALLBACK attention (round-1 proven)
// ---------------------------------------------------------------------------
__global__ __launch_bounds__(256)
void attn_k(const u16* __restrict__ qkv, u16* __restrict__ attn)
{
    const int qt = blockIdx.x, h = blockIdx.y, b = blockIdx.z;
    const int hk = h >> 2;
    const int tid = threadIdx.x;
    const int lane = tid & 63, w = tid >> 6;
    const int l15 = lane & 15, lhi = lane >> 4;
    __shared__ u16 sK[64 * 72];
    __shared__ u16 sVT[64 * 74];
    __shared__ u16 sP[4 * 16 * 72];

    const int q0 = qt * 64;
    const u16* qptr = qkv + (size_t)(b * T_ + q0 + w * 16 + l15) * 1536 + h * 64 + lhi * 8;
    bf16x8 aq0 = *(const bf16x8*)qptr;
    bf16x8 aq1 = *(const bf16x8*)(qptr + 32);

    f32x4 accO[4];
#pragma unroll
    for (int d = 0; d < 4; ++d) accO[d] = f32x4{0.f, 0.f, 0.f, 0.f};
    float m_r[4] = {-1e30f, -1e30f, -1e30f, -1e30f};
    float l_r[4] = {0.f, 0.f, 0.f, 0.f};
    const int myq = q0 + w * 16 + lhi * 4;
    u16* sPw = sP + w * 16 * 72;

    for (int kt = 0; kt <= qt; ++kt) {
#pragma unroll
        for (int i = 0; i < 2; ++i) {
            int cid = tid + i * 256;
            int r = cid >> 3, kc = cid & 7;
            const u16* src = qkv + (size_t)(b * T_ + kt * 64 + r) * 1536 + 1024 + hk * 64 + kc * 8;
            *(u32x4*)&sK[r * 72 + kc * 8] = *(const u32x4*)src;
        }
#pragma unroll
        for (int i = 0; i < 2; ++i) {
            int cid = tid + i * 256;
            int tt = cid >> 3, dc = cid & 7;
            const u16* src = qkv + (size_t)(b * T_ + kt * 64 + tt) * 1536 + 1280 + hk * 64 + dc * 8;
            bf16x8 vv = *(const bf16x8*)src;
#pragma unroll
            for (int j = 0; j < 8; ++j) sVT[(dc * 8 + j) * 74 + tt] = (u16)vv[j];
        }
        __syncthreads();

        f32x4 accS[4];
#pragma unroll
        for (int nf = 0; nf < 4; ++nf) accS[nf] = f32x4{0.f, 0.f, 0.f, 0.f};
#pragma unroll
        for (int s = 0; s < 2; ++s) {
            bf16x8 aqs = s ? aq1 : aq0;
#pragma unroll
            for (int nf = 0; nf < 4; ++nf) {
                bf16x8 bk = *(const bf16x8*)&sK[(nf * 16 + l15) * 72 + s * 32 + lhi * 8];
                accS[nf] = __builtin_amdgcn_mfma_f32_16x16x32_bf16(aqs, bk, accS[nf], 0, 0, 0);
            }
        }
#pragma unroll
        for (int nf = 0; nf < 4; ++nf)
#pragma unroll
            for (int r = 0; r < 4; ++r) {
                float v = accS[nf][r] * SCALE_;
                if (kt == qt) {
                    int kp = kt * 64 + nf * 16 + l15;
                    if (kp > myq + r) v = -1e30f;
                }
                accS[nf][r] = v;
            }
        float sc[4];
#pragma unroll
        for (int r = 0; r < 4; ++r) {
            float mx = fmaxf(fmaxf(accS[0][r], accS[1][r]), fmaxf(accS[2][r], accS[3][r]));
#pragma unroll
            for (int off = 1; off < 16; off <<= 1) mx = fmaxf(mx, __shfl_xor(mx, off));
            float mn = fmaxf(m_r[r], mx);
            sc[r] = expf(m_r[r] - mn);
            m_r[r] = mn;
        }
        float rs[4] = {0.f, 0.f, 0.f, 0.f};
#pragma unroll
        for (int nf = 0; nf < 4; ++nf)
#pragma unroll
            for (int r = 0; r < 4; ++r) {
                float p = expf(accS[nf][r] - m_r[r]);
                accS[nf][r] = p;
                rs[r] += p;
            }
#pragma unroll
        for (int r = 0; r < 4; ++r) {
#pragma unroll
            for (int off = 1; off < 16; off <<= 1) rs[r] += __shfl_xor(rs[r], off);
            l_r[r] = l_r[r] * sc[r] + rs[r];
        }
#pragma unroll
        for (int d = 0; d < 4; ++d)
#pragma unroll
            for (int r = 0; r < 4; ++r) accO[d][r] *= sc[r];

#pragma unroll
        for (int nf = 0; nf < 4; ++nf)
#pragma unroll
            for (int r = 0; r < 4; ++r)
                sPw[(lhi * 4 + r) * 72 + nf * 16 + l15] = f2bf(accS[nf][r]);
        bf16x8 pa0 = *(const bf16x8*)&sPw[l15 * 72 + lhi * 8];
        bf16x8 pa1 = *(const bf16x8*)&sPw[l15 * 72 + 32 + lhi * 8];
#pragma unroll
        for (int s = 0; s < 2; ++s) {
            bf16x8 pas = s ? pa1 : pa0;
#pragma unroll
            for (int d = 0; d < 4; ++d) {
                bf16x8 bvv = *(const bf16x8*)&sVT[(d * 16 + l15) * 74 + s * 32 + lhi * 8];
                accO[d] = __builtin_amdgcn_mfma_f32_16x16x32_bf16(pas, bvv, accO[d], 0, 0, 0);
            }
        }
        __syncthreads();
    }

#pragma unroll
    for (int d = 0; d < 4; ++d)
#pragma unroll
        for (int r = 0; r < 4; ++r) {
            int row = q0 + w * 16 + lhi * 4 + r;
            float o = accO[d][r] / l_r[r];
            attn[(size_t)(b * T_ + row) * 1024 + h * 64 + d * 16 + l15] = f2bf(o);
        }
}

// ---------------------------------------------------------------------------
// Small elementwise kernels
// ---------------------------------------------------------------------------
__global__ __launch_bounds__(256)
void gather_k(const int* __restrict__ ids, const float* __restrict__ emb,
              float* __restrict__ x)
{
    int m = blockIdx.x, tid = threadIdx.x;
    int id = ids[m];
    *(f32x4*)(x + (size_t)m * D_ + tid * 4) =
        *(const f32x4*)(emb + (size_t)id * D_ + tid * 4);
}

__global__ __launch_bounds__(256)
void rmsnorm_k(const float* __restrict__ x, const float* __restrict__ g,
               u16* __restrict__ out)
{
    const int row = blockIdx.x, tid = threadIdx.x;
    const float* xr = x + (size_t)row * D_;
    f32x4 v = *(const f32x4*)(xr + tid * 4);
    float ss = v.x * v.x + v.y * v.y + v.z * v.z + v.w * v.w;
#pragma unroll
    for (int off = 32; off >= 1; off >>= 1) ss += __shfl_xor(ss, off);
    __shared__ float red[4];
    if ((tid & 63) == 0) red[tid >> 6] = ss;
    __syncthreads();
    float tot = red[0] + red[1] + red[2] + red[3];
    float rr = rsqrtf(tot * (1.0f / D_) + 1e-6f);
    f32x4 wv = *(const f32x4*)(g + tid * 4);
    u16x4 o;
    o.x = f2bf(v.x * rr * wv.x); o.y = f2bf(v.y * rr * wv.y);
    o.z = f2bf(v.z * rr * wv.z); o.w = f2bf(v.w * rr * wv.w);
    *(u16x4*)(out + (size_t)row * D_ + tid * 4) = o;
}

// x += p0 + p1 (split-K partials), store x, then rmsnorm -> out (bf16)
__global__ __launch_bounds__(256)
void rmsnorm_add_k(float* __restrict__ x, const float* __restrict__ p,
                   const float* __restrict__ g, u16* __restrict__ out)
{
    const int row = blockIdx.x, tid = threadIdx.x;
    float* xr = x + (size_t)row * D_;
    const float* p0 = p + (size_t)row * D_;
    const float* p1 = p + (size_t)(M_ * (size_t)D_) + (size_t)row * D_;
    f32x4 a = *(const f32x4*)(xr + tid * 4);
    f32x4 b = *(const f32x4*)(p0 + tid * 4);
    f32x4 c = *(const f32x4*)(p1 + tid * 4);
    f32x4 v;
    v.x = a.x + b.x + c.x; v.y = a.y + b.y + c.y;
    v.z = a.z + b.z + c.z; v.w = a.w + b.w + c.w;
    *(f32x4*)(xr + tid * 4) = v;
    float ss = v.x * v.x + v.y * v.y + v.z * v.z + v.w * v.w;
#pragma unroll
    for (int off = 32; off >= 1; off >>= 1) ss += __shfl_xor(ss, off);
    __shared__ float red[4];
    if ((tid & 63) == 0) red[tid >> 6] = ss;
    __syncthreads();
    float tot = red[0] + red[1] + red[2] + red[3];
    float rr = rsqrtf(tot * (1.0f / D_) + 1e-6f);
    f32x4 wv = *(const f32x4*)(g + tid * 4);
    u16x4 o;
    o.x = f2bf(v.x * rr * wv.x); o.y = f2bf(v.y * rr * wv.y);
    o.z = f2bf(v.z * rr * wv.z); o.w = f2bf(v.w * rr * wv.w);
    *(u16x4*)(out + (size_t)row * D_ + tid * 4) = o;
}

// f32-silu (fallback path)
__global__ __launch_bounds__(256)
void silu_f32_k(const float* __restrict__ h13, u16* __restrict__ hh)
{
    int m = blockIdx.y;
    int f = blockIdx.x * 256 + threadIdx.x;
    float a = h13[(size_t)m * (2 * F_) + f];
    float c = h13[(size_t)m * (2 * F_) + F_ + f];
    float s = a / (1.0f + expf(-a));
    hh[(size_t)m * F_ + f] = f2bf(s * c);
}

__global__ __launch_bounds__(640)
void rope_slow_k(u16* __restrict__ qkv)
{
    int m = blockIdx.x;
    int c2 = threadIdx.x;
    int col = (c2 < 512) ? (c2 * 2) : (1024 + (c2 - 512) * 2);
    int d = col & 63;
    int t = m & (T_ - 1);
    float ang = (float)t * powf(10000.0f, -(float)d / 64.0f);
    float cs = cosf(ang), sn = sinf(ang);
    u16* p = qkv + (size_t)m * 1536 + col;
    float x0 = bf2f(p[0]), x1 = bf2f(p[1]);
    p[0] = f2bf(x0 * cs - x1 * sn);
    p[1] = f2bf(x0 * sn + x1 * cs);
}

// ---------------------------------------------------------------------------
extern "C" void kernel_launch(void* const* d_in, const int* in_sizes, int n_in,
                              void* d_out, int out_size, void* d_ws, size_t ws_size,
                              hipStream_t stream)
{
    const int*   ids = (const int*)d_in[0];
    const float* emb = (const float*)d_in[1];
    const float* qw  = (const float*)d_in[2];
    const float* kw  = (const float*)d_in[3];
    const float* vw  = (const float*)d_in[4];
    const float* ow  = (const float*)d_in[5];
    const float* w1  = (const float*)d_in[6];
    const float* w2  = (const float*)d_in[7];
    const float* w3  = (const float*)d_in[8];
    const float* n1  = (const float*)d_in[9];
    const float* n2  = (const float*)d_in[10];
    const float* nfw = (const float*)d_in[11];
    float* out = (float*)d_out;
    char*  ws  = (char*)d_ws;

    // ---- workspace layout ----
    float* x    = (float*)(ws);                    //  8 MB residual f32
    u16*   xn   = (u16*)(ws + 8388608ULL);         //  4 MB normed acts
    u16*   qkvb = (u16*)(ws + 12582912ULL);        //  6 MB fused qkv
    u16*   attnb= (u16*)(ws + 18874368ULL);        //  4 MB attn out
    float* pW   = (float*)(ws + 23068672ULL);      // 16 MB split-K partials (O & W2 time-shared)
    u16*   hh   = (u16*)(ws + 46137344ULL);        // 11 MB silu(h1)*h3
    float* ropec= (float*)(ws + 57671680ULL);      // 128 KB
    float* ropes= (float*)(ws + 57802752ULL);      // 128 KB
    u16*   embb = (u16*)(ws + 57933824ULL);        // 62.5 MB
    u16*   wqkv = (u16*)(ws + 123469824ULL);       // 24 MB
    u16*   wob  = (u16*)(ws + 148635648ULL);       // 16 MB
    u16*   w13b = (u16*)(ws + 165412864ULL);       // 88 MB (w1/w3 row-interleaved)
    u16*   w2b  = (u16*)(ws + 257687552ULL);       // 44 MB
    u16*   vtb  = (u16*)(ws + 303824896ULL);       //  1 MB V^T
    const unsigned long long NEED = 304873472ULL;

    if (ws_size >= NEED) {
        // ONE mega-prep dispatch: all cvts + rope tables + gather
        prep_k<<<122240, 256, 0, stream>>>(
            emb, qw, kw, vw, ow, w1, w2, w3, ids,
            embb, wqkv, wob, w13b, w2b, x, ropec, ropes);

        for (int l = 0; l < L_; ++l) {
            if (l == 0)
                rmsnorm_k<<<M_, 256, 0, stream>>>(x, n1, xn);
            else
                rmsnorm_add_k<<<M_, 256, 0, stream>>>(x, pW, n1 + l * D_, xn);
            // fused QKV + RoPE + V-transpose (v cols -> vtb, not qkvb)
            gemm2_k<64, 64, 4><<<32 * 24, 256, 0, stream>>>(
                xn, D_, wqkv + (size_t)l * 1572864, 1536, (float*)vtb, qkvb, ropec, ropes);
            attn3_k<<<dim3(32, HK_, B_), 512, 0, stream>>>(qkvb, vtb, attnb);
            // O-proj split-K2 -> f32 partials pW (absorbed by n2 rmsnorm_add)
            gemm2_k<64, 64, 5><<<2 * 32 * 16, 256, 0, stream>>>(
                attnb, D_, wob + (size_t)l * 1048576, 1024, pW, nullptr, nullptr, nullptr);
            rmsnorm_add_k<<<M_, 256, 0, stream>>>(x, pW, n2 + l * D_, xn);
            // fused W1||W3 (interleaved) + SiLU -> hh
            gemm2_k<128, 128, 3><<<16 * 44, 256, 0, stream>>>(
                xn, D_, w13b + (size_t)l * 5767168, 5632, nullptr, hh, nullptr, nullptr);
            // W2 split-K2 -> f32 partials pW (absorbed by next rmsnorm_add)
            gemm2_k<64, 64, 5><<<2 * 32 * 16, 256, 0, stream>>>(
                hh, F_, w2b + (size_t)l * 2883584, 1024, pW, nullptr, nullptr, nullptr);
        }

        rmsnorm_add_k<<<M_, 256, 0, stream>>>(x, pW, nfw, xn);
        // logits: 8-phase 256^2 (best measured: ~193 us), coalesced epilogue
        gemm8_k<1><<<8 * 125, 512, 0, stream>>>(
            xn, D_, embb, V_, out, nullptr);
        return;
    }

    // ---------------- fallback: round-1 proven path ----------------
    float* h13f = (float*)(ws + 23068672ULL);
    u16*   hhf  = (u16*)(ws + 69206016ULL);
    gather_k<<<M_, 256, 0, stream>>>(ids, emb, x);

    for (int l = 0; l < L_; ++l) {
        rmsnorm_k<<<M_, 256, 0, stream>>>(x, n1 + l * D_, xn);
        gemm_k<128, 64, 0, 3><<<dim3(24, 16), 256, 0, stream>>>(
            xn, D_,
            qw + (size_t)l * H_ * DH_ * D_,
            kw + (size_t)l * HK_ * DH_ * D_,
            vw + (size_t)l * HK_ * DH_ * D_,
            1024, 256, 1536, nullptr, qkvb);
        rope_slow_k<<<M_, 640, 0, stream>>>(qkvb);
        attn_k<<<dim3(T_ / 64, H_, B_), 256, 0, stream>>>(qkvb, attnb);
        gemm_k<128, 64, 2, 1><<<dim3(16, 16), 256, 0, stream>>>(
            attnb, D_, ow + (size_t)l * D_ * D_, nullptr, nullptr,
            0, 0, D_, x, nullptr);
        rmsnorm_k<<<M_, 256, 0, stream>>>(x, n2 + l * D_, xn);
        gemm_k<128, 128, 1, 2><<<dim3(44, 16), 256, 0, stream>>>(
            xn, D_, w1 + (size_t)l * F_ * D_, w3 + (size_t)l * F_ * D_, nullptr,
            F_, 0, 2 * F_, h13f, nullptr);
        silu_f32_k<<<dim3(11, M_), 256, 0, stream>>>(h13f, hhf);
        gemm_k<128, 64, 2, 1><<<dim3(16, 16), 256, 0, stream>>>(
            hhf, F_, w2 + (size_t)l * D_ * F_, nullptr, nullptr,
            0, 0, D_, x, nullptr);
    }

    rmsnorm_k<<<M_, 256, 0, stream>>>(x, nfw, xn);
    gemm_k<128, 128, 1, 1><<<dim3(250, 16), 256, 0, stream>>>(
        xn, D_, emb, nullptr, nullptr, 0, 0, V_, out, nullptr);
}